// Round 1
// baseline (1196.302 us; speedup 1.0000x reference)
//
#include <hip/hip_runtime.h>
#include <math.h>

#define LSEQ 4096
#define DDIM 1024
#define NB 4
#define NH 16
#define DHD 64
#define NFREQ 2049
#define NFMAX 4097

__device__ __forceinline__ float gelu_exact(float v) {
    return 0.5f * v * (1.0f + erff(v * 0.70710678118654752440f));
}

// ---------------- xbar = mean over l of x ----------------
__global__ __launch_bounds__(256) void k_xbar_partial(const float* __restrict__ x, float* __restrict__ xbp) {
    int d = blockIdx.x * 256 + threadIdx.x;
    int chunk = blockIdx.y;          // 16 chunks of 256 l
    int b = blockIdx.z;
    const float* p = x + ((size_t)b * LSEQ + (size_t)chunk * 256) * DDIM + d;
    float acc = 0.f;
    for (int l = 0; l < 256; ++l) acc += p[(size_t)l * DDIM];
    xbp[(size_t)(b * 16 + chunk) * DDIM + d] = acc;
}

__global__ __launch_bounds__(256) void k_xbar_reduce(const float* __restrict__ xbp, float* __restrict__ xbar) {
    int d = blockIdx.x * 256 + threadIdx.x;
    int b = blockIdx.y;
    float acc = 0.f;
    for (int c = 0; c < 16; ++c) acc += xbp[(size_t)(b * 16 + c) * DDIM + d];
    xbar[b * DDIM + d] = acc * (1.0f / LSEQ);
}

// ---------------- q_bar = xbar @ Wq^T (one wave per e, all 4 b) ----------------
__global__ __launch_bounds__(256) void k_qbar(const float* __restrict__ xbar, const float* __restrict__ Wq,
                                              float* __restrict__ qbar) {
    int lane = threadIdx.x & 63;
    int e = blockIdx.x * 4 + (threadIdx.x >> 6);
    const float* wrow = Wq + (size_t)e * DDIM;
    float a0 = 0, a1 = 0, a2 = 0, a3 = 0;
    for (int i = 0; i < 16; ++i) {
        int d = lane + i * 64;
        float w = wrow[d];
        a0 += w * xbar[d];
        a1 += w * xbar[DDIM + d];
        a2 += w * xbar[2 * DDIM + d];
        a3 += w * xbar[3 * DDIM + d];
    }
    for (int off = 32; off > 0; off >>= 1) {
        a0 += __shfl_down(a0, off);
        a1 += __shfl_down(a1, off);
        a2 += __shfl_down(a2, off);
        a3 += __shfl_down(a3, off);
    }
    if (lane == 0) {
        qbar[e] = a0;
        qbar[DDIM + e] = a1;
        qbar[2 * DDIM + e] = a2;
        qbar[3 * DDIM + e] = a3;
    }
}

// ---------------- per-(b,h): LN -> W1+gelu (h1), LN -> Ww1 gelu -> Ww2 sigmoid (gw) ----------------
__global__ __launch_bounds__(256) void k_mlp(const float* __restrict__ qbar,
                                             const float* __restrict__ ln_g_s, const float* __restrict__ ln_g_b,
                                             const float* __restrict__ W1, const float* __restrict__ b1,
                                             const float* __restrict__ ln_w_s, const float* __restrict__ ln_w_b,
                                             const float* __restrict__ Ww1, const float* __restrict__ bw1,
                                             const float* __restrict__ Ww2, const float* __restrict__ bw2,
                                             float* __restrict__ h1g, float* __restrict__ gwp1) {
    int bh = blockIdx.x;   // b*16+h ; qbar offset bh*64 == b*1024 + h*64
    __shared__ float q[64], hg[64], hw[64], g1[64];
    __shared__ float sm, sv;
    int t = threadIdx.x;
    if (t < 64) q[t] = qbar[bh * 64 + t];
    __syncthreads();
    if (t == 0) {
        float m = 0;
        for (int i = 0; i < 64; ++i) m += q[i];
        m *= (1.0f / 64.0f);
        float v = 0;
        for (int i = 0; i < 64; ++i) { float dd = q[i] - m; v += dd * dd; }
        v *= (1.0f / 64.0f);
        sm = m; sv = v;
    }
    __syncthreads();
    if (t < 64) {
        float n = (q[t] - sm) * rsqrtf(sv + 1e-5f);
        hg[t] = n * ln_g_s[t] + ln_g_b[t];
        hw[t] = n * ln_w_s[t] + ln_w_b[t];
    }
    __syncthreads();
    {
        int f = t;  // 0..255
        const float* w = W1 + (size_t)f * 64;
        float s = b1[f];
        for (int d0 = 0; d0 < 64; ++d0) s += hg[d0] * w[d0];
        h1g[(size_t)bh * 256 + f] = gelu_exact(s);
    }
    if (t < 64) {
        const float* w = Ww1 + (size_t)t * 64;
        float s = bw1[t];
        for (int k = 0; k < 64; ++k) s += hw[k] * w[k];
        g1[t] = gelu_exact(s);
    }
    __syncthreads();
    if (t < 64) {
        const float* w = Ww2 + (size_t)t * 64;
        float s = bw2[t];
        for (int k = 0; k < 64; ++k) s += g1[k] * w[k];
        gwp1[bh * 64 + t] = 1.0f + 1.0f / (1.0f + expf(-s));  // store 1+gw
    }
}

// ---------------- gate = h1 @ W2^T (+b2), only needed rows; one wave per (f,part) over all 64 bh ----------------
__global__ __launch_bounds__(256) void k_gate(const float* __restrict__ h1g, const float* __restrict__ W2,
                                              const float* __restrict__ b2,
                                              float* __restrict__ gre, float* __restrict__ gim) {
    int task = blockIdx.x * 4 + (threadIdx.x >> 6);
    if (task >= 2 * NFREQ) return;
    int lane = threadIdx.x & 63;
    int part = task >= NFREQ;
    int f = task - part * NFREQ;
    int row = part ? (NFMAX + f) : f;
    const float* w = W2 + (size_t)row * 256;
    float w0 = w[lane], w1 = w[64 + lane], w2 = w[128 + lane], w3 = w[192 + lane];
    float bias = b2[row];
    float* dst = part ? gim : gre;
    for (int bh = 0; bh < 64; ++bh) {
        const float* hr = h1g + (size_t)bh * 256;
        float p = w0 * hr[lane] + w1 * hr[64 + lane] + w2 * hr[128 + lane] + w3 * hr[192 + lane];
        for (int off = 32; off > 0; off >>= 1) p += __shfl_down(p, off);
        if (lane == 0) dst[(size_t)bh * NFREQ + f] = p + bias;
    }
}

// ---------------- v GEMM: vt[b][e][l] = sum_d x[b][l][d] * Wv[e][d] ----------------
__global__ __launch_bounds__(256) void k_vgemm(const float* __restrict__ x, const float* __restrict__ Wv,
                                               float* __restrict__ vt) {
    __shared__ float as[32][68];   // [k][l]
    __shared__ float bs[32][68];   // [k][e]
    __shared__ float st[64][65];   // [e][l] stage for transposed write
    int e0 = blockIdx.x * 64;
    int l0 = blockIdx.y * 64;
    int b = blockIdx.z;
    int t = threadIdx.x;
    int tx = t & 15, ty = t >> 4;
    float acc[4][4] = {{0.f}};
    const float* Ab = x + ((size_t)b * LSEQ + l0) * DDIM;
    const float* Bb = Wv + (size_t)e0 * DDIM;
    int lrow = t >> 2;          // 0..63
    int lcol = (t & 3) * 8;     // 0,8,16,24
    for (int k0 = 0; k0 < DDIM; k0 += 32) {
        float4 a0 = *(const float4*)(Ab + (size_t)lrow * DDIM + k0 + lcol);
        float4 a1 = *(const float4*)(Ab + (size_t)lrow * DDIM + k0 + lcol + 4);
        float4 c0 = *(const float4*)(Bb + (size_t)lrow * DDIM + k0 + lcol);
        float4 c1 = *(const float4*)(Bb + (size_t)lrow * DDIM + k0 + lcol + 4);
        as[lcol + 0][lrow] = a0.x; as[lcol + 1][lrow] = a0.y; as[lcol + 2][lrow] = a0.z; as[lcol + 3][lrow] = a0.w;
        as[lcol + 4][lrow] = a1.x; as[lcol + 5][lrow] = a1.y; as[lcol + 6][lrow] = a1.z; as[lcol + 7][lrow] = a1.w;
        bs[lcol + 0][lrow] = c0.x; bs[lcol + 1][lrow] = c0.y; bs[lcol + 2][lrow] = c0.z; bs[lcol + 3][lrow] = c0.w;
        bs[lcol + 4][lrow] = c1.x; bs[lcol + 5][lrow] = c1.y; bs[lcol + 6][lrow] = c1.z; bs[lcol + 7][lrow] = c1.w;
        __syncthreads();
#pragma unroll
        for (int k = 0; k < 32; ++k) {
            float4 av = *(const float4*)&as[k][ty * 4];
            float4 bv = *(const float4*)&bs[k][tx * 4];
            acc[0][0] += av.x * bv.x; acc[0][1] += av.x * bv.y; acc[0][2] += av.x * bv.z; acc[0][3] += av.x * bv.w;
            acc[1][0] += av.y * bv.x; acc[1][1] += av.y * bv.y; acc[1][2] += av.y * bv.z; acc[1][3] += av.y * bv.w;
            acc[2][0] += av.z * bv.x; acc[2][1] += av.z * bv.y; acc[2][2] += av.z * bv.z; acc[2][3] += av.z * bv.w;
            acc[3][0] += av.w * bv.x; acc[3][1] += av.w * bv.y; acc[3][2] += av.w * bv.z; acc[3][3] += av.w * bv.w;
        }
        __syncthreads();
    }
#pragma unroll
    for (int i = 0; i < 4; ++i)
#pragma unroll
        for (int j = 0; j < 4; ++j)
            st[tx * 4 + j][ty * 4 + i] = acc[i][j];
    __syncthreads();
    int wv = t >> 6, ln = t & 63;
    for (int i = 0; i < 16; ++i) {
        int er = i * 4 + wv;
        vt[((size_t)b * DDIM + e0 + er) * LSEQ + l0 + ln] = st[er][ln];
    }
}

// ---------------- FFT + gate + modrelu + iFFT + (1+gw) scale, in place on vt[b][e][:] ----------------
__global__ __launch_bounds__(256) void k_fft(float* __restrict__ vty,
                                             const float* __restrict__ gre, const float* __restrict__ gim,
                                             const float* __restrict__ mrb, const float* __restrict__ gwp1) {
    __shared__ float2 Z[4096];
    __shared__ float2 TW[2048];
    int blk = blockIdx.x;
    int b = blk >> 10, e = blk & 1023;
    int h = e >> 6, dh = e & 63;
    int bh = b * 16 + h;
    float* base = vty + (size_t)blk * 4096;
    int t = threadIdx.x;
    for (int k = t; k < 2048; k += 256) {
        float ang = -6.2831853071795864769f * ((float)k / 4096.0f);
        float s, c;
        __sincosf(ang, &s, &c);
        TW[k] = make_float2(c, s);   // exp(-2*pi*i*k/N)
    }
    for (int i = t; i < 4096; i += 256) Z[i] = make_float2(base[i], 0.f);
    __syncthreads();
    // forward DIF (natural in -> bit-reversed out)
    for (int s = 12; s >= 1; --s) {
        int hh = 1 << (s - 1);
        int str = 12 - s;
        for (int q = t; q < 2048; q += 256) {
            int j = q & (hh - 1);
            int i0 = ((q >> (s - 1)) << s) + j;
            int i1 = i0 + hh;
            float2 u = Z[i0], v = Z[i1];
            float sr = u.x - v.x, si = u.y - v.y;
            Z[i0] = make_float2(u.x + v.x, u.y + v.y);
            float2 w = TW[j << str];
            Z[i1] = make_float2(sr * w.x - si * w.y, sr * w.y + si * w.x);
        }
        __syncthreads();
    }
    // gate * modrelu at natural freq f (stored at bit-reversed position), Hermitian extension
    for (int f = t; f < NFREQ; f += 256) {
        int p = __brev((unsigned)f) >> 20;
        float2 v = Z[p];
        float gr = gre[(size_t)bh * NFREQ + f];
        float gi = gim[(size_t)bh * NFREQ + f];
        float yr = v.x * gr - v.y * gi;
        float yi = v.x * gi + v.y * gr;
        float mag = sqrtf(yr * yr + yi * yi);
        float tb = mag + mrb[(size_t)h * NFMAX + f];
        tb = tb > 0.f ? tb : 0.f;
        float sc = tb / (mag + 1e-6f);
        yr *= sc; yi *= sc;
        Z[p] = make_float2(yr, yi);
        if (f >= 1 && f <= 2047) {
            int p2 = __brev((unsigned)(4096 - f)) >> 20;
            Z[p2] = make_float2(yr, -yi);
        }
    }
    __syncthreads();
    // inverse DIT (bit-reversed in -> natural out), conj twiddles, 1/N at end
    for (int s = 1; s <= 12; ++s) {
        int hh = 1 << (s - 1);
        int str = 12 - s;
        for (int q = t; q < 2048; q += 256) {
            int j = q & (hh - 1);
            int i0 = ((q >> (s - 1)) << s) + j;
            int i1 = i0 + hh;
            float2 w = TW[j << str];
            float2 v = Z[i1];
            float tr = v.x * w.x + v.y * w.y;
            float ti = v.y * w.x - v.x * w.y;
            float2 u = Z[i0];
            Z[i0] = make_float2(u.x + tr, u.y + ti);
            Z[i1] = make_float2(u.x - tr, u.y - ti);
        }
        __syncthreads();
    }
    float scale = (1.0f / 4096.0f) * gwp1[bh * 64 + dh];
    for (int i = t; i < 4096; i += 256) base[i] = Z[i].x * scale;
}

// ---------------- out GEMM: out[b][l][e2] = sum_e yt[b][e][l] * Wo[e2][e] ----------------
__global__ __launch_bounds__(256) void k_ogemm(const float* __restrict__ yt, const float* __restrict__ Wo,
                                               float* __restrict__ out) {
    __shared__ float as[32][68];   // [e_k][l]
    __shared__ float bs[32][68];   // [e_k][e2]
    int e20 = blockIdx.x * 64;
    int l0 = blockIdx.y * 64;
    int b = blockIdx.z;
    int t = threadIdx.x;
    int tx = t & 15, ty = t >> 4;
    float acc[4][4] = {{0.f}};
    int ac = t >> 3;           // 0..31 (k of A)
    int ar = (t & 7) * 8;      // 0..56 (l)
    int brow = t >> 2;         // 0..63 (e2)
    int bcol = (t & 3) * 8;    // 0..24 (k)
    for (int k0 = 0; k0 < DDIM; k0 += 32) {
        float4 a0 = *(const float4*)(yt + ((size_t)b * DDIM + k0 + ac) * LSEQ + l0 + ar);
        float4 a1 = *(const float4*)(yt + ((size_t)b * DDIM + k0 + ac) * LSEQ + l0 + ar + 4);
        *(float4*)&as[ac][ar] = a0;
        *(float4*)&as[ac][ar + 4] = a1;
        float4 c0 = *(const float4*)(Wo + (size_t)(e20 + brow) * DDIM + k0 + bcol);
        float4 c1 = *(const float4*)(Wo + (size_t)(e20 + brow) * DDIM + k0 + bcol + 4);
        bs[bcol + 0][brow] = c0.x; bs[bcol + 1][brow] = c0.y; bs[bcol + 2][brow] = c0.z; bs[bcol + 3][brow] = c0.w;
        bs[bcol + 4][brow] = c1.x; bs[bcol + 5][brow] = c1.y; bs[bcol + 6][brow] = c1.z; bs[bcol + 7][brow] = c1.w;
        __syncthreads();
#pragma unroll
        for (int k = 0; k < 32; ++k) {
            float4 av = *(const float4*)&as[k][ty * 4];
            float4 bv = *(const float4*)&bs[k][tx * 4];
            acc[0][0] += av.x * bv.x; acc[0][1] += av.x * bv.y; acc[0][2] += av.x * bv.z; acc[0][3] += av.x * bv.w;
            acc[1][0] += av.y * bv.x; acc[1][1] += av.y * bv.y; acc[1][2] += av.y * bv.z; acc[1][3] += av.y * bv.w;
            acc[2][0] += av.z * bv.x; acc[2][1] += av.z * bv.y; acc[2][2] += av.z * bv.z; acc[2][3] += av.z * bv.w;
            acc[3][0] += av.w * bv.x; acc[3][1] += av.w * bv.y; acc[3][2] += av.w * bv.z; acc[3][3] += av.w * bv.w;
        }
        __syncthreads();
    }
#pragma unroll
    for (int i = 0; i < 4; ++i) {
        float4 r = make_float4(acc[i][0], acc[i][1], acc[i][2], acc[i][3]);
        *(float4*)(out + ((size_t)b * LSEQ + l0 + ty * 4 + i) * DDIM + e20 + tx * 4) = r;
    }
}

extern "C" void kernel_launch(void* const* d_in, const int* in_sizes, int n_in,
                              void* d_out, int out_size, void* d_ws, size_t ws_size,
                              hipStream_t stream) {
    const float* x      = (const float*)d_in[0];
    const float* Wq     = (const float*)d_in[1];
    const float* Wv     = (const float*)d_in[2];
    const float* Wo     = (const float*)d_in[3];
    const float* ln_g_s = (const float*)d_in[4];
    const float* ln_g_b = (const float*)d_in[5];
    const float* W1     = (const float*)d_in[6];
    const float* b1     = (const float*)d_in[7];
    const float* W2     = (const float*)d_in[8];
    const float* b2     = (const float*)d_in[9];
    const float* mrb    = (const float*)d_in[10];
    const float* ln_w_s = (const float*)d_in[11];
    const float* ln_w_b = (const float*)d_in[12];
    const float* Ww1    = (const float*)d_in[13];
    const float* bw1    = (const float*)d_in[14];
    const float* Ww2    = (const float*)d_in[15];
    const float* bw2    = (const float*)d_in[16];
    float* out = (float*)d_out;

    float* ws   = (float*)d_ws;
    float* vty  = ws;                    // B*D*L = 16777216 (v_t, then y_t in place)
    float* xbp  = vty + 16777216;        // 4*16*1024 = 65536
    float* xbar = xbp + 65536;           // 4096
    float* qbar = xbar + 4096;           // 4096
    float* h1g  = qbar + 4096;           // 64*256 = 16384
    float* gwp1 = h1g + 16384;           // 64*64 = 4096
    float* gre  = gwp1 + 4096;           // 64*2049 = 131136
    float* gim  = gre + 131136;          // 131136

    k_xbar_partial<<<dim3(4, 16, 4), 256, 0, stream>>>(x, xbp);
    k_xbar_reduce<<<dim3(4, 4), 256, 0, stream>>>(xbp, xbar);
    k_qbar<<<256, 256, 0, stream>>>(xbar, Wq, qbar);
    k_mlp<<<64, 256, 0, stream>>>(qbar, ln_g_s, ln_g_b, W1, b1, ln_w_s, ln_w_b,
                                  Ww1, bw1, Ww2, bw2, h1g, gwp1);
    k_gate<<<1025, 256, 0, stream>>>(h1g, W2, b2, gre, gim);
    k_vgemm<<<dim3(16, 64, 4), 256, 0, stream>>>(x, Wv, vty);
    k_fft<<<4096, 256, 0, stream>>>(vty, gre, gim, mrb, gwp1);
    k_ogemm<<<dim3(16, 64, 4), 256, 0, stream>>>(vty, Wo, out);
}

// Round 2
// 394.951 us; speedup vs baseline: 3.0290x; 3.0290x over previous
//
#include <hip/hip_runtime.h>
#include <math.h>

#define LSEQ 4096
#define DDIM 1024
#define NB 4
#define NH 16
#define DHD 64
#define NFREQ 2049
#define NFMAX 4097

typedef __bf16 bf16_8 __attribute__((ext_vector_type(8)));
typedef float f32x4 __attribute__((ext_vector_type(4)));

__device__ __forceinline__ float gelu_exact(float v) {
    return 0.5f * v * (1.0f + erff(v * 0.70710678118654752440f));
}

__device__ __forceinline__ void gload16(const void* g, void* l) {
    __builtin_amdgcn_global_load_lds((const __attribute__((address_space(1))) char*)g,
                                     (__attribute__((address_space(3))) char*)l, 16, 0, 0);
}

// ---------------- xbar partial + x -> bf16 cast (single pass over x) ----------------
__global__ __launch_bounds__(256) void k_xbar_partial(const float* __restrict__ x, float* __restrict__ xbp,
                                                      __bf16* __restrict__ xbf) {
    int d = blockIdx.x * 256 + threadIdx.x;
    int chunk = blockIdx.y;
    int b = blockIdx.z;
    size_t base = ((size_t)b * LSEQ + (size_t)chunk * 256) * DDIM + d;
    float acc = 0.f;
    for (int l = 0; l < 256; ++l) {
        float v = x[base + (size_t)l * DDIM];
        acc += v;
        xbf[base + (size_t)l * DDIM] = (__bf16)v;
    }
    xbp[(size_t)(b * 16 + chunk) * DDIM + d] = acc;
}

__global__ __launch_bounds__(256) void k_xbar_reduce(const float* __restrict__ xbp, float* __restrict__ xbar) {
    int d = blockIdx.x * 256 + threadIdx.x;
    int b = blockIdx.y;
    float acc = 0.f;
    for (int c = 0; c < 16; ++c) acc += xbp[(size_t)(b * 16 + c) * DDIM + d];
    xbar[b * DDIM + d] = acc * (1.0f / LSEQ);
}

// ---------------- weight fp32 -> bf16 ----------------
__global__ __launch_bounds__(256) void k_cvt(const float* __restrict__ s, __bf16* __restrict__ d, int n) {
    int i = (blockIdx.x * 256 + threadIdx.x) * 4;
    if (i < n) {
        float4 v = *(const float4*)(s + i);
        d[i] = (__bf16)v.x; d[i + 1] = (__bf16)v.y; d[i + 2] = (__bf16)v.z; d[i + 3] = (__bf16)v.w;
    }
}

// ---------------- q_bar = xbar @ Wq^T ----------------
__global__ __launch_bounds__(256) void k_qbar(const float* __restrict__ xbar, const float* __restrict__ Wq,
                                              float* __restrict__ qbar) {
    int lane = threadIdx.x & 63;
    int e = blockIdx.x * 4 + (threadIdx.x >> 6);
    const float* wrow = Wq + (size_t)e * DDIM;
    float a0 = 0, a1 = 0, a2 = 0, a3 = 0;
    for (int i = 0; i < 16; ++i) {
        int d = lane + i * 64;
        float w = wrow[d];
        a0 += w * xbar[d];
        a1 += w * xbar[DDIM + d];
        a2 += w * xbar[2 * DDIM + d];
        a3 += w * xbar[3 * DDIM + d];
    }
    for (int off = 32; off > 0; off >>= 1) {
        a0 += __shfl_down(a0, off);
        a1 += __shfl_down(a1, off);
        a2 += __shfl_down(a2, off);
        a3 += __shfl_down(a3, off);
    }
    if (lane == 0) {
        qbar[e] = a0;
        qbar[DDIM + e] = a1;
        qbar[2 * DDIM + e] = a2;
        qbar[3 * DDIM + e] = a3;
    }
}

// ---------------- per-(b,h) MLPs ----------------
__global__ __launch_bounds__(256) void k_mlp(const float* __restrict__ qbar,
                                             const float* __restrict__ ln_g_s, const float* __restrict__ ln_g_b,
                                             const float* __restrict__ W1, const float* __restrict__ b1,
                                             const float* __restrict__ ln_w_s, const float* __restrict__ ln_w_b,
                                             const float* __restrict__ Ww1, const float* __restrict__ bw1,
                                             const float* __restrict__ Ww2, const float* __restrict__ bw2,
                                             float* __restrict__ h1g, float* __restrict__ gwp1) {
    int bh = blockIdx.x;
    __shared__ float q[64], hg[64], hw[64], g1[64];
    __shared__ float sm, sv;
    int t = threadIdx.x;
    if (t < 64) q[t] = qbar[bh * 64 + t];
    __syncthreads();
    if (t == 0) {
        float m = 0;
        for (int i = 0; i < 64; ++i) m += q[i];
        m *= (1.0f / 64.0f);
        float v = 0;
        for (int i = 0; i < 64; ++i) { float dd = q[i] - m; v += dd * dd; }
        v *= (1.0f / 64.0f);
        sm = m; sv = v;
    }
    __syncthreads();
    if (t < 64) {
        float n = (q[t] - sm) * rsqrtf(sv + 1e-5f);
        hg[t] = n * ln_g_s[t] + ln_g_b[t];
        hw[t] = n * ln_w_s[t] + ln_w_b[t];
    }
    __syncthreads();
    {
        int f = t;
        const float* w = W1 + (size_t)f * 64;
        float s = b1[f];
        for (int d0 = 0; d0 < 64; ++d0) s += hg[d0] * w[d0];
        h1g[(size_t)bh * 256 + f] = gelu_exact(s);
    }
    if (t < 64) {
        const float* w = Ww1 + (size_t)t * 64;
        float s = bw1[t];
        for (int k = 0; k < 64; ++k) s += hw[k] * w[k];
        g1[t] = gelu_exact(s);
    }
    __syncthreads();
    if (t < 64) {
        const float* w = Ww2 + (size_t)t * 64;
        float s = bw2[t];
        for (int k = 0; k < 64; ++k) s += g1[k] * w[k];
        gwp1[bh * 64 + t] = 1.0f + 1.0f / (1.0f + expf(-s));
    }
}

// ---------------- gate rows ----------------
__global__ __launch_bounds__(256) void k_gate(const float* __restrict__ h1g, const float* __restrict__ W2,
                                              const float* __restrict__ b2,
                                              float* __restrict__ gre, float* __restrict__ gim) {
    int task = blockIdx.x * 4 + (threadIdx.x >> 6);
    if (task >= 2 * NFREQ) return;
    int lane = threadIdx.x & 63;
    int part = task >= NFREQ;
    int f = task - part * NFREQ;
    int row = part ? (NFMAX + f) : f;
    const float* w = W2 + (size_t)row * 256;
    float w0 = w[lane], w1 = w[64 + lane], w2 = w[128 + lane], w3 = w[192 + lane];
    float bias = b2[row];
    float* dst = part ? gim : gre;
    for (int bh = 0; bh < 64; ++bh) {
        const float* hr = h1g + (size_t)bh * 256;
        float p = w0 * hr[lane] + w1 * hr[64 + lane] + w2 * hr[128 + lane] + w3 * hr[192 + lane];
        for (int off = 32; off > 0; off >>= 1) p += __shfl_down(p, off);
        if (lane == 0) dst[(size_t)bh * NFREQ + f] = p + bias;
    }
}

// ---------------- bf16 MFMA GEMM core: C[128x128] = A[m0..][K] * B[n0..][K]^T ----------------
__device__ __forceinline__ void gemm_core(const __bf16* __restrict__ A, const __bf16* __restrict__ B,
                                          int m0, int n0, __bf16* As, __bf16* Bs, f32x4 (&acc)[4][4]) {
    int t = threadIdx.x;
    int lane = t & 63, w = t >> 6;
    int lrow = lane & 15, lk = (lane >> 4) * 8;
    int wm = (w >> 1) * 64, wn = (w & 1) * 64;
#pragma unroll
    for (int mi = 0; mi < 4; ++mi)
#pragma unroll
        for (int ni = 0; ni < 4; ++ni) acc[mi][ni] = (f32x4){0.f, 0.f, 0.f, 0.f};
    for (int k0 = 0; k0 < 1024; k0 += 32) {
#pragma unroll
        for (int i = 0; i < 2; ++i) {
            int r = w * 32 + i * 16 + (lane >> 2);
            int kc = k0 + (lane & 3) * 8;
            gload16(A + ((size_t)(m0 + r) << 10) + kc, &As[(w * 32 + i * 16) * 32]);
            gload16(B + ((size_t)(n0 + r) << 10) + kc, &Bs[(w * 32 + i * 16) * 32]);
        }
        __syncthreads();
        bf16_8 af[4], bfr[4];
#pragma unroll
        for (int mi = 0; mi < 4; ++mi) af[mi] = *(const bf16_8*)&As[(wm + mi * 16 + lrow) * 32 + lk];
#pragma unroll
        for (int ni = 0; ni < 4; ++ni) bfr[ni] = *(const bf16_8*)&Bs[(wn + ni * 16 + lrow) * 32 + lk];
#pragma unroll
        for (int mi = 0; mi < 4; ++mi)
#pragma unroll
            for (int ni = 0; ni < 4; ++ni)
                acc[mi][ni] = __builtin_amdgcn_mfma_f32_16x16x32_bf16(af[mi], bfr[ni], acc[mi][ni], 0, 0, 0);
        __syncthreads();
    }
}

// vgemm: vt[b][e][l] (bf16) = (x @ Wv^T)^T  — transposed bf16 epilogue via per-wave LDS staging
__global__ __launch_bounds__(256) void k_vgemm(const __bf16* __restrict__ xbf, const __bf16* __restrict__ Wvb,
                                               __bf16* __restrict__ vt) {
    __shared__ __align__(16) __bf16 As[128 * 32];
    __shared__ __align__(16) __bf16 Bs[128 * 32];
    __shared__ float st[4][16][66];
    int n0 = blockIdx.x * 128, m0 = blockIdx.y * 128, b = blockIdx.z;
    f32x4 acc[4][4];
    gemm_core(xbf + ((size_t)b << 22), Wvb, m0, n0, As, Bs, acc);
    int t = threadIdx.x;
    int lane = t & 63, w = t >> 6;
    int wm = (w >> 1) * 64, wn = (w & 1) * 64;
    size_t vbase = ((size_t)b << 22);
#pragma unroll
    for (int ni = 0; ni < 4; ++ni) {
#pragma unroll
        for (int mi = 0; mi < 4; ++mi)
#pragma unroll
            for (int r = 0; r < 4; ++r)
                st[w][lane & 15][mi * 16 + (lane >> 4) * 4 + r] = acc[mi][ni][r];
        asm volatile("" ::: "memory");
#pragma unroll
        for (int er = 0; er < 16; ++er) {
            float v = st[w][er][lane];
            vt[vbase + (size_t)(n0 + wn + ni * 16 + er) * LSEQ + m0 + wm + lane] = (__bf16)v;
        }
        asm volatile("" ::: "memory");
    }
}

// ogemm: out[b][l][e2] (fp32) = ybf @ Wo^T
__global__ __launch_bounds__(256) void k_ogemm(const __bf16* __restrict__ ybf, const __bf16* __restrict__ Wob,
                                               float* __restrict__ out) {
    __shared__ __align__(16) __bf16 As[128 * 32];
    __shared__ __align__(16) __bf16 Bs[128 * 32];
    int n0 = blockIdx.x * 128, m0 = blockIdx.y * 128, b = blockIdx.z;
    f32x4 acc[4][4];
    gemm_core(ybf + ((size_t)b << 22), Wob, m0, n0, As, Bs, acc);
    int t = threadIdx.x;
    int lane = t & 63, w = t >> 6;
    int wm = (w >> 1) * 64, wn = (w & 1) * 64;
    float* ob = out + ((size_t)b << 22);
#pragma unroll
    for (int mi = 0; mi < 4; ++mi)
#pragma unroll
        for (int ni = 0; ni < 4; ++ni)
#pragma unroll
            for (int r = 0; r < 4; ++r)
                ob[(size_t)(m0 + wm + mi * 16 + (lane >> 4) * 4 + r) * DDIM + n0 + wn + ni * 16 + (lane & 15)] =
                    acc[mi][ni][r];
}

// ---------------- FFT + gate + modrelu + iFFT + (1+gw), bf16 in/out, in place ----------------
__global__ __launch_bounds__(256) void k_fft(__bf16* __restrict__ vty,
                                             const float* __restrict__ gre, const float* __restrict__ gim,
                                             const float* __restrict__ mrb, const float* __restrict__ gwp1) {
    __shared__ float2 Z[4096];
    __shared__ float2 TW[2048];
    int blk = blockIdx.x;
    int b = blk >> 10, e = blk & 1023;
    int h = e >> 6, dh = e & 63;
    int bh = b * 16 + h;
    __bf16* base = vty + (size_t)blk * 4096;
    int t = threadIdx.x;
    for (int k = t; k < 2048; k += 256) {
        float ang = -6.2831853071795864769f * ((float)k / 4096.0f);
        float s, c;
        __sincosf(ang, &s, &c);
        TW[k] = make_float2(c, s);
    }
    for (int i = t; i < 4096; i += 256) Z[i] = make_float2((float)base[i], 0.f);
    __syncthreads();
    for (int s = 12; s >= 1; --s) {
        int hh = 1 << (s - 1);
        int str = 12 - s;
        for (int q = t; q < 2048; q += 256) {
            int j = q & (hh - 1);
            int i0 = ((q >> (s - 1)) << s) + j;
            int i1 = i0 + hh;
            float2 u = Z[i0], v = Z[i1];
            float sr = u.x - v.x, si = u.y - v.y;
            Z[i0] = make_float2(u.x + v.x, u.y + v.y);
            float2 w = TW[j << str];
            Z[i1] = make_float2(sr * w.x - si * w.y, sr * w.y + si * w.x);
        }
        __syncthreads();
    }
    for (int f = t; f < NFREQ; f += 256) {
        int p = __brev((unsigned)f) >> 20;
        float2 v = Z[p];
        float gr = gre[(size_t)bh * NFREQ + f];
        float gi = gim[(size_t)bh * NFREQ + f];
        float yr = v.x * gr - v.y * gi;
        float yi = v.x * gi + v.y * gr;
        float mag = sqrtf(yr * yr + yi * yi);
        float tb = mag + mrb[(size_t)h * NFMAX + f];
        tb = tb > 0.f ? tb : 0.f;
        float sc = tb / (mag + 1e-6f);
        yr *= sc; yi *= sc;
        Z[p] = make_float2(yr, yi);
        if (f >= 1 && f <= 2047) {
            int p2 = __brev((unsigned)(4096 - f)) >> 20;
            Z[p2] = make_float2(yr, -yi);
        }
    }
    __syncthreads();
    for (int s = 1; s <= 12; ++s) {
        int hh = 1 << (s - 1);
        int str = 12 - s;
        for (int q = t; q < 2048; q += 256) {
            int j = q & (hh - 1);
            int i0 = ((q >> (s - 1)) << s) + j;
            int i1 = i0 + hh;
            float2 w = TW[j << str];
            float2 v = Z[i1];
            float tr = v.x * w.x + v.y * w.y;
            float ti = v.y * w.x - v.x * w.y;
            float2 u = Z[i0];
            Z[i0] = make_float2(u.x + tr, u.y + ti);
            Z[i1] = make_float2(u.x - tr, u.y - ti);
        }
        __syncthreads();
    }
    float scale = (1.0f / 4096.0f) * gwp1[bh * 64 + dh];
    for (int i = t; i < 4096; i += 256) base[i] = (__bf16)(Z[i].x * scale);
}

// ---------------- transpose: vt[b][e][l] bf16 -> ybf[b][l][e] bf16 (64x64 tiles) ----------------
__global__ __launch_bounds__(256) void k_t2(const __bf16* __restrict__ vt, __bf16* __restrict__ ybf) {
    __shared__ __bf16 tl[64][66];
    int e0 = blockIdx.x * 64, l0 = blockIdx.y * 64, b = blockIdx.z;
    int t = threadIdx.x;
    const __bf16* src = vt + ((size_t)b << 22);
    __bf16* dst = ybf + ((size_t)b << 22);
    int er = t >> 3, lc = (t & 7) * 8;
#pragma unroll
    for (int it = 0; it < 2; ++it) {
        int e = er + it * 32;
        bf16_8 v = *(const bf16_8*)&src[(size_t)(e0 + e) * LSEQ + l0 + lc];
#pragma unroll
        for (int j = 0; j < 8; ++j) tl[e][lc + j] = v[j];
    }
    __syncthreads();
    int lr = t >> 3, ec = (t & 7) * 8;
#pragma unroll
    for (int it = 0; it < 2; ++it) {
        int l = lr + it * 32;
        bf16_8 v;
#pragma unroll
        for (int j = 0; j < 8; ++j) v[j] = tl[ec + j][l];
        *(bf16_8*)&dst[(size_t)(l0 + l) * DDIM + e0 + ec] = v;
    }
}

extern "C" void kernel_launch(void* const* d_in, const int* in_sizes, int n_in,
                              void* d_out, int out_size, void* d_ws, size_t ws_size,
                              hipStream_t stream) {
    const float* x      = (const float*)d_in[0];
    const float* Wq     = (const float*)d_in[1];
    const float* Wv     = (const float*)d_in[2];
    const float* Wo     = (const float*)d_in[3];
    const float* ln_g_s = (const float*)d_in[4];
    const float* ln_g_b = (const float*)d_in[5];
    const float* W1     = (const float*)d_in[6];
    const float* b1     = (const float*)d_in[7];
    const float* W2     = (const float*)d_in[8];
    const float* b2     = (const float*)d_in[9];
    const float* mrb    = (const float*)d_in[10];
    const float* ln_w_s = (const float*)d_in[11];
    const float* ln_w_b = (const float*)d_in[12];
    const float* Ww1    = (const float*)d_in[13];
    const float* bw1    = (const float*)d_in[14];
    const float* Ww2    = (const float*)d_in[15];
    const float* bw2    = (const float*)d_in[16];
    float* out = (float*)d_out;

    char* W = (char*)d_ws;
    __bf16* xbf = (__bf16*)W;                       // 33,554,432 B (later aliased as ybf)
    __bf16* ybf = xbf;
    __bf16* Wvb = (__bf16*)(W + 33554432);          // 2 MB
    __bf16* Wob = (__bf16*)(W + 35651584);          // 2 MB
    float*  xbp = (float*)(W + 37748736);           // 65536 f
    float*  xbar= (float*)(W + 38010880);           // 4096 f
    float*  qbar= (float*)(W + 38027264);           // 4096 f
    float*  h1g = (float*)(W + 38043648);           // 16384 f
    float*  gwp1= (float*)(W + 38109184);           // 4096 f
    float*  gre = (float*)(W + 38125568);           // 131136 f
    float*  gim = (float*)(W + 38650112);           // 131136 f

    __bf16* vt = (__bf16*)d_out;                    // scratch inside d_out (33.5 MB of 67 MB)

    k_xbar_partial<<<dim3(4, 16, 4), 256, 0, stream>>>(x, xbp, xbf);
    k_cvt<<<1024, 256, 0, stream>>>(Wv, Wvb, DDIM * DDIM);
    k_cvt<<<1024, 256, 0, stream>>>(Wo, Wob, DDIM * DDIM);
    k_xbar_reduce<<<dim3(4, 4), 256, 0, stream>>>(xbp, xbar);
    k_qbar<<<256, 256, 0, stream>>>(xbar, Wq, qbar);
    k_mlp<<<64, 256, 0, stream>>>(qbar, ln_g_s, ln_g_b, W1, b1, ln_w_s, ln_w_b,
                                  Ww1, bw1, Ww2, bw2, h1g, gwp1);
    k_gate<<<1025, 256, 0, stream>>>(h1g, W2, b2, gre, gim);
    k_vgemm<<<dim3(8, 32, 4), 256, 0, stream>>>(xbf, Wvb, vt);
    k_fft<<<4096, 256, 0, stream>>>(vt, gre, gim, mrb, gwp1);
    k_t2<<<dim3(16, 64, 4), 256, 0, stream>>>(vt, ybf);
    k_ogemm<<<dim3(8, 32, 4), 256, 0, stream>>>(ybf, Wob, out);
}

// Round 3
// 263.753 us; speedup vs baseline: 4.5357x; 1.4974x over previous
//
#include <hip/hip_runtime.h>
#include <math.h>

#define LSEQ 4096
#define DDIM 1024
#define NB 4
#define NH 16
#define DHD 64
#define NFREQ 2049
#define NFMAX 4097

typedef __bf16 bf16_8 __attribute__((ext_vector_type(8)));
typedef float f32x4 __attribute__((ext_vector_type(4)));
typedef unsigned short u16x8 __attribute__((ext_vector_type(8)));

__device__ __forceinline__ float gelu_exact(float v) {
    return 0.5f * v * (1.0f + erff(v * 0.70710678118654752440f));
}

__device__ __forceinline__ void gload16(const void* g, void* l) {
    __builtin_amdgcn_global_load_lds((const __attribute__((address_space(1))) char*)g,
                                     (__attribute__((address_space(3))) char*)l, 16, 0, 0);
}

// ---------------- xbar partial + x -> bf16 cast (single pass over x) ----------------
__global__ __launch_bounds__(256) void k_xbar_partial(const float* __restrict__ x, float* __restrict__ xbp,
                                                      __bf16* __restrict__ xbf) {
    int d = blockIdx.x * 256 + threadIdx.x;
    int chunk = blockIdx.y;
    int b = blockIdx.z;
    size_t base = ((size_t)b * LSEQ + (size_t)chunk * 256) * DDIM + d;
    float acc = 0.f;
    for (int l = 0; l < 256; ++l) {
        float v = x[base + (size_t)l * DDIM];
        acc += v;
        xbf[base + (size_t)l * DDIM] = (__bf16)v;
    }
    xbp[(size_t)(b * 16 + chunk) * DDIM + d] = acc;
}

__global__ __launch_bounds__(256) void k_xbar_reduce(const float* __restrict__ xbp, float* __restrict__ xbar) {
    int d = blockIdx.x * 256 + threadIdx.x;
    int b = blockIdx.y;
    float acc = 0.f;
    for (int c = 0; c < 16; ++c) acc += xbp[(size_t)(b * 16 + c) * DDIM + d];
    xbar[b * DDIM + d] = acc * (1.0f / LSEQ);
}

// ---------------- weight fp32 -> bf16 ----------------
__global__ __launch_bounds__(256) void k_cvt(const float* __restrict__ s, __bf16* __restrict__ d, int n) {
    int i = (blockIdx.x * 256 + threadIdx.x) * 4;
    if (i < n) {
        float4 v = *(const float4*)(s + i);
        d[i] = (__bf16)v.x; d[i + 1] = (__bf16)v.y; d[i + 2] = (__bf16)v.z; d[i + 3] = (__bf16)v.w;
    }
}

// ---------------- q_bar = xbar @ Wq^T ----------------
__global__ __launch_bounds__(256) void k_qbar(const float* __restrict__ xbar, const float* __restrict__ Wq,
                                              float* __restrict__ qbar) {
    int lane = threadIdx.x & 63;
    int e = blockIdx.x * 4 + (threadIdx.x >> 6);
    const float* wrow = Wq + (size_t)e * DDIM;
    float a0 = 0, a1 = 0, a2 = 0, a3 = 0;
    for (int i = 0; i < 16; ++i) {
        int d = lane + i * 64;
        float w = wrow[d];
        a0 += w * xbar[d];
        a1 += w * xbar[DDIM + d];
        a2 += w * xbar[2 * DDIM + d];
        a3 += w * xbar[3 * DDIM + d];
    }
    for (int off = 32; off > 0; off >>= 1) {
        a0 += __shfl_down(a0, off);
        a1 += __shfl_down(a1, off);
        a2 += __shfl_down(a2, off);
        a3 += __shfl_down(a3, off);
    }
    if (lane == 0) {
        qbar[e] = a0;
        qbar[DDIM + e] = a1;
        qbar[2 * DDIM + e] = a2;
        qbar[3 * DDIM + e] = a3;
    }
}

// ---------------- per-(b,h) MLPs ----------------
__global__ __launch_bounds__(256) void k_mlp(const float* __restrict__ qbar,
                                             const float* __restrict__ ln_g_s, const float* __restrict__ ln_g_b,
                                             const float* __restrict__ W1, const float* __restrict__ b1,
                                             const float* __restrict__ ln_w_s, const float* __restrict__ ln_w_b,
                                             const float* __restrict__ Ww1, const float* __restrict__ bw1,
                                             const float* __restrict__ Ww2, const float* __restrict__ bw2,
                                             float* __restrict__ h1g, float* __restrict__ gwp1) {
    int bh = blockIdx.x;
    __shared__ float q[64], hg[64], hw[64], g1[64];
    __shared__ float sm, sv;
    int t = threadIdx.x;
    if (t < 64) q[t] = qbar[bh * 64 + t];
    __syncthreads();
    if (t == 0) {
        float m = 0;
        for (int i = 0; i < 64; ++i) m += q[i];
        m *= (1.0f / 64.0f);
        float v = 0;
        for (int i = 0; i < 64; ++i) { float dd = q[i] - m; v += dd * dd; }
        v *= (1.0f / 64.0f);
        sm = m; sv = v;
    }
    __syncthreads();
    if (t < 64) {
        float n = (q[t] - sm) * rsqrtf(sv + 1e-5f);
        hg[t] = n * ln_g_s[t] + ln_g_b[t];
        hw[t] = n * ln_w_s[t] + ln_w_b[t];
    }
    __syncthreads();
    {
        int f = t;
        const float* w = W1 + (size_t)f * 64;
        float s = b1[f];
        for (int d0 = 0; d0 < 64; ++d0) s += hg[d0] * w[d0];
        h1g[(size_t)bh * 256 + f] = gelu_exact(s);
    }
    if (t < 64) {
        const float* w = Ww1 + (size_t)t * 64;
        float s = bw1[t];
        for (int k = 0; k < 64; ++k) s += hw[k] * w[k];
        g1[t] = gelu_exact(s);
    }
    __syncthreads();
    if (t < 64) {
        const float* w = Ww2 + (size_t)t * 64;
        float s = bw2[t];
        for (int k = 0; k < 64; ++k) s += g1[k] * w[k];
        gwp1[bh * 64 + t] = 1.0f + 1.0f / (1.0f + expf(-s));
    }
}

// ---------------- gate rows ----------------
__global__ __launch_bounds__(256) void k_gate(const float* __restrict__ h1g, const float* __restrict__ W2,
                                              const float* __restrict__ b2,
                                              float* __restrict__ gre, float* __restrict__ gim) {
    int task = blockIdx.x * 4 + (threadIdx.x >> 6);
    if (task >= 2 * NFREQ) return;
    int lane = threadIdx.x & 63;
    int part = task >= NFREQ;
    int f = task - part * NFREQ;
    int row = part ? (NFMAX + f) : f;
    const float* w = W2 + (size_t)row * 256;
    float w0 = w[lane], w1 = w[64 + lane], w2 = w[128 + lane], w3 = w[192 + lane];
    float bias = b2[row];
    float* dst = part ? gim : gre;
    for (int bh = 0; bh < 64; ++bh) {
        const float* hr = h1g + (size_t)bh * 256;
        float p = w0 * hr[lane] + w1 * hr[64 + lane] + w2 * hr[128 + lane] + w3 * hr[192 + lane];
        for (int off = 32; off > 0; off >>= 1) p += __shfl_down(p, off);
        if (lane == 0) dst[(size_t)bh * NFREQ + f] = p + bias;
    }
}

// ---------------- bf16 MFMA GEMM core ----------------
__device__ __forceinline__ void gemm_core(const __bf16* __restrict__ A, const __bf16* __restrict__ B,
                                          int m0, int n0, __bf16* As, __bf16* Bs, f32x4 (&acc)[4][4]) {
    int t = threadIdx.x;
    int lane = t & 63, w = t >> 6;
    int lrow = lane & 15, lk = (lane >> 4) * 8;
    int wm = (w >> 1) * 64, wn = (w & 1) * 64;
#pragma unroll
    for (int mi = 0; mi < 4; ++mi)
#pragma unroll
        for (int ni = 0; ni < 4; ++ni) acc[mi][ni] = (f32x4){0.f, 0.f, 0.f, 0.f};
    for (int k0 = 0; k0 < 1024; k0 += 32) {
#pragma unroll
        for (int i = 0; i < 2; ++i) {
            int r = w * 32 + i * 16 + (lane >> 2);
            int kc = k0 + (lane & 3) * 8;
            gload16(A + ((size_t)(m0 + r) << 10) + kc, &As[(w * 32 + i * 16) * 32]);
            gload16(B + ((size_t)(n0 + r) << 10) + kc, &Bs[(w * 32 + i * 16) * 32]);
        }
        __syncthreads();
        bf16_8 af[4], bfr[4];
#pragma unroll
        for (int mi = 0; mi < 4; ++mi) af[mi] = *(const bf16_8*)&As[(wm + mi * 16 + lrow) * 32 + lk];
#pragma unroll
        for (int ni = 0; ni < 4; ++ni) bfr[ni] = *(const bf16_8*)&Bs[(wn + ni * 16 + lrow) * 32 + lk];
#pragma unroll
        for (int mi = 0; mi < 4; ++mi)
#pragma unroll
            for (int ni = 0; ni < 4; ++ni)
                acc[mi][ni] = __builtin_amdgcn_mfma_f32_16x16x32_bf16(af[mi], bfr[ni], acc[mi][ni], 0, 0, 0);
        __syncthreads();
    }
}

// vgemm: vt[b][e][l] (bf16) = (x @ Wv^T)^T
__global__ __launch_bounds__(256) void k_vgemm(const __bf16* __restrict__ xbf, const __bf16* __restrict__ Wvb,
                                               __bf16* __restrict__ vt) {
    __shared__ __align__(16) __bf16 As[128 * 32];
    __shared__ __align__(16) __bf16 Bs[128 * 32];
    __shared__ float st[4][16][66];
    int n0 = blockIdx.x * 128, m0 = blockIdx.y * 128, b = blockIdx.z;
    f32x4 acc[4][4];
    gemm_core(xbf + ((size_t)b << 22), Wvb, m0, n0, As, Bs, acc);
    int t = threadIdx.x;
    int lane = t & 63, w = t >> 6;
    int wm = (w >> 1) * 64, wn = (w & 1) * 64;
    size_t vbase = ((size_t)b << 22);
#pragma unroll
    for (int ni = 0; ni < 4; ++ni) {
#pragma unroll
        for (int mi = 0; mi < 4; ++mi)
#pragma unroll
            for (int r = 0; r < 4; ++r)
                st[w][lane & 15][mi * 16 + (lane >> 4) * 4 + r] = acc[mi][ni][r];
        asm volatile("" ::: "memory");
#pragma unroll
        for (int er = 0; er < 16; ++er) {
            float v = st[w][er][lane];
            vt[vbase + (size_t)(n0 + wn + ni * 16 + er) * LSEQ + m0 + wm + lane] = (__bf16)v;
        }
        asm volatile("" ::: "memory");
    }
}

// ogemm: out[b][l][e2] (fp32) = ybf @ Wo^T
__global__ __launch_bounds__(256) void k_ogemm(const __bf16* __restrict__ ybf, const __bf16* __restrict__ Wob,
                                               float* __restrict__ out) {
    __shared__ __align__(16) __bf16 As[128 * 32];
    __shared__ __align__(16) __bf16 Bs[128 * 32];
    int n0 = blockIdx.x * 128, m0 = blockIdx.y * 128, b = blockIdx.z;
    f32x4 acc[4][4];
    gemm_core(ybf + ((size_t)b << 22), Wob, m0, n0, As, Bs, acc);
    int t = threadIdx.x;
    int lane = t & 63, w = t >> 6;
    int wm = (w >> 1) * 64, wn = (w & 1) * 64;
    float* ob = out + ((size_t)b << 22);
#pragma unroll
    for (int mi = 0; mi < 4; ++mi)
#pragma unroll
        for (int ni = 0; ni < 4; ++ni)
#pragma unroll
            for (int r = 0; r < 4; ++r)
                ob[(size_t)(m0 + wm + mi * 16 + (lane >> 4) * 4 + r) * DDIM + n0 + wn + ni * 16 + (lane & 15)] =
                    acc[mi][ni][r];
}

// ================= register-blocked radix-16 FFT, 2 real channels per block =================
__device__ __forceinline__ float2 cmul(float2 a, float2 b) {
    return make_float2(a.x * b.x - a.y * b.y, a.x * b.y + a.y * b.x);
}
__device__ __forceinline__ int PAD(int i) { return i + (i >> 4) + (i >> 8); }
__device__ __forceinline__ int UPAD(int i) { return i + ((i >> 6) << 3); }
__device__ __forceinline__ int DR(int k) { return ((k & 15) << 8) | (k & 0xF0) | (k >> 8); }

template <int S>  // S=1: fwd (e^{-i}), S=-1: inverse (conj)
__device__ __forceinline__ void dft16(float2* x) {
    const float C1 = 0.9238795325112867f, SS = 0.3826834323650898f, R2 = 0.7071067811865476f;
    const float sg = (S == 1) ? -1.f : 1.f;
    float2 a[16];
#pragma unroll
    for (int n0 = 0; n0 < 4; ++n0) {
        float2 x0 = x[n0], x1 = x[n0 + 4], x2 = x[n0 + 8], x3 = x[n0 + 12];
        float e0x = x0.x + x2.x, e0y = x0.y + x2.y;
        float e1x = x0.x - x2.x, e1y = x0.y - x2.y;
        float o0x = x1.x + x3.x, o0y = x1.y + x3.y;
        float o1x = x1.x - x3.x, o1y = x1.y - x3.y;
        a[n0 * 4 + 0] = make_float2(e0x + o0x, e0y + o0y);
        a[n0 * 4 + 2] = make_float2(e0x - o0x, e0y - o0y);
        float ix = (S == 1) ? o1y : -o1y;
        float iy = (S == 1) ? -o1x : o1x;
        a[n0 * 4 + 1] = make_float2(e1x + ix, e1y + iy);
        a[n0 * 4 + 3] = make_float2(e1x - ix, e1y - iy);
    }
    const float2 w1 = make_float2(C1, sg * SS);
    const float2 w2 = make_float2(R2, sg * R2);
    const float2 w3 = make_float2(SS, sg * C1);
    const float2 w6 = make_float2(-R2, sg * R2);
    const float2 w9 = make_float2(-C1, -sg * SS);
    a[5] = cmul(a[5], w1);
    a[6] = cmul(a[6], w2);
    a[7] = cmul(a[7], w3);
    a[9] = cmul(a[9], w2);
    { float2 v = a[10]; a[10] = (S == 1) ? make_float2(v.y, -v.x) : make_float2(-v.y, v.x); }
    a[11] = cmul(a[11], w6);
    a[13] = cmul(a[13], w3);
    a[14] = cmul(a[14], w6);
    a[15] = cmul(a[15], w9);
#pragma unroll
    for (int k0 = 0; k0 < 4; ++k0) {
        float2 x0 = a[k0], x1 = a[4 + k0], x2 = a[8 + k0], x3 = a[12 + k0];
        float e0x = x0.x + x2.x, e0y = x0.y + x2.y;
        float e1x = x0.x - x2.x, e1y = x0.y - x2.y;
        float o0x = x1.x + x3.x, o0y = x1.y + x3.y;
        float o1x = x1.x - x3.x, o1y = x1.y - x3.y;
        x[k0] = make_float2(e0x + o0x, e0y + o0y);
        x[k0 + 8] = make_float2(e0x - o0x, e0y - o0y);
        float ix = (S == 1) ? o1y : -o1y;
        float iy = (S == 1) ? -o1x : o1x;
        x[k0 + 4] = make_float2(e1x + ix, e1y + iy);
        x[k0 + 12] = make_float2(e1x - ix, e1y - iy);
    }
}

template <int S>
__device__ __forceinline__ void twiddle_chain(float2* x, int j, float invN) {
    float ang = ((S == 1) ? -6.283185307179586f : 6.283185307179586f) * ((float)j * invN);
    float sn, cs;
    __sincosf(ang, &sn, &cs);
    float2 w = make_float2(cs, sn), wp = w;
#pragma unroll
    for (int r = 1; r < 16; ++r) {
        x[r] = cmul(x[r], wp);
        wp = cmul(wp, w);
    }
}

__global__ __launch_bounds__(256, 4) void k_fft(__bf16* __restrict__ vty,
                                                const float* __restrict__ gre, const float* __restrict__ gim,
                                                const float* __restrict__ mrb, const float* __restrict__ gwp1) {
    __shared__ float2 Zp[4366];
    unsigned int* S32 = (unsigned int*)Zp;
    int pid = blockIdx.x;
    int b = pid >> 9, ep = pid & 511;
    int e = ep * 2;
    int h = e >> 6, dh = e & 63;
    int bh = b * 16 + h;
    size_t gbase = (size_t)bh * NFREQ;
    size_t mbase = (size_t)h * NFMAX;
    __bf16* row1 = vty + ((size_t)b << 22) + ((size_t)e << 12);
    __bf16* row2 = row1 + 4096;
    int t = threadIdx.x;

    // ---- load: Z[i] = (v1[i], v2[i]) ----
#pragma unroll
    for (int cc = 0; cc < 2; ++cc) {
        int c = t + cc * 256;
        bf16_8 a = *(const bf16_8*)&row1[c * 8];
        bf16_8 bb = *(const bf16_8*)&row2[c * 8];
#pragma unroll
        for (int m = 0; m < 8; ++m)
            Zp[PAD(c * 8 + m)] = make_float2((float)a[m], (float)bb[m]);
    }
    __syncthreads();

    float2 x[16];
    // ---- fwd stage 1 (D=256) ----
    {
        int j = t;
#pragma unroll
        for (int r = 0; r < 16; ++r) x[r] = Zp[PAD(r * 256 + j)];
        dft16<1>(x);
        twiddle_chain<1>(x, j, 1.0f / 4096.0f);
#pragma unroll
        for (int r = 0; r < 16; ++r) Zp[PAD(r * 256 + j)] = x[r];
    }
    __syncthreads();
    // ---- fwd stage 2 (D=16) ----
    {
        int g = t >> 4, j = t & 15, base = g * 256 + j;
#pragma unroll
        for (int r = 0; r < 16; ++r) x[r] = Zp[PAD(base + r * 16)];
        dft16<1>(x);
        twiddle_chain<1>(x, j, 1.0f / 256.0f);
#pragma unroll
        for (int r = 0; r < 16; ++r) Zp[PAD(base + r * 16)] = x[r];
    }
    __syncthreads();
    // ---- fwd stage 3 (D=1) ----
    {
        int base = t * 16;
#pragma unroll
        for (int r = 0; r < 16; ++r) x[r] = Zp[PAD(base + r)];
        dft16<1>(x);
#pragma unroll
        for (int r = 0; r < 16; ++r) Zp[PAD(base + r)] = x[r];
    }
    __syncthreads();
    // ---- gate + modrelu (in digit-reversed storage; in-place per thread) ----
#pragma unroll
    for (int r = 0; r < 8; ++r) {
        int k = (r << 8) + t;
        int sA = DR(k);
        int kB = (4096 - k) & 4095;
        int sB = DR(kB);
        float2 Za = Zp[PAD(sA)];
        float2 Zb = Zp[PAD(sB)];
        float v1r = 0.5f * (Za.x + Zb.x), v1i = 0.5f * (Za.y - Zb.y);
        float v2r = 0.5f * (Za.y + Zb.y), v2i = 0.5f * (Zb.x - Za.x);
        float gr = gre[gbase + k], gi = gim[gbase + k];
        float bia = mrb[mbase + k];
        float y1r = v1r * gr - v1i * gi, y1i = v1r * gi + v1i * gr;
        float m1 = sqrtf(y1r * y1r + y1i * y1i);
        float s1 = fmaxf(m1 + bia, 0.f) / (m1 + 1e-6f);
        y1r *= s1; y1i *= s1;
        float y2r = v2r * gr - v2i * gi, y2i = v2r * gi + v2i * gr;
        float m2 = sqrtf(y2r * y2r + y2i * y2i);
        float s2 = fmaxf(m2 + bia, 0.f) / (m2 + 1e-6f);
        y2r *= s2; y2i *= s2;
        if (k == 0) { y1i = 0.f; y2i = 0.f; }
        Zp[PAD(sA)] = make_float2(y1r - y2i, y1i + y2r);
        if (k) Zp[PAD(sB)] = make_float2(y1r + y2i, y2r - y1i);
    }
    if (t == 0) {  // Nyquist k=2048, slot DR(2048)=8
        float2 Za = Zp[PAD(8)];
        float gr = gre[gbase + 2048], gi = gim[gbase + 2048];
        float bia = mrb[mbase + 2048];
        float y1r = Za.x * gr, y1i = Za.x * gi;
        float m1 = sqrtf(y1r * y1r + y1i * y1i);
        float s1 = fmaxf(m1 + bia, 0.f) / (m1 + 1e-6f);
        float y2r = Za.y * gr, y2i = Za.y * gi;
        float m2 = sqrtf(y2r * y2r + y2i * y2i);
        float s2 = fmaxf(m2 + bia, 0.f) / (m2 + 1e-6f);
        Zp[PAD(8)] = make_float2(y1r * s1, y2r * s2);
    }
    __syncthreads();
    // ---- inv stage 1 (D=1) ----
    {
        int base = t * 16;
#pragma unroll
        for (int r = 0; r < 16; ++r) x[r] = Zp[PAD(base + r)];
        dft16<-1>(x);
#pragma unroll
        for (int r = 0; r < 16; ++r) Zp[PAD(base + r)] = x[r];
    }
    __syncthreads();
    // ---- inv stage 2 (D=16) ----
    {
        int g = t >> 4, j = t & 15, base = g * 256 + j;
#pragma unroll
        for (int r = 0; r < 16; ++r) x[r] = Zp[PAD(base + r * 16)];
        twiddle_chain<-1>(x, j, 1.0f / 256.0f);
        dft16<-1>(x);
#pragma unroll
        for (int r = 0; r < 16; ++r) Zp[PAD(base + r * 16)] = x[r];
    }
    __syncthreads();
    // ---- inv stage 3 (D=256) + scale + pack ----
    {
        int j = t;
#pragma unroll
        for (int r = 0; r < 16; ++r) x[r] = Zp[PAD(r * 256 + j)];
        twiddle_chain<-1>(x, j, 1.0f / 4096.0f);
        dft16<-1>(x);
        float sc1 = gwp1[bh * 64 + dh] * (1.0f / 4096.0f);
        float sc2 = gwp1[bh * 64 + dh + 1] * (1.0f / 4096.0f);
        unsigned int pk[16];
#pragma unroll
        for (int r = 0; r < 16; ++r) {
            __bf16 h1 = (__bf16)(x[r].x * sc1);
            __bf16 h2 = (__bf16)(x[r].y * sc2);
            pk[r] = (unsigned int)__builtin_bit_cast(unsigned short, h1) |
                    ((unsigned int)__builtin_bit_cast(unsigned short, h2) << 16);
        }
        __syncthreads();
#pragma unroll
        for (int r = 0; r < 16; ++r) S32[UPAD(t + 256 * r)] = pk[r];
    }
    __syncthreads();
    // ---- coalesced stores ----
#pragma unroll
    for (int cc = 0; cc < 2; ++cc) {
        int c = t + cc * 256;
        u16x8 o1, o2;
#pragma unroll
        for (int m = 0; m < 8; ++m) {
            unsigned int u = S32[UPAD(c * 8 + m)];
            o1[m] = (unsigned short)(u & 0xffff);
            o2[m] = (unsigned short)(u >> 16);
        }
        *(u16x8*)&row1[c * 8] = o1;
        *(u16x8*)&row2[c * 8] = o2;
    }
}

// ---------------- transpose: vt[b][e][l] bf16 -> ybf[b][l][e] bf16 ----------------
__global__ __launch_bounds__(256) void k_t2(const __bf16* __restrict__ vt, __bf16* __restrict__ ybf) {
    __shared__ __bf16 tl[64][66];
    int e0 = blockIdx.x * 64, l0 = blockIdx.y * 64, b = blockIdx.z;
    int t = threadIdx.x;
    const __bf16* src = vt + ((size_t)b << 22);
    __bf16* dst = ybf + ((size_t)b << 22);
    int er = t >> 3, lc = (t & 7) * 8;
#pragma unroll
    for (int it = 0; it < 2; ++it) {
        int e = er + it * 32;
        bf16_8 v = *(const bf16_8*)&src[(size_t)(e0 + e) * LSEQ + l0 + lc];
#pragma unroll
        for (int j = 0; j < 8; ++j) tl[e][lc + j] = v[j];
    }
    __syncthreads();
    int lr = t >> 3, ec = (t & 7) * 8;
#pragma unroll
    for (int it = 0; it < 2; ++it) {
        int l = lr + it * 32;
        bf16_8 v;
#pragma unroll
        for (int j = 0; j < 8; ++j) v[j] = tl[ec + j][l];
        *(bf16_8*)&dst[(size_t)(l0 + l) * DDIM + e0 + ec] = v;
    }
}

extern "C" void kernel_launch(void* const* d_in, const int* in_sizes, int n_in,
                              void* d_out, int out_size, void* d_ws, size_t ws_size,
                              hipStream_t stream) {
    const float* x      = (const float*)d_in[0];
    const float* Wq     = (const float*)d_in[1];
    const float* Wv     = (const float*)d_in[2];
    const float* Wo     = (const float*)d_in[3];
    const float* ln_g_s = (const float*)d_in[4];
    const float* ln_g_b = (const float*)d_in[5];
    const float* W1     = (const float*)d_in[6];
    const float* b1     = (const float*)d_in[7];
    const float* W2     = (const float*)d_in[8];
    const float* b2     = (const float*)d_in[9];
    const float* mrb    = (const float*)d_in[10];
    const float* ln_w_s = (const float*)d_in[11];
    const float* ln_w_b = (const float*)d_in[12];
    const float* Ww1    = (const float*)d_in[13];
    const float* bw1    = (const float*)d_in[14];
    const float* Ww2    = (const float*)d_in[15];
    const float* bw2    = (const float*)d_in[16];
    float* out = (float*)d_out;

    char* W = (char*)d_ws;
    __bf16* xbf = (__bf16*)W;                       // 33,554,432 B (later aliased as ybf)
    __bf16* ybf = xbf;
    __bf16* Wvb = (__bf16*)(W + 33554432);          // 2 MB
    __bf16* Wob = (__bf16*)(W + 35651584);          // 2 MB
    float*  xbp = (float*)(W + 37748736);           // 65536 f
    float*  xbar= (float*)(W + 38010880);           // 4096 f
    float*  qbar= (float*)(W + 38027264);           // 4096 f
    float*  h1g = (float*)(W + 38043648);           // 16384 f
    float*  gwp1= (float*)(W + 38109184);           // 4096 f
    float*  gre = (float*)(W + 38125568);           // 131136 f
    float*  gim = (float*)(W + 38650112);           // 131136 f

    __bf16* vt = (__bf16*)d_out;                    // scratch inside d_out

    k_xbar_partial<<<dim3(4, 16, 4), 256, 0, stream>>>(x, xbp, xbf);
    k_cvt<<<1024, 256, 0, stream>>>(Wv, Wvb, DDIM * DDIM);
    k_cvt<<<1024, 256, 0, stream>>>(Wo, Wob, DDIM * DDIM);
    k_xbar_reduce<<<dim3(4, 4), 256, 0, stream>>>(xbp, xbar);
    k_qbar<<<256, 256, 0, stream>>>(xbar, Wq, qbar);
    k_mlp<<<64, 256, 0, stream>>>(qbar, ln_g_s, ln_g_b, W1, b1, ln_w_s, ln_w_b,
                                  Ww1, bw1, Ww2, bw2, h1g, gwp1);
    k_gate<<<1025, 256, 0, stream>>>(h1g, W2, b2, gre, gim);
    k_vgemm<<<dim3(8, 32, 4), 256, 0, stream>>>(xbf, Wvb, vt);
    k_fft<<<2048, 256, 0, stream>>>(vt, gre, gim, mrb, gwp1);
    k_t2<<<dim3(16, 64, 4), 256, 0, stream>>>(vt, ybf);
    k_ogemm<<<dim3(8, 32, 4), 256, 0, stream>>>(ybf, Wob, out);
}

// Round 4
// 245.495 us; speedup vs baseline: 4.8730x; 1.0744x over previous
//
#include <hip/hip_runtime.h>
#include <math.h>

#define LSEQ 4096
#define DDIM 1024
#define NB 4
#define NH 16
#define DHD 64
#define NFREQ 2049
#define NFMAX 4097

typedef __bf16 bf16_8 __attribute__((ext_vector_type(8)));
typedef float f32x4 __attribute__((ext_vector_type(4)));
typedef unsigned short u16x8 __attribute__((ext_vector_type(8)));

__device__ __forceinline__ float gelu_exact(float v) {
    return 0.5f * v * (1.0f + erff(v * 0.70710678118654752440f));
}

__device__ __forceinline__ void gload16(const void* g, void* l) {
    __builtin_amdgcn_global_load_lds((const __attribute__((address_space(1))) char*)g,
                                     (__attribute__((address_space(3))) char*)l, 16, 0, 0);
}

// ---------------- xbar partial + x -> bf16 cast (single pass over x) ----------------
__global__ __launch_bounds__(256) void k_xbar_partial(const float* __restrict__ x, float* __restrict__ xbp,
                                                      __bf16* __restrict__ xbf) {
    int d = blockIdx.x * 256 + threadIdx.x;
    int chunk = blockIdx.y;
    int b = blockIdx.z;
    size_t base = ((size_t)b * LSEQ + (size_t)chunk * 256) * DDIM + d;
    float acc = 0.f;
    for (int l = 0; l < 256; ++l) {
        float v = x[base + (size_t)l * DDIM];
        acc += v;
        xbf[base + (size_t)l * DDIM] = (__bf16)v;
    }
    xbp[(size_t)(b * 16 + chunk) * DDIM + d] = acc;
}

__global__ __launch_bounds__(256) void k_xbar_reduce(const float* __restrict__ xbp, float* __restrict__ xbar) {
    int d = blockIdx.x * 256 + threadIdx.x;
    int b = blockIdx.y;
    float acc = 0.f;
    for (int c = 0; c < 16; ++c) acc += xbp[(size_t)(b * 16 + c) * DDIM + d];
    xbar[b * DDIM + d] = acc * (1.0f / LSEQ);
}

// ---------------- weight fp32 -> bf16 ----------------
__global__ __launch_bounds__(256) void k_cvt(const float* __restrict__ s, __bf16* __restrict__ d, int n) {
    int i = (blockIdx.x * 256 + threadIdx.x) * 4;
    if (i < n) {
        float4 v = *(const float4*)(s + i);
        d[i] = (__bf16)v.x; d[i + 1] = (__bf16)v.y; d[i + 2] = (__bf16)v.z; d[i + 3] = (__bf16)v.w;
    }
}

// ---------------- q_bar = xbar @ Wq^T ----------------
__global__ __launch_bounds__(256) void k_qbar(const float* __restrict__ xbar, const float* __restrict__ Wq,
                                              float* __restrict__ qbar) {
    int lane = threadIdx.x & 63;
    int e = blockIdx.x * 4 + (threadIdx.x >> 6);
    const float* wrow = Wq + (size_t)e * DDIM;
    float a0 = 0, a1 = 0, a2 = 0, a3 = 0;
    for (int i = 0; i < 16; ++i) {
        int d = lane + i * 64;
        float w = wrow[d];
        a0 += w * xbar[d];
        a1 += w * xbar[DDIM + d];
        a2 += w * xbar[2 * DDIM + d];
        a3 += w * xbar[3 * DDIM + d];
    }
    for (int off = 32; off > 0; off >>= 1) {
        a0 += __shfl_down(a0, off);
        a1 += __shfl_down(a1, off);
        a2 += __shfl_down(a2, off);
        a3 += __shfl_down(a3, off);
    }
    if (lane == 0) {
        qbar[e] = a0;
        qbar[DDIM + e] = a1;
        qbar[2 * DDIM + e] = a2;
        qbar[3 * DDIM + e] = a3;
    }
}

// ---------------- per-(b,h) MLPs ----------------
__global__ __launch_bounds__(256) void k_mlp(const float* __restrict__ qbar,
                                             const float* __restrict__ ln_g_s, const float* __restrict__ ln_g_b,
                                             const float* __restrict__ W1, const float* __restrict__ b1,
                                             const float* __restrict__ ln_w_s, const float* __restrict__ ln_w_b,
                                             const float* __restrict__ Ww1, const float* __restrict__ bw1,
                                             const float* __restrict__ Ww2, const float* __restrict__ bw2,
                                             float* __restrict__ h1g, float* __restrict__ gwp1) {
    int bh = blockIdx.x;
    __shared__ float q[64], hg[64], hw[64], g1[64];
    __shared__ float sm, sv;
    int t = threadIdx.x;
    if (t < 64) q[t] = qbar[bh * 64 + t];
    __syncthreads();
    if (t == 0) {
        float m = 0;
        for (int i = 0; i < 64; ++i) m += q[i];
        m *= (1.0f / 64.0f);
        float v = 0;
        for (int i = 0; i < 64; ++i) { float dd = q[i] - m; v += dd * dd; }
        v *= (1.0f / 64.0f);
        sm = m; sv = v;
    }
    __syncthreads();
    if (t < 64) {
        float n = (q[t] - sm) * rsqrtf(sv + 1e-5f);
        hg[t] = n * ln_g_s[t] + ln_g_b[t];
        hw[t] = n * ln_w_s[t] + ln_w_b[t];
    }
    __syncthreads();
    {
        int f = t;
        const float* w = W1 + (size_t)f * 64;
        float s = b1[f];
        for (int d0 = 0; d0 < 64; ++d0) s += hg[d0] * w[d0];
        h1g[(size_t)bh * 256 + f] = gelu_exact(s);
    }
    if (t < 64) {
        const float* w = Ww1 + (size_t)t * 64;
        float s = bw1[t];
        for (int k = 0; k < 64; ++k) s += hw[k] * w[k];
        g1[t] = gelu_exact(s);
    }
    __syncthreads();
    if (t < 64) {
        const float* w = Ww2 + (size_t)t * 64;
        float s = bw2[t];
        for (int k = 0; k < 64; ++k) s += g1[k] * w[k];
        gwp1[bh * 64 + t] = 1.0f + 1.0f / (1.0f + expf(-s));
    }
}

// ---------------- gate rows ----------------
__global__ __launch_bounds__(256) void k_gate(const float* __restrict__ h1g, const float* __restrict__ W2,
                                              const float* __restrict__ b2,
                                              float* __restrict__ gre, float* __restrict__ gim) {
    int task = blockIdx.x * 4 + (threadIdx.x >> 6);
    if (task >= 2 * NFREQ) return;
    int lane = threadIdx.x & 63;
    int part = task >= NFREQ;
    int f = task - part * NFREQ;
    int row = part ? (NFMAX + f) : f;
    const float* w = W2 + (size_t)row * 256;
    float w0 = w[lane], w1 = w[64 + lane], w2 = w[128 + lane], w3 = w[192 + lane];
    float bias = b2[row];
    float* dst = part ? gim : gre;
    for (int bh = 0; bh < 64; ++bh) {
        const float* hr = h1g + (size_t)bh * 256;
        float p = w0 * hr[lane] + w1 * hr[64 + lane] + w2 * hr[128 + lane] + w3 * hr[192 + lane];
        for (int off = 32; off > 0; off >>= 1) p += __shfl_down(p, off);
        if (lane == 0) dst[(size_t)bh * NFREQ + f] = p + bias;
    }
}

// ---------------- bf16 MFMA GEMM core ----------------
__device__ __forceinline__ void gemm_core(const __bf16* __restrict__ A, const __bf16* __restrict__ B,
                                          int m0, int n0, __bf16* As, __bf16* Bs, f32x4 (&acc)[4][4]) {
    int t = threadIdx.x;
    int lane = t & 63, w = t >> 6;
    int lrow = lane & 15, lk = (lane >> 4) * 8;
    int wm = (w >> 1) * 64, wn = (w & 1) * 64;
#pragma unroll
    for (int mi = 0; mi < 4; ++mi)
#pragma unroll
        for (int ni = 0; ni < 4; ++ni) acc[mi][ni] = (f32x4){0.f, 0.f, 0.f, 0.f};
    for (int k0 = 0; k0 < 1024; k0 += 32) {
#pragma unroll
        for (int i = 0; i < 2; ++i) {
            int r = w * 32 + i * 16 + (lane >> 2);
            int kc = k0 + (lane & 3) * 8;
            gload16(A + ((size_t)(m0 + r) << 10) + kc, &As[(w * 32 + i * 16) * 32]);
            gload16(B + ((size_t)(n0 + r) << 10) + kc, &Bs[(w * 32 + i * 16) * 32]);
        }
        __syncthreads();
        bf16_8 af[4], bfr[4];
#pragma unroll
        for (int mi = 0; mi < 4; ++mi) af[mi] = *(const bf16_8*)&As[(wm + mi * 16 + lrow) * 32 + lk];
#pragma unroll
        for (int ni = 0; ni < 4; ++ni) bfr[ni] = *(const bf16_8*)&Bs[(wn + ni * 16 + lrow) * 32 + lk];
#pragma unroll
        for (int mi = 0; mi < 4; ++mi)
#pragma unroll
            for (int ni = 0; ni < 4; ++ni)
                acc[mi][ni] = __builtin_amdgcn_mfma_f32_16x16x32_bf16(af[mi], bfr[ni], acc[mi][ni], 0, 0, 0);
        __syncthreads();
    }
}

// vgemm: vt[b][e][l] (bf16) = (x @ Wv^T)^T
__global__ __launch_bounds__(256) void k_vgemm(const __bf16* __restrict__ xbf, const __bf16* __restrict__ Wvb,
                                               __bf16* __restrict__ vt) {
    __shared__ __align__(16) __bf16 As[128 * 32];
    __shared__ __align__(16) __bf16 Bs[128 * 32];
    __shared__ float st[4][16][66];
    int n0 = blockIdx.x * 128, m0 = blockIdx.y * 128, b = blockIdx.z;
    f32x4 acc[4][4];
    gemm_core(xbf + ((size_t)b << 22), Wvb, m0, n0, As, Bs, acc);
    int t = threadIdx.x;
    int lane = t & 63, w = t >> 6;
    int wm = (w >> 1) * 64, wn = (w & 1) * 64;
    size_t vbase = ((size_t)b << 22);
#pragma unroll
    for (int ni = 0; ni < 4; ++ni) {
#pragma unroll
        for (int mi = 0; mi < 4; ++mi)
#pragma unroll
            for (int r = 0; r < 4; ++r)
                st[w][lane & 15][mi * 16 + (lane >> 4) * 4 + r] = acc[mi][ni][r];
        asm volatile("" ::: "memory");
#pragma unroll
        for (int er = 0; er < 16; ++er) {
            float v = st[w][er][lane];
            vt[vbase + (size_t)(n0 + wn + ni * 16 + er) * LSEQ + m0 + wm + lane] = (__bf16)v;
        }
        asm volatile("" ::: "memory");
    }
}

// ogemm: out[b][l][e2] (fp32) = ybf @ Wo^T
__global__ __launch_bounds__(256) void k_ogemm(const __bf16* __restrict__ ybf, const __bf16* __restrict__ Wob,
                                               float* __restrict__ out) {
    __shared__ __align__(16) __bf16 As[128 * 32];
    __shared__ __align__(16) __bf16 Bs[128 * 32];
    int n0 = blockIdx.x * 128, m0 = blockIdx.y * 128, b = blockIdx.z;
    f32x4 acc[4][4];
    gemm_core(ybf + ((size_t)b << 22), Wob, m0, n0, As, Bs, acc);
    int t = threadIdx.x;
    int lane = t & 63, w = t >> 6;
    int wm = (w >> 1) * 64, wn = (w & 1) * 64;
    float* ob = out + ((size_t)b << 22);
#pragma unroll
    for (int mi = 0; mi < 4; ++mi)
#pragma unroll
        for (int ni = 0; ni < 4; ++ni)
#pragma unroll
            for (int r = 0; r < 4; ++r)
                ob[(size_t)(m0 + wm + mi * 16 + (lane >> 4) * 4 + r) * DDIM + n0 + wn + ni * 16 + (lane & 15)] =
                    acc[mi][ni][r];
}

// ================= register-blocked radix-16 FFT, 2 real channels per block =================
__device__ __forceinline__ float2 cmul(float2 a, float2 b) {
    return make_float2(a.x * b.x - a.y * b.y, a.x * b.y + a.y * b.x);
}
__device__ __forceinline__ int PAD(int i) { return i + (i >> 4) + (i >> 8); }
__device__ __forceinline__ int UPAD(int i) { return i + ((i >> 6) << 3); }
__device__ __forceinline__ int DR(int k) { return ((k & 15) << 8) | (k & 0xF0) | (k >> 8); }

template <int S>  // S=1: fwd (e^{-i}), S=-1: inverse (conj)
__device__ __forceinline__ void dft16(float2* x) {
    const float C1 = 0.9238795325112867f, SS = 0.3826834323650898f, R2 = 0.7071067811865476f;
    const float sg = (S == 1) ? -1.f : 1.f;
    float2 a[16];
#pragma unroll
    for (int n0 = 0; n0 < 4; ++n0) {
        float2 x0 = x[n0], x1 = x[n0 + 4], x2 = x[n0 + 8], x3 = x[n0 + 12];
        float e0x = x0.x + x2.x, e0y = x0.y + x2.y;
        float e1x = x0.x - x2.x, e1y = x0.y - x2.y;
        float o0x = x1.x + x3.x, o0y = x1.y + x3.y;
        float o1x = x1.x - x3.x, o1y = x1.y - x3.y;
        a[n0 * 4 + 0] = make_float2(e0x + o0x, e0y + o0y);
        a[n0 * 4 + 2] = make_float2(e0x - o0x, e0y - o0y);
        float ix = (S == 1) ? o1y : -o1y;
        float iy = (S == 1) ? -o1x : o1x;
        a[n0 * 4 + 1] = make_float2(e1x + ix, e1y + iy);
        a[n0 * 4 + 3] = make_float2(e1x - ix, e1y - iy);
    }
    const float2 w1 = make_float2(C1, sg * SS);
    const float2 w2 = make_float2(R2, sg * R2);
    const float2 w3 = make_float2(SS, sg * C1);
    const float2 w6 = make_float2(-R2, sg * R2);
    const float2 w9 = make_float2(-C1, -sg * SS);
    a[5] = cmul(a[5], w1);
    a[6] = cmul(a[6], w2);
    a[7] = cmul(a[7], w3);
    a[9] = cmul(a[9], w2);
    { float2 v = a[10]; a[10] = (S == 1) ? make_float2(v.y, -v.x) : make_float2(-v.y, v.x); }
    a[11] = cmul(a[11], w6);
    a[13] = cmul(a[13], w3);
    a[14] = cmul(a[14], w6);
    a[15] = cmul(a[15], w9);
#pragma unroll
    for (int k0 = 0; k0 < 4; ++k0) {
        float2 x0 = a[k0], x1 = a[4 + k0], x2 = a[8 + k0], x3 = a[12 + k0];
        float e0x = x0.x + x2.x, e0y = x0.y + x2.y;
        float e1x = x0.x - x2.x, e1y = x0.y - x2.y;
        float o0x = x1.x + x3.x, o0y = x1.y + x3.y;
        float o1x = x1.x - x3.x, o1y = x1.y - x3.y;
        x[k0] = make_float2(e0x + o0x, e0y + o0y);
        x[k0 + 8] = make_float2(e0x - o0x, e0y - o0y);
        float ix = (S == 1) ? o1y : -o1y;
        float iy = (S == 1) ? -o1x : o1x;
        x[k0 + 4] = make_float2(e1x + ix, e1y + iy);
        x[k0 + 12] = make_float2(e1x - ix, e1y - iy);
    }
}

template <int S>
__device__ __forceinline__ void twiddle_chain(float2* x, int j, float invN) {
    float ang = ((S == 1) ? -6.283185307179586f : 6.283185307179586f) * ((float)j * invN);
    float sn, cs;
    __sincosf(ang, &sn, &cs);
    float2 w = make_float2(cs, sn), wp = w;
#pragma unroll
    for (int r = 1; r < 16; ++r) {
        x[r] = cmul(x[r], wp);
        wp = cmul(wp, w);
    }
}

__global__ __launch_bounds__(256, 2) void k_fft(__bf16* __restrict__ vty,
                                                const float* __restrict__ gre, const float* __restrict__ gim,
                                                const float* __restrict__ mrb, const float* __restrict__ gwp1) {
    __shared__ float2 Zp[4366];
    unsigned int* S32 = (unsigned int*)Zp;
    int pid = blockIdx.x;
    int b = pid >> 9, ep = pid & 511;
    int e = ep * 2;
    int h = e >> 6, dh = e & 63;
    int bh = b * 16 + h;
    size_t gbase = (size_t)bh * NFREQ;
    size_t mbase = (size_t)h * NFMAX;
    __bf16* row1 = vty + ((size_t)b << 22) + ((size_t)e << 12);
    __bf16* row2 = row1 + 4096;
    int t = threadIdx.x;

    // ---- load: Z[i] = (v1[i], v2[i]) ----
#pragma unroll
    for (int cc = 0; cc < 2; ++cc) {
        int c = t + cc * 256;
        bf16_8 a = *(const bf16_8*)&row1[c * 8];
        bf16_8 bb = *(const bf16_8*)&row2[c * 8];
#pragma unroll
        for (int m = 0; m < 8; ++m)
            Zp[PAD(c * 8 + m)] = make_float2((float)a[m], (float)bb[m]);
    }
    __syncthreads();

    float2 x[16];
    // ---- fwd stage 1 (D=256) ----
    {
        int j = t;
#pragma unroll
        for (int r = 0; r < 16; ++r) x[r] = Zp[PAD(r * 256 + j)];
        dft16<1>(x);
        twiddle_chain<1>(x, j, 1.0f / 4096.0f);
#pragma unroll
        for (int r = 0; r < 16; ++r) Zp[PAD(r * 256 + j)] = x[r];
    }
    __syncthreads();
    // ---- fwd stage 2 (D=16) ----
    {
        int g = t >> 4, j = t & 15, base = g * 256 + j;
#pragma unroll
        for (int r = 0; r < 16; ++r) x[r] = Zp[PAD(base + r * 16)];
        dft16<1>(x);
        twiddle_chain<1>(x, j, 1.0f / 256.0f);
#pragma unroll
        for (int r = 0; r < 16; ++r) Zp[PAD(base + r * 16)] = x[r];
    }
    __syncthreads();
    // ---- fwd stage 3 (D=1) ----
    {
        int base = t * 16;
#pragma unroll
        for (int r = 0; r < 16; ++r) x[r] = Zp[PAD(base + r)];
        dft16<1>(x);
#pragma unroll
        for (int r = 0; r < 16; ++r) Zp[PAD(base + r)] = x[r];
    }
    __syncthreads();
    // ---- gate + modrelu (in digit-reversed storage; in-place per thread) ----
#pragma unroll
    for (int r = 0; r < 8; ++r) {
        int k = (r << 8) + t;
        int sA = DR(k);
        int kB = (4096 - k) & 4095;
        int sB = DR(kB);
        float2 Za = Zp[PAD(sA)];
        float2 Zb = Zp[PAD(sB)];
        float v1r = 0.5f * (Za.x + Zb.x), v1i = 0.5f * (Za.y - Zb.y);
        float v2r = 0.5f * (Za.y + Zb.y), v2i = 0.5f * (Zb.x - Za.x);
        float gr = gre[gbase + k], gi = gim[gbase + k];
        float bia = mrb[mbase + k];
        float y1r = v1r * gr - v1i * gi, y1i = v1r * gi + v1i * gr;
        float m1 = sqrtf(y1r * y1r + y1i * y1i);
        float s1 = fmaxf(m1 + bia, 0.f) / (m1 + 1e-6f);
        y1r *= s1; y1i *= s1;
        float y2r = v2r * gr - v2i * gi, y2i = v2r * gi + v2i * gr;
        float m2 = sqrtf(y2r * y2r + y2i * y2i);
        float s2 = fmaxf(m2 + bia, 0.f) / (m2 + 1e-6f);
        y2r *= s2; y2i *= s2;
        if (k == 0) { y1i = 0.f; y2i = 0.f; }
        Zp[PAD(sA)] = make_float2(y1r - y2i, y1i + y2r);
        if (k) Zp[PAD(sB)] = make_float2(y1r + y2i, y2r - y1i);
    }
    if (t == 0) {  // Nyquist k=2048, slot DR(2048)=8
        float2 Za = Zp[PAD(8)];
        float gr = gre[gbase + 2048], gi = gim[gbase + 2048];
        float bia = mrb[mbase + 2048];
        float y1r = Za.x * gr, y1i = Za.x * gi;
        float m1 = sqrtf(y1r * y1r + y1i * y1i);
        float s1 = fmaxf(m1 + bia, 0.f) / (m1 + 1e-6f);
        float y2r = Za.y * gr, y2i = Za.y * gi;
        float m2 = sqrtf(y2r * y2r + y2i * y2i);
        float s2 = fmaxf(m2 + bia, 0.f) / (m2 + 1e-6f);
        Zp[PAD(8)] = make_float2(y1r * s1, y2r * s2);
    }
    __syncthreads();
    // ---- inv stage 1 (D=1) ----
    {
        int base = t * 16;
#pragma unroll
        for (int r = 0; r < 16; ++r) x[r] = Zp[PAD(base + r)];
        dft16<-1>(x);
#pragma unroll
        for (int r = 0; r < 16; ++r) Zp[PAD(base + r)] = x[r];
    }
    __syncthreads();
    // ---- inv stage 2 (D=16) ----
    {
        int g = t >> 4, j = t & 15, base = g * 256 + j;
#pragma unroll
        for (int r = 0; r < 16; ++r) x[r] = Zp[PAD(base + r * 16)];
        twiddle_chain<-1>(x, j, 1.0f / 256.0f);
        dft16<-1>(x);
#pragma unroll
        for (int r = 0; r < 16; ++r) Zp[PAD(base + r * 16)] = x[r];
    }
    __syncthreads();
    // ---- inv stage 3 (D=256) + scale + pack ----
    {
        int j = t;
#pragma unroll
        for (int r = 0; r < 16; ++r) x[r] = Zp[PAD(r * 256 + j)];
        twiddle_chain<-1>(x, j, 1.0f / 4096.0f);
        dft16<-1>(x);
        float sc1 = gwp1[bh * 64 + dh] * (1.0f / 4096.0f);
        float sc2 = gwp1[bh * 64 + dh + 1] * (1.0f / 4096.0f);
        unsigned int pk[16];
#pragma unroll
        for (int r = 0; r < 16; ++r) {
            __bf16 h1 = (__bf16)(x[r].x * sc1);
            __bf16 h2 = (__bf16)(x[r].y * sc2);
            pk[r] = (unsigned int)__builtin_bit_cast(unsigned short, h1) |
                    ((unsigned int)__builtin_bit_cast(unsigned short, h2) << 16);
        }
        __syncthreads();
#pragma unroll
        for (int r = 0; r < 16; ++r) S32[UPAD(t + 256 * r)] = pk[r];
    }
    __syncthreads();
    // ---- coalesced stores ----
#pragma unroll
    for (int cc = 0; cc < 2; ++cc) {
        int c = t + cc * 256;
        u16x8 o1, o2;
#pragma unroll
        for (int m = 0; m < 8; ++m) {
            unsigned int u = S32[UPAD(c * 8 + m)];
            o1[m] = (unsigned short)(u & 0xffff);
            o2[m] = (unsigned short)(u >> 16);
        }
        *(u16x8*)&row1[c * 8] = o1;
        *(u16x8*)&row2[c * 8] = o2;
    }
}

// ---------------- transpose: vt[b][e][l] bf16 -> ybf[b][l][e] bf16 ----------------
__global__ __launch_bounds__(256) void k_t2(const __bf16* __restrict__ vt, __bf16* __restrict__ ybf) {
    __shared__ __bf16 tl[64][66];
    int e0 = blockIdx.x * 64, l0 = blockIdx.y * 64, b = blockIdx.z;
    int t = threadIdx.x;
    const __bf16* src = vt + ((size_t)b << 22);
    __bf16* dst = ybf + ((size_t)b << 22);
    int er = t >> 3, lc = (t & 7) * 8;
#pragma unroll
    for (int it = 0; it < 2; ++it) {
        int e = er + it * 32;
        bf16_8 v = *(const bf16_8*)&src[(size_t)(e0 + e) * LSEQ + l0 + lc];
#pragma unroll
        for (int j = 0; j < 8; ++j) tl[e][lc + j] = v[j];
    }
    __syncthreads();
    int lr = t >> 3, ec = (t & 7) * 8;
#pragma unroll
    for (int it = 0; it < 2; ++it) {
        int l = lr + it * 32;
        bf16_8 v;
#pragma unroll
        for (int j = 0; j < 8; ++j) v[j] = tl[ec + j][l];
        *(bf16_8*)&dst[(size_t)(l0 + l) * DDIM + e0 + ec] = v;
    }
}

extern "C" void kernel_launch(void* const* d_in, const int* in_sizes, int n_in,
                              void* d_out, int out_size, void* d_ws, size_t ws_size,
                              hipStream_t stream) {
    const float* x      = (const float*)d_in[0];
    const float* Wq     = (const float*)d_in[1];
    const float* Wv     = (const float*)d_in[2];
    const float* Wo     = (const float*)d_in[3];
    const float* ln_g_s = (const float*)d_in[4];
    const float* ln_g_b = (const float*)d_in[5];
    const float* W1     = (const float*)d_in[6];
    const float* b1     = (const float*)d_in[7];
    const float* W2     = (const float*)d_in[8];
    const float* b2     = (const float*)d_in[9];
    const float* mrb    = (const float*)d_in[10];
    const float* ln_w_s = (const float*)d_in[11];
    const float* ln_w_b = (const float*)d_in[12];
    const float* Ww1    = (const float*)d_in[13];
    const float* bw1    = (const float*)d_in[14];
    const float* Ww2    = (const float*)d_in[15];
    const float* bw2    = (const float*)d_in[16];
    float* out = (float*)d_out;

    char* W = (char*)d_ws;
    __bf16* xbf = (__bf16*)W;                       // 33,554,432 B (later aliased as ybf)
    __bf16* ybf = xbf;
    __bf16* Wvb = (__bf16*)(W + 33554432);          // 2 MB
    __bf16* Wob = (__bf16*)(W + 35651584);          // 2 MB
    float*  xbp = (float*)(W + 37748736);           // 65536 f
    float*  xbar= (float*)(W + 38010880);           // 4096 f
    float*  qbar= (float*)(W + 38027264);           // 4096 f
    float*  h1g = (float*)(W + 38043648);           // 16384 f
    float*  gwp1= (float*)(W + 38109184);           // 4096 f
    float*  gre = (float*)(W + 38125568);           // 131136 f
    float*  gim = (float*)(W + 38650112);           // 131136 f

    __bf16* vt = (__bf16*)d_out;                    // scratch inside d_out

    k_xbar_partial<<<dim3(4, 16, 4), 256, 0, stream>>>(x, xbp, xbf);
    k_cvt<<<1024, 256, 0, stream>>>(Wv, Wvb, DDIM * DDIM);
    k_cvt<<<1024, 256, 0, stream>>>(Wo, Wob, DDIM * DDIM);
    k_xbar_reduce<<<dim3(4, 4), 256, 0, stream>>>(xbp, xbar);
    k_qbar<<<256, 256, 0, stream>>>(xbar, Wq, qbar);
    k_mlp<<<64, 256, 0, stream>>>(qbar, ln_g_s, ln_g_b, W1, b1, ln_w_s, ln_w_b,
                                  Ww1, bw1, Ww2, bw2, h1g, gwp1);
    k_gate<<<1025, 256, 0, stream>>>(h1g, W2, b2, gre, gim);
    k_vgemm<<<dim3(8, 32, 4), 256, 0, stream>>>(xbf, Wvb, vt);
    k_fft<<<2048, 256, 0, stream>>>(vt, gre, gim, mrb, gwp1);
    k_t2<<<dim3(16, 64, 4), 256, 0, stream>>>(vt, ybf);
    k_ogemm<<<dim3(8, 32, 4), 256, 0, stream>>>(ybf, Wob, out);
}

// Round 5
// 245.264 us; speedup vs baseline: 4.8776x; 1.0009x over previous
//
#include <hip/hip_runtime.h>
#include <math.h>

#define LSEQ 4096
#define DDIM 1024
#define NB 4
#define NH 16
#define DHD 64
#define NFREQ 2049
#define NFMAX 4097

typedef __bf16 bf16_8 __attribute__((ext_vector_type(8)));
typedef float f32x4 __attribute__((ext_vector_type(4)));
typedef unsigned short u16x8 __attribute__((ext_vector_type(8)));

__device__ __forceinline__ float gelu_exact(float v) {
    return 0.5f * v * (1.0f + erff(v * 0.70710678118654752440f));
}

__device__ __forceinline__ void gload16(const void* g, void* l) {
    __builtin_amdgcn_global_load_lds((const __attribute__((address_space(1))) char*)g,
                                     (__attribute__((address_space(3))) char*)l, 16, 0, 0);
}

// ---------------- xbar partial + x -> bf16 cast (single pass over x) ----------------
__global__ __launch_bounds__(256) void k_xbar_partial(const float* __restrict__ x, float* __restrict__ xbp,
                                                      __bf16* __restrict__ xbf) {
    int d = blockIdx.x * 256 + threadIdx.x;
    int chunk = blockIdx.y;
    int b = blockIdx.z;
    size_t base = ((size_t)b * LSEQ + (size_t)chunk * 256) * DDIM + d;
    float acc = 0.f;
    for (int l = 0; l < 256; ++l) {
        float v = x[base + (size_t)l * DDIM];
        acc += v;
        xbf[base + (size_t)l * DDIM] = (__bf16)v;
    }
    xbp[(size_t)(b * 16 + chunk) * DDIM + d] = acc;
}

__global__ __launch_bounds__(256) void k_xbar_reduce(const float* __restrict__ xbp, float* __restrict__ xbar) {
    int d = blockIdx.x * 256 + threadIdx.x;
    int b = blockIdx.y;
    float acc = 0.f;
    for (int c = 0; c < 16; ++c) acc += xbp[(size_t)(b * 16 + c) * DDIM + d];
    xbar[b * DDIM + d] = acc * (1.0f / LSEQ);
}

// ---------------- weight fp32 -> bf16 ----------------
__global__ __launch_bounds__(256) void k_cvt(const float* __restrict__ s, __bf16* __restrict__ d, int n) {
    int i = (blockIdx.x * 256 + threadIdx.x) * 4;
    if (i < n) {
        float4 v = *(const float4*)(s + i);
        d[i] = (__bf16)v.x; d[i + 1] = (__bf16)v.y; d[i + 2] = (__bf16)v.z; d[i + 3] = (__bf16)v.w;
    }
}

// ---------------- q_bar = xbar @ Wq^T ----------------
__global__ __launch_bounds__(256) void k_qbar(const float* __restrict__ xbar, const float* __restrict__ Wq,
                                              float* __restrict__ qbar) {
    int lane = threadIdx.x & 63;
    int e = blockIdx.x * 4 + (threadIdx.x >> 6);
    const float* wrow = Wq + (size_t)e * DDIM;
    float a0 = 0, a1 = 0, a2 = 0, a3 = 0;
    for (int i = 0; i < 16; ++i) {
        int d = lane + i * 64;
        float w = wrow[d];
        a0 += w * xbar[d];
        a1 += w * xbar[DDIM + d];
        a2 += w * xbar[2 * DDIM + d];
        a3 += w * xbar[3 * DDIM + d];
    }
    for (int off = 32; off > 0; off >>= 1) {
        a0 += __shfl_down(a0, off);
        a1 += __shfl_down(a1, off);
        a2 += __shfl_down(a2, off);
        a3 += __shfl_down(a3, off);
    }
    if (lane == 0) {
        qbar[e] = a0;
        qbar[DDIM + e] = a1;
        qbar[2 * DDIM + e] = a2;
        qbar[3 * DDIM + e] = a3;
    }
}

// ---------------- per-(b,h) MLPs ----------------
__global__ __launch_bounds__(256) void k_mlp(const float* __restrict__ qbar,
                                             const float* __restrict__ ln_g_s, const float* __restrict__ ln_g_b,
                                             const float* __restrict__ W1, const float* __restrict__ b1,
                                             const float* __restrict__ ln_w_s, const float* __restrict__ ln_w_b,
                                             const float* __restrict__ Ww1, const float* __restrict__ bw1,
                                             const float* __restrict__ Ww2, const float* __restrict__ bw2,
                                             float* __restrict__ h1g, float* __restrict__ gwp1) {
    int bh = blockIdx.x;
    __shared__ float q[64], hg[64], hw[64], g1[64];
    __shared__ float sm, sv;
    int t = threadIdx.x;
    if (t < 64) q[t] = qbar[bh * 64 + t];
    __syncthreads();
    if (t == 0) {
        float m = 0;
        for (int i = 0; i < 64; ++i) m += q[i];
        m *= (1.0f / 64.0f);
        float v = 0;
        for (int i = 0; i < 64; ++i) { float dd = q[i] - m; v += dd * dd; }
        v *= (1.0f / 64.0f);
        sm = m; sv = v;
    }
    __syncthreads();
    if (t < 64) {
        float n = (q[t] - sm) * rsqrtf(sv + 1e-5f);
        hg[t] = n * ln_g_s[t] + ln_g_b[t];
        hw[t] = n * ln_w_s[t] + ln_w_b[t];
    }
    __syncthreads();
    {
        int f = t;
        const float* w = W1 + (size_t)f * 64;
        float s = b1[f];
        for (int d0 = 0; d0 < 64; ++d0) s += hg[d0] * w[d0];
        h1g[(size_t)bh * 256 + f] = gelu_exact(s);
    }
    if (t < 64) {
        const float* w = Ww1 + (size_t)t * 64;
        float s = bw1[t];
        for (int k = 0; k < 64; ++k) s += hw[k] * w[k];
        g1[t] = gelu_exact(s);
    }
    __syncthreads();
    if (t < 64) {
        const float* w = Ww2 + (size_t)t * 64;
        float s = bw2[t];
        for (int k = 0; k < 64; ++k) s += g1[k] * w[k];
        gwp1[bh * 64 + t] = 1.0f + 1.0f / (1.0f + expf(-s));
    }
}

// ---------------- gate rows ----------------
__global__ __launch_bounds__(256) void k_gate(const float* __restrict__ h1g, const float* __restrict__ W2,
                                              const float* __restrict__ b2,
                                              float* __restrict__ gre, float* __restrict__ gim) {
    int task = blockIdx.x * 4 + (threadIdx.x >> 6);
    if (task >= 2 * NFREQ) return;
    int lane = threadIdx.x & 63;
    int part = task >= NFREQ;
    int f = task - part * NFREQ;
    int row = part ? (NFMAX + f) : f;
    const float* w = W2 + (size_t)row * 256;
    float w0 = w[lane], w1 = w[64 + lane], w2 = w[128 + lane], w3 = w[192 + lane];
    float bias = b2[row];
    float* dst = part ? gim : gre;
    for (int bh = 0; bh < 64; ++bh) {
        const float* hr = h1g + (size_t)bh * 256;
        float p = w0 * hr[lane] + w1 * hr[64 + lane] + w2 * hr[128 + lane] + w3 * hr[192 + lane];
        for (int off = 32; off > 0; off >>= 1) p += __shfl_down(p, off);
        if (lane == 0) dst[(size_t)bh * NFREQ + f] = p + bias;
    }
}

// ---------------- bf16 MFMA GEMM core ----------------
__device__ __forceinline__ void gemm_core(const __bf16* __restrict__ A, const __bf16* __restrict__ B,
                                          int m0, int n0, __bf16* As, __bf16* Bs, f32x4 (&acc)[4][4]) {
    int t = threadIdx.x;
    int lane = t & 63, w = t >> 6;
    int lrow = lane & 15, lk = (lane >> 4) * 8;
    int wm = (w >> 1) * 64, wn = (w & 1) * 64;
#pragma unroll
    for (int mi = 0; mi < 4; ++mi)
#pragma unroll
        for (int ni = 0; ni < 4; ++ni) acc[mi][ni] = (f32x4){0.f, 0.f, 0.f, 0.f};
    for (int k0 = 0; k0 < 1024; k0 += 32) {
#pragma unroll
        for (int i = 0; i < 2; ++i) {
            int r = w * 32 + i * 16 + (lane >> 2);
            int kc = k0 + (lane & 3) * 8;
            gload16(A + ((size_t)(m0 + r) << 10) + kc, &As[(w * 32 + i * 16) * 32]);
            gload16(B + ((size_t)(n0 + r) << 10) + kc, &Bs[(w * 32 + i * 16) * 32]);
        }
        __syncthreads();
        bf16_8 af[4], bfr[4];
#pragma unroll
        for (int mi = 0; mi < 4; ++mi) af[mi] = *(const bf16_8*)&As[(wm + mi * 16 + lrow) * 32 + lk];
#pragma unroll
        for (int ni = 0; ni < 4; ++ni) bfr[ni] = *(const bf16_8*)&Bs[(wn + ni * 16 + lrow) * 32 + lk];
#pragma unroll
        for (int mi = 0; mi < 4; ++mi)
#pragma unroll
            for (int ni = 0; ni < 4; ++ni)
                acc[mi][ni] = __builtin_amdgcn_mfma_f32_16x16x32_bf16(af[mi], bfr[ni], acc[mi][ni], 0, 0, 0);
        __syncthreads();
    }
}

// vgemm: vt[b][e][l] (bf16) = (x @ Wv^T)^T
__global__ __launch_bounds__(256) void k_vgemm(const __bf16* __restrict__ xbf, const __bf16* __restrict__ Wvb,
                                               __bf16* __restrict__ vt) {
    __shared__ __align__(16) __bf16 As[128 * 32];
    __shared__ __align__(16) __bf16 Bs[128 * 32];
    __shared__ float st[4][16][66];
    int n0 = blockIdx.x * 128, m0 = blockIdx.y * 128, b = blockIdx.z;
    f32x4 acc[4][4];
    gemm_core(xbf + ((size_t)b << 22), Wvb, m0, n0, As, Bs, acc);
    int t = threadIdx.x;
    int lane = t & 63, w = t >> 6;
    int wm = (w >> 1) * 64, wn = (w & 1) * 64;
    size_t vbase = ((size_t)b << 22);
#pragma unroll
    for (int ni = 0; ni < 4; ++ni) {
#pragma unroll
        for (int mi = 0; mi < 4; ++mi)
#pragma unroll
            for (int r = 0; r < 4; ++r)
                st[w][lane & 15][mi * 16 + (lane >> 4) * 4 + r] = acc[mi][ni][r];
        asm volatile("" ::: "memory");
#pragma unroll
        for (int er = 0; er < 16; ++er) {
            float v = st[w][er][lane];
            vt[vbase + (size_t)(n0 + wn + ni * 16 + er) * LSEQ + m0 + wm + lane] = (__bf16)v;
        }
        asm volatile("" ::: "memory");
    }
}

// ogemm: out[b][l][e2] (fp32) = ybf @ Wo^T
__global__ __launch_bounds__(256) void k_ogemm(const __bf16* __restrict__ ybf, const __bf16* __restrict__ Wob,
                                               float* __restrict__ out) {
    __shared__ __align__(16) __bf16 As[128 * 32];
    __shared__ __align__(16) __bf16 Bs[128 * 32];
    int n0 = blockIdx.x * 128, m0 = blockIdx.y * 128, b = blockIdx.z;
    f32x4 acc[4][4];
    gemm_core(ybf + ((size_t)b << 22), Wob, m0, n0, As, Bs, acc);
    int t = threadIdx.x;
    int lane = t & 63, w = t >> 6;
    int wm = (w >> 1) * 64, wn = (w & 1) * 64;
    float* ob = out + ((size_t)b << 22);
#pragma unroll
    for (int mi = 0; mi < 4; ++mi)
#pragma unroll
        for (int ni = 0; ni < 4; ++ni)
#pragma unroll
            for (int r = 0; r < 4; ++r)
                ob[(size_t)(m0 + wm + mi * 16 + (lane >> 4) * 4 + r) * DDIM + n0 + wn + ni * 16 + (lane & 15)] =
                    acc[mi][ni][r];
}

// ================= register-blocked radix-16 FFT, 2 real channels per block =================
__device__ __forceinline__ float2 cmul(float2 a, float2 b) {
    return make_float2(a.x * b.x - a.y * b.y, a.x * b.y + a.y * b.x);
}
__device__ __forceinline__ int PAD(int i) { return i + (i >> 4) + (i >> 8); }
__device__ __forceinline__ int UPAD(int i) { return i + ((i >> 6) << 3); }
__device__ __forceinline__ int DR(int k) { return ((k & 15) << 8) | (k & 0xF0) | (k >> 8); }

template <int S>  // S=1: fwd (e^{-i}), S=-1: inverse (conj)
__device__ __forceinline__ void dft16(float2* x) {
    const float C1 = 0.9238795325112867f, SS = 0.3826834323650898f, R2 = 0.7071067811865476f;
    const float sg = (S == 1) ? -1.f : 1.f;
    float2 a[16];
#pragma unroll
    for (int n0 = 0; n0 < 4; ++n0) {
        float2 x0 = x[n0], x1 = x[n0 + 4], x2 = x[n0 + 8], x3 = x[n0 + 12];
        float e0x = x0.x + x2.x, e0y = x0.y + x2.y;
        float e1x = x0.x - x2.x, e1y = x0.y - x2.y;
        float o0x = x1.x + x3.x, o0y = x1.y + x3.y;
        float o1x = x1.x - x3.x, o1y = x1.y - x3.y;
        a[n0 * 4 + 0] = make_float2(e0x + o0x, e0y + o0y);
        a[n0 * 4 + 2] = make_float2(e0x - o0x, e0y - o0y);
        float ix = (S == 1) ? o1y : -o1y;
        float iy = (S == 1) ? -o1x : o1x;
        a[n0 * 4 + 1] = make_float2(e1x + ix, e1y + iy);
        a[n0 * 4 + 3] = make_float2(e1x - ix, e1y - iy);
    }
    const float2 w1 = make_float2(C1, sg * SS);
    const float2 w2 = make_float2(R2, sg * R2);
    const float2 w3 = make_float2(SS, sg * C1);
    const float2 w6 = make_float2(-R2, sg * R2);
    const float2 w9 = make_float2(-C1, -sg * SS);
    a[5] = cmul(a[5], w1);
    a[6] = cmul(a[6], w2);
    a[7] = cmul(a[7], w3);
    a[9] = cmul(a[9], w2);
    { float2 v = a[10]; a[10] = (S == 1) ? make_float2(v.y, -v.x) : make_float2(-v.y, v.x); }
    a[11] = cmul(a[11], w6);
    a[13] = cmul(a[13], w3);
    a[14] = cmul(a[14], w6);
    a[15] = cmul(a[15], w9);
#pragma unroll
    for (int k0 = 0; k0 < 4; ++k0) {
        float2 x0 = a[k0], x1 = a[4 + k0], x2 = a[8 + k0], x3 = a[12 + k0];
        float e0x = x0.x + x2.x, e0y = x0.y + x2.y;
        float e1x = x0.x - x2.x, e1y = x0.y - x2.y;
        float o0x = x1.x + x3.x, o0y = x1.y + x3.y;
        float o1x = x1.x - x3.x, o1y = x1.y - x3.y;
        x[k0] = make_float2(e0x + o0x, e0y + o0y);
        x[k0 + 8] = make_float2(e0x - o0x, e0y - o0y);
        float ix = (S == 1) ? o1y : -o1y;
        float iy = (S == 1) ? -o1x : o1x;
        x[k0 + 4] = make_float2(e1x + ix, e1y + iy);
        x[k0 + 12] = make_float2(e1x - ix, e1y - iy);
    }
}

// Independent per-r twiddles: x[r] *= exp(S * -2*pi*i * j*r*invN).
// No serial wp chain -> 15 independent sincos (TRANS pipe) + 15 independent cmuls.
template <int S>
__device__ __forceinline__ void twiddle_chain(float2* x, int j, float invN) {
    float base = ((S == 1) ? -6.283185307179586f : 6.283185307179586f) * invN;
#pragma unroll
    for (int r = 1; r < 16; ++r) {
        float sn, cs;
        __sincosf(base * (float)(j * r), &sn, &cs);
        x[r] = cmul(x[r], make_float2(cs, sn));
    }
}

__global__ __launch_bounds__(256, 2) void k_fft(__bf16* __restrict__ vty,
                                                const float* __restrict__ gre, const float* __restrict__ gim,
                                                const float* __restrict__ mrb, const float* __restrict__ gwp1) {
    __shared__ float2 Zp[4366];
    unsigned int* S32 = (unsigned int*)Zp;
    int pid = blockIdx.x;
    int b = pid >> 9, ep = pid & 511;
    int e = ep * 2;
    int h = e >> 6, dh = e & 63;
    int bh = b * 16 + h;
    size_t gbase = (size_t)bh * NFREQ;
    size_t mbase = (size_t)h * NFMAX;
    __bf16* row1 = vty + ((size_t)b << 22) + ((size_t)e << 12);
    __bf16* row2 = row1 + 4096;
    int t = threadIdx.x;

    // ---- load: Z[i] = (v1[i], v2[i]) ----
#pragma unroll
    for (int cc = 0; cc < 2; ++cc) {
        int c = t + cc * 256;
        bf16_8 a = *(const bf16_8*)&row1[c * 8];
        bf16_8 bb = *(const bf16_8*)&row2[c * 8];
#pragma unroll
        for (int m = 0; m < 8; ++m)
            Zp[PAD(c * 8 + m)] = make_float2((float)a[m], (float)bb[m]);
    }
    __syncthreads();

    float2 x[16];
    // ---- fwd stage 1 (D=256) ----
    {
        int j = t;
#pragma unroll
        for (int r = 0; r < 16; ++r) x[r] = Zp[PAD(r * 256 + j)];
        dft16<1>(x);
        twiddle_chain<1>(x, j, 1.0f / 4096.0f);
#pragma unroll
        for (int r = 0; r < 16; ++r) Zp[PAD(r * 256 + j)] = x[r];
    }
    __syncthreads();
    // ---- fwd stage 2 (D=16) ----
    {
        int g = t >> 4, j = t & 15, base = g * 256 + j;
#pragma unroll
        for (int r = 0; r < 16; ++r) x[r] = Zp[PAD(base + r * 16)];
        dft16<1>(x);
        twiddle_chain<1>(x, j, 1.0f / 256.0f);
#pragma unroll
        for (int r = 0; r < 16; ++r) Zp[PAD(base + r * 16)] = x[r];
    }
    __syncthreads();
    // ---- fwd stage 3 (D=1) ----
    {
        int base = t * 16;
#pragma unroll
        for (int r = 0; r < 16; ++r) x[r] = Zp[PAD(base + r)];
        dft16<1>(x);
#pragma unroll
        for (int r = 0; r < 16; ++r) Zp[PAD(base + r)] = x[r];
    }
    __syncthreads();
    // ---- gate + modrelu (in digit-reversed storage; in-place per thread) ----
#pragma unroll
    for (int r = 0; r < 8; ++r) {
        int k = (r << 8) + t;
        int sA = DR(k);
        int kB = (4096 - k) & 4095;
        int sB = DR(kB);
        float2 Za = Zp[PAD(sA)];
        float2 Zb = Zp[PAD(sB)];
        float v1r = 0.5f * (Za.x + Zb.x), v1i = 0.5f * (Za.y - Zb.y);
        float v2r = 0.5f * (Za.y + Zb.y), v2i = 0.5f * (Zb.x - Za.x);
        float gr = gre[gbase + k], gi = gim[gbase + k];
        float bia = mrb[mbase + k];
        float y1r = v1r * gr - v1i * gi, y1i = v1r * gi + v1i * gr;
        float m1 = sqrtf(y1r * y1r + y1i * y1i);
        float s1 = fmaxf(m1 + bia, 0.f) / (m1 + 1e-6f);
        y1r *= s1; y1i *= s1;
        float y2r = v2r * gr - v2i * gi, y2i = v2r * gi + v2i * gr;
        float m2 = sqrtf(y2r * y2r + y2i * y2i);
        float s2 = fmaxf(m2 + bia, 0.f) / (m2 + 1e-6f);
        y2r *= s2; y2i *= s2;
        if (k == 0) { y1i = 0.f; y2i = 0.f; }
        Zp[PAD(sA)] = make_float2(y1r - y2i, y1i + y2r);
        if (k) Zp[PAD(sB)] = make_float2(y1r + y2i, y2r - y1i);
    }
    if (t == 0) {  // Nyquist k=2048, slot DR(2048)=8
        float2 Za = Zp[PAD(8)];
        float gr = gre[gbase + 2048], gi = gim[gbase + 2048];
        float bia = mrb[mbase + 2048];
        float y1r = Za.x * gr, y1i = Za.x * gi;
        float m1 = sqrtf(y1r * y1r + y1i * y1i);
        float s1 = fmaxf(m1 + bia, 0.f) / (m1 + 1e-6f);
        float y2r = Za.y * gr, y2i = Za.y * gi;
        float m2 = sqrtf(y2r * y2r + y2i * y2i);
        float s2 = fmaxf(m2 + bia, 0.f) / (m2 + 1e-6f);
        Zp[PAD(8)] = make_float2(y1r * s1, y2r * s2);
    }
    __syncthreads();
    // ---- inv stage 1 (D=1) ----
    {
        int base = t * 16;
#pragma unroll
        for (int r = 0; r < 16; ++r) x[r] = Zp[PAD(base + r)];
        dft16<-1>(x);
#pragma unroll
        for (int r = 0; r < 16; ++r) Zp[PAD(base + r)] = x[r];
    }
    __syncthreads();
    // ---- inv stage 2 (D=16) ----
    {
        int g = t >> 4, j = t & 15, base = g * 256 + j;
#pragma unroll
        for (int r = 0; r < 16; ++r) x[r] = Zp[PAD(base + r * 16)];
        twiddle_chain<-1>(x, j, 1.0f / 256.0f);
        dft16<-1>(x);
#pragma unroll
        for (int r = 0; r < 16; ++r) Zp[PAD(base + r * 16)] = x[r];
    }
    __syncthreads();
    // ---- inv stage 3 (D=256) + scale + pack ----
    {
        int j = t;
#pragma unroll
        for (int r = 0; r < 16; ++r) x[r] = Zp[PAD(r * 256 + j)];
        twiddle_chain<-1>(x, j, 1.0f / 4096.0f);
        dft16<-1>(x);
        float sc1 = gwp1[bh * 64 + dh] * (1.0f / 4096.0f);
        float sc2 = gwp1[bh * 64 + dh + 1] * (1.0f / 4096.0f);
        unsigned int pk[16];
#pragma unroll
        for (int r = 0; r < 16; ++r) {
            __bf16 h1 = (__bf16)(x[r].x * sc1);
            __bf16 h2 = (__bf16)(x[r].y * sc2);
            pk[r] = (unsigned int)__builtin_bit_cast(unsigned short, h1) |
                    ((unsigned int)__builtin_bit_cast(unsigned short, h2) << 16);
        }
        __syncthreads();
#pragma unroll
        for (int r = 0; r < 16; ++r) S32[UPAD(t + 256 * r)] = pk[r];
    }
    __syncthreads();
    // ---- coalesced stores ----
#pragma unroll
    for (int cc = 0; cc < 2; ++cc) {
        int c = t + cc * 256;
        u16x8 o1, o2;
#pragma unroll
        for (int m = 0; m < 8; ++m) {
            unsigned int u = S32[UPAD(c * 8 + m)];
            o1[m] = (unsigned short)(u & 0xffff);
            o2[m] = (unsigned short)(u >> 16);
        }
        *(u16x8*)&row1[c * 8] = o1;
        *(u16x8*)&row2[c * 8] = o2;
    }
}

// ---------------- transpose: vt[b][e][l] bf16 -> ybf[b][l][e] bf16 ----------------
__global__ __launch_bounds__(256) void k_t2(const __bf16* __restrict__ vt, __bf16* __restrict__ ybf) {
    __shared__ __bf16 tl[64][66];
    int e0 = blockIdx.x * 64, l0 = blockIdx.y * 64, b = blockIdx.z;
    int t = threadIdx.x;
    const __bf16* src = vt + ((size_t)b << 22);
    __bf16* dst = ybf + ((size_t)b << 22);
    int er = t >> 3, lc = (t & 7) * 8;
#pragma unroll
    for (int it = 0; it < 2; ++it) {
        int e = er + it * 32;
        bf16_8 v = *(const bf16_8*)&src[(size_t)(e0 + e) * LSEQ + l0 + lc];
#pragma unroll
        for (int j = 0; j < 8; ++j) tl[e][lc + j] = v[j];
    }
    __syncthreads();
    int lr = t >> 3, ec = (t & 7) * 8;
#pragma unroll
    for (int it = 0; it < 2; ++it) {
        int l = lr + it * 32;
        bf16_8 v;
#pragma unroll
        for (int j = 0; j < 8; ++j) v[j] = tl[ec + j][l];
        *(bf16_8*)&dst[(size_t)(l0 + l) * DDIM + e0 + ec] = v;
    }
}

extern "C" void kernel_launch(void* const* d_in, const int* in_sizes, int n_in,
                              void* d_out, int out_size, void* d_ws, size_t ws_size,
                              hipStream_t stream) {
    const float* x      = (const float*)d_in[0];
    const float* Wq     = (const float*)d_in[1];
    const float* Wv     = (const float*)d_in[2];
    const float* Wo     = (const float*)d_in[3];
    const float* ln_g_s = (const float*)d_in[4];
    const float* ln_g_b = (const float*)d_in[5];
    const float* W1     = (const float*)d_in[6];
    const float* b1     = (const float*)d_in[7];
    const float* W2     = (const float*)d_in[8];
    const float* b2     = (const float*)d_in[9];
    const float* mrb    = (const float*)d_in[10];
    const float* ln_w_s = (const float*)d_in[11];
    const float* ln_w_b = (const float*)d_in[12];
    const float* Ww1    = (const float*)d_in[13];
    const float* bw1    = (const float*)d_in[14];
    const float* Ww2    = (const float*)d_in[15];
    const float* bw2    = (const float*)d_in[16];
    float* out = (float*)d_out;

    char* W = (char*)d_ws;
    __bf16* xbf = (__bf16*)W;                       // 33,554,432 B (later aliased as ybf)
    __bf16* ybf = xbf;
    __bf16* Wvb = (__bf16*)(W + 33554432);          // 2 MB
    __bf16* Wob = (__bf16*)(W + 35651584);          // 2 MB
    float*  xbp = (float*)(W + 37748736);           // 65536 f
    float*  xbar= (float*)(W + 38010880);           // 4096 f
    float*  qbar= (float*)(W + 38027264);           // 4096 f
    float*  h1g = (float*)(W + 38043648);           // 16384 f
    float*  gwp1= (float*)(W + 38109184);           // 4096 f
    float*  gre = (float*)(W + 38125568);           // 131136 f
    float*  gim = (float*)(W + 38650112);           // 131136 f

    __bf16* vt = (__bf16*)d_out;                    // scratch inside d_out

    k_xbar_partial<<<dim3(4, 16, 4), 256, 0, stream>>>(x, xbp, xbf);
    k_cvt<<<1024, 256, 0, stream>>>(Wv, Wvb, DDIM * DDIM);
    k_cvt<<<1024, 256, 0, stream>>>(Wo, Wob, DDIM * DDIM);
    k_xbar_reduce<<<dim3(4, 4), 256, 0, stream>>>(xbp, xbar);
    k_qbar<<<256, 256, 0, stream>>>(xbar, Wq, qbar);
    k_mlp<<<64, 256, 0, stream>>>(qbar, ln_g_s, ln_g_b, W1, b1, ln_w_s, ln_w_b,
                                  Ww1, bw1, Ww2, bw2, h1g, gwp1);
    k_gate<<<1025, 256, 0, stream>>>(h1g, W2, b2, gre, gim);
    k_vgemm<<<dim3(8, 32, 4), 256, 0, stream>>>(xbf, Wvb, vt);
    k_fft<<<2048, 256, 0, stream>>>(vt, gre, gim, mrb, gwp1);
    k_t2<<<dim3(16, 64, 4), 256, 0, stream>>>(vt, ybf);
    k_ogemm<<<dim3(8, 32, 4), 256, 0, stream>>>(ybf, Wob, out);
}

// Round 6
// 244.965 us; speedup vs baseline: 4.8836x; 1.0012x over previous
//
#include <hip/hip_runtime.h>
#include <math.h>

#define LSEQ 4096
#define DDIM 1024
#define NB 4
#define NH 16
#define DHD 64
#define NFREQ 2049
#define NFMAX 4097

typedef __bf16 bf16_8 __attribute__((ext_vector_type(8)));
typedef float f32x4 __attribute__((ext_vector_type(4)));

__device__ __forceinline__ float gelu_exact(float v) {
    return 0.5f * v * (1.0f + erff(v * 0.70710678118654752440f));
}

__device__ __forceinline__ void gload16(const void* g, void* l) {
    __builtin_amdgcn_global_load_lds((const __attribute__((address_space(1))) char*)g,
                                     (__attribute__((address_space(3))) char*)l, 16, 0, 0);
}

// ---------------- xbar partial + x -> bf16 cast (single pass over x) ----------------
__global__ __launch_bounds__(256) void k_xbar_partial(const float* __restrict__ x, float* __restrict__ xbp,
                                                      __bf16* __restrict__ xbf) {
    int d = blockIdx.x * 256 + threadIdx.x;
    int chunk = blockIdx.y;
    int b = blockIdx.z;
    size_t base = ((size_t)b * LSEQ + (size_t)chunk * 256) * DDIM + d;
    float acc = 0.f;
    for (int l = 0; l < 256; ++l) {
        float v = x[base + (size_t)l * DDIM];
        acc += v;
        xbf[base + (size_t)l * DDIM] = (__bf16)v;
    }
    xbp[(size_t)(b * 16 + chunk) * DDIM + d] = acc;
}

__global__ __launch_bounds__(256) void k_xbar_reduce(const float* __restrict__ xbp, float* __restrict__ xbar) {
    int d = blockIdx.x * 256 + threadIdx.x;
    int b = blockIdx.y;
    float acc = 0.f;
    for (int c = 0; c < 16; ++c) acc += xbp[(size_t)(b * 16 + c) * DDIM + d];
    xbar[b * DDIM + d] = acc * (1.0f / LSEQ);
}

// ---------------- weight fp32 -> bf16 ----------------
__global__ __launch_bounds__(256) void k_cvt(const float* __restrict__ s, __bf16* __restrict__ d, int n) {
    int i = (blockIdx.x * 256 + threadIdx.x) * 4;
    if (i < n) {
        float4 v = *(const float4*)(s + i);
        d[i] = (__bf16)v.x; d[i + 1] = (__bf16)v.y; d[i + 2] = (__bf16)v.z; d[i + 3] = (__bf16)v.w;
    }
}

// ---------------- q_bar = xbar @ Wq^T ----------------
__global__ __launch_bounds__(256) void k_qbar(const float* __restrict__ xbar, const float* __restrict__ Wq,
                                              float* __restrict__ qbar) {
    int lane = threadIdx.x & 63;
    int e = blockIdx.x * 4 + (threadIdx.x >> 6);
    const float* wrow = Wq + (size_t)e * DDIM;
    float a0 = 0, a1 = 0, a2 = 0, a3 = 0;
    for (int i = 0; i < 16; ++i) {
        int d = lane + i * 64;
        float w = wrow[d];
        a0 += w * xbar[d];
        a1 += w * xbar[DDIM + d];
        a2 += w * xbar[2 * DDIM + d];
        a3 += w * xbar[3 * DDIM + d];
    }
    for (int off = 32; off > 0; off >>= 1) {
        a0 += __shfl_down(a0, off);
        a1 += __shfl_down(a1, off);
        a2 += __shfl_down(a2, off);
        a3 += __shfl_down(a3, off);
    }
    if (lane == 0) {
        qbar[e] = a0;
        qbar[DDIM + e] = a1;
        qbar[2 * DDIM + e] = a2;
        qbar[3 * DDIM + e] = a3;
    }
}

// ---------------- per-(b,h) MLPs ----------------
__global__ __launch_bounds__(256) void k_mlp(const float* __restrict__ qbar,
                                             const float* __restrict__ ln_g_s, const float* __restrict__ ln_g_b,
                                             const float* __restrict__ W1, const float* __restrict__ b1,
                                             const float* __restrict__ ln_w_s, const float* __restrict__ ln_w_b,
                                             const float* __restrict__ Ww1, const float* __restrict__ bw1,
                                             const float* __restrict__ Ww2, const float* __restrict__ bw2,
                                             float* __restrict__ h1g, float* __restrict__ gwp1) {
    int bh = blockIdx.x;
    __shared__ float q[64], hg[64], hw[64], g1[64];
    __shared__ float sm, sv;
    int t = threadIdx.x;
    if (t < 64) q[t] = qbar[bh * 64 + t];
    __syncthreads();
    if (t == 0) {
        float m = 0;
        for (int i = 0; i < 64; ++i) m += q[i];
        m *= (1.0f / 64.0f);
        float v = 0;
        for (int i = 0; i < 64; ++i) { float dd = q[i] - m; v += dd * dd; }
        v *= (1.0f / 64.0f);
        sm = m; sv = v;
    }
    __syncthreads();
    if (t < 64) {
        float n = (q[t] - sm) * rsqrtf(sv + 1e-5f);
        hg[t] = n * ln_g_s[t] + ln_g_b[t];
        hw[t] = n * ln_w_s[t] + ln_w_b[t];
    }
    __syncthreads();
    {
        int f = t;
        const float* w = W1 + (size_t)f * 64;
        float s = b1[f];
        for (int d0 = 0; d0 < 64; ++d0) s += hg[d0] * w[d0];
        h1g[(size_t)bh * 256 + f] = gelu_exact(s);
    }
    if (t < 64) {
        const float* w = Ww1 + (size_t)t * 64;
        float s = bw1[t];
        for (int k = 0; k < 64; ++k) s += hw[k] * w[k];
        g1[t] = gelu_exact(s);
    }
    __syncthreads();
    if (t < 64) {
        const float* w = Ww2 + (size_t)t * 64;
        float s = bw2[t];
        for (int k = 0; k < 64; ++k) s += g1[k] * w[k];
        gwp1[bh * 64 + t] = 1.0f + 1.0f / (1.0f + expf(-s));
    }
}

// ---------------- gate rows ----------------
__global__ __launch_bounds__(256) void k_gate(const float* __restrict__ h1g, const float* __restrict__ W2,
                                              const float* __restrict__ b2,
                                              float* __restrict__ gre, float* __restrict__ gim) {
    int task = blockIdx.x * 4 + (threadIdx.x >> 6);
    if (task >= 2 * NFREQ) return;
    int lane = threadIdx.x & 63;
    int part = task >= NFREQ;
    int f = task - part * NFREQ;
    int row = part ? (NFMAX + f) : f;
    const float* w = W2 + (size_t)row * 256;
    float w0 = w[lane], w1 = w[64 + lane], w2 = w[128 + lane], w3 = w[192 + lane];
    float bias = b2[row];
    float* dst = part ? gim : gre;
    for (int bh = 0; bh < 64; ++bh) {
        const float* hr = h1g + (size_t)bh * 256;
        float p = w0 * hr[lane] + w1 * hr[64 + lane] + w2 * hr[128 + lane] + w3 * hr[192 + lane];
        for (int off = 32; off > 0; off >>= 1) p += __shfl_down(p, off);
        if (lane == 0) dst[(size_t)bh * NFREQ + f] = p + bias;
    }
}

// ---------------- bf16 MFMA GEMM core ----------------
__device__ __forceinline__ void gemm_core(const __bf16* __restrict__ A, const __bf16* __restrict__ B,
                                          int m0, int n0, __bf16* As, __bf16* Bs, f32x4 (&acc)[4][4]) {
    int t = threadIdx.x;
    int lane = t & 63, w = t >> 6;
    int lrow = lane & 15, lk = (lane >> 4) * 8;
    int wm = (w >> 1) * 64, wn = (w & 1) * 64;
#pragma unroll
    for (int mi = 0; mi < 4; ++mi)
#pragma unroll
        for (int ni = 0; ni < 4; ++ni) acc[mi][ni] = (f32x4){0.f, 0.f, 0.f, 0.f};
    for (int k0 = 0; k0 < 1024; k0 += 32) {
#pragma unroll
        for (int i = 0; i < 2; ++i) {
            int r = w * 32 + i * 16 + (lane >> 2);
            int kc = k0 + (lane & 3) * 8;
            gload16(A + ((size_t)(m0 + r) << 10) + kc, &As[(w * 32 + i * 16) * 32]);
            gload16(B + ((size_t)(n0 + r) << 10) + kc, &Bs[(w * 32 + i * 16) * 32]);
        }
        __syncthreads();
        bf16_8 af[4], bfr[4];
#pragma unroll
        for (int mi = 0; mi < 4; ++mi) af[mi] = *(const bf16_8*)&As[(wm + mi * 16 + lrow) * 32 + lk];
#pragma unroll
        for (int ni = 0; ni < 4; ++ni) bfr[ni] = *(const bf16_8*)&Bs[(wn + ni * 16 + lrow) * 32 + lk];
#pragma unroll
        for (int mi = 0; mi < 4; ++mi)
#pragma unroll
            for (int ni = 0; ni < 4; ++ni)
                acc[mi][ni] = __builtin_amdgcn_mfma_f32_16x16x32_bf16(af[mi], bfr[ni], acc[mi][ni], 0, 0, 0);
        __syncthreads();
    }
}

// vgemm: vt[b][e][l] (bf16) = (x @ Wv^T)^T
__global__ __launch_bounds__(256) void k_vgemm(const __bf16* __restrict__ xbf, const __bf16* __restrict__ Wvb,
                                               __bf16* __restrict__ vt) {
    __shared__ __align__(16) __bf16 As[128 * 32];
    __shared__ __align__(16) __bf16 Bs[128 * 32];
    __shared__ float st[4][16][66];
    int n0 = blockIdx.x * 128, m0 = blockIdx.y * 128, b = blockIdx.z;
    f32x4 acc[4][4];
    gemm_core(xbf + ((size_t)b << 22), Wvb, m0, n0, As, Bs, acc);
    int t = threadIdx.x;
    int lane = t & 63, w = t >> 6;
    int wm = (w >> 1) * 64, wn = (w & 1) * 64;
    size_t vbase = ((size_t)b << 22);
#pragma unroll
    for (int ni = 0; ni < 4; ++ni) {
#pragma unroll
        for (int mi = 0; mi < 4; ++mi)
#pragma unroll
            for (int r = 0; r < 4; ++r)
                st[w][lane & 15][mi * 16 + (lane >> 4) * 4 + r] = acc[mi][ni][r];
        asm volatile("" ::: "memory");
#pragma unroll
        for (int er = 0; er < 16; ++er) {
            float v = st[w][er][lane];
            vt[vbase + (size_t)(n0 + wn + ni * 16 + er) * LSEQ + m0 + wm + lane] = (__bf16)v;
        }
        asm volatile("" ::: "memory");
    }
}

// ogemm: out[b][l][e2] (fp32) = ybf @ Wo^T
__global__ __launch_bounds__(256) void k_ogemm(const __bf16* __restrict__ ybf, const __bf16* __restrict__ Wob,
                                               float* __restrict__ out) {
    __shared__ __align__(16) __bf16 As[128 * 32];
    __shared__ __align__(16) __bf16 Bs[128 * 32];
    int n0 = blockIdx.x * 128, m0 = blockIdx.y * 128, b = blockIdx.z;
    f32x4 acc[4][4];
    gemm_core(ybf + ((size_t)b << 22), Wob, m0, n0, As, Bs, acc);
    int t = threadIdx.x;
    int lane = t & 63, w = t >> 6;
    int wm = (w >> 1) * 64, wn = (w & 1) * 64;
    float* ob = out + ((size_t)b << 22);
#pragma unroll
    for (int mi = 0; mi < 4; ++mi)
#pragma unroll
        for (int ni = 0; ni < 4; ++ni)
#pragma unroll
            for (int r = 0; r < 4; ++r)
                ob[(size_t)(m0 + wm + mi * 16 + (lane >> 4) * 4 + r) * DDIM + n0 + wn + ni * 16 + (lane & 15)] =
                    acc[mi][ni][r];
}

// ================= rfft4096 per channel via cfft2048 (even/odd pack), radix 8-8-8-4 =================
__device__ __forceinline__ float2 cmul(float2 a, float2 b) {
    return make_float2(a.x * b.x - a.y * b.y, a.x * b.y + a.y * b.x);
}
__device__ __forceinline__ int P8(int i) { return i + (i >> 3) + (i >> 8); }
// storage slot of bin k after DIF stages radix 8(D=256),8(D=32),8(D=4),4(D=1)
__device__ __forceinline__ int SR8(int k) {
    return ((k & 7) << 8) | (((k >> 3) & 7) << 5) | (((k >> 6) & 7) << 2) | (k >> 9);
}

template <int S>  // S=1 fwd (e^{-i..}), S=-1 inverse
__device__ __forceinline__ void dft4v(float2* x) {
    float2 t0 = make_float2(x[0].x + x[2].x, x[0].y + x[2].y);
    float2 t1 = make_float2(x[0].x - x[2].x, x[0].y - x[2].y);
    float2 t2 = make_float2(x[1].x + x[3].x, x[1].y + x[3].y);
    float2 t3 = make_float2(x[1].x - x[3].x, x[1].y - x[3].y);
    float2 j3 = (S == 1) ? make_float2(t3.y, -t3.x) : make_float2(-t3.y, t3.x);
    x[0] = make_float2(t0.x + t2.x, t0.y + t2.y);
    x[2] = make_float2(t0.x - t2.x, t0.y - t2.y);
    x[1] = make_float2(t1.x + j3.x, t1.y + j3.y);
    x[3] = make_float2(t1.x - j3.x, t1.y - j3.y);
}

template <int S>
__device__ __forceinline__ void dft8v(float2* x) {
    float2 e[4] = {x[0], x[2], x[4], x[6]};
    float2 o[4] = {x[1], x[3], x[5], x[7]};
    dft4v<S>(e);
    dft4v<S>(o);
    const float c = 0.7071067811865476f;
    const float sg = (S == 1) ? -1.f : 1.f;
    o[1] = cmul(o[1], make_float2(c, sg * c));
    o[2] = (S == 1) ? make_float2(o[2].y, -o[2].x) : make_float2(-o[2].y, o[2].x);
    o[3] = cmul(o[3], make_float2(-c, sg * c));
    x[0] = make_float2(e[0].x + o[0].x, e[0].y + o[0].y);
    x[4] = make_float2(e[0].x - o[0].x, e[0].y - o[0].y);
    x[1] = make_float2(e[1].x + o[1].x, e[1].y + o[1].y);
    x[5] = make_float2(e[1].x - o[1].x, e[1].y - o[1].y);
    x[2] = make_float2(e[2].x + o[2].x, e[2].y + o[2].y);
    x[6] = make_float2(e[2].x - o[2].x, e[2].y - o[2].y);
    x[3] = make_float2(e[3].x + o[3].x, e[3].y + o[3].y);
    x[7] = make_float2(e[3].x - o[3].x, e[3].y - o[3].y);
}

template <int S>
__device__ __forceinline__ void tw8(float2* x, int j, float invN) {
    float base = ((S == 1) ? -6.283185307179586f : 6.283185307179586f) * invN;
#pragma unroll
    for (int r = 1; r < 8; ++r) {
        float sn, cs;
        __sincosf(base * (float)(j * r), &sn, &cs);
        x[r] = cmul(x[r], make_float2(cs, sn));
    }
}

__global__ __launch_bounds__(256, 2) void k_fft(__bf16* __restrict__ vty,
                                                const float* __restrict__ gre, const float* __restrict__ gim,
                                                const float* __restrict__ mrb, const float* __restrict__ gwp1) {
    __shared__ float2 Zp[2312];
    int pid = blockIdx.x;
    int b = pid >> 10, e = pid & 1023;
    int h = e >> 6, dh = e & 63;
    int bh = b * 16 + h;
    size_t gbase = (size_t)bh * NFREQ;
    size_t mbase = (size_t)h * NFMAX;
    __bf16* row = vty + ((size_t)b << 22) + ((size_t)e << 12);
    int t = threadIdx.x;

    // ---- load: z[m] = (v[2m], v[2m+1]) ----
#pragma unroll
    for (int cc = 0; cc < 2; ++cc) {
        int c = t + cc * 256;
        bf16_8 a = *(const bf16_8*)&row[c * 8];
#pragma unroll
        for (int q = 0; q < 4; ++q)
            Zp[P8(c * 4 + q)] = make_float2((float)a[2 * q], (float)a[2 * q + 1]);
    }
    __syncthreads();

    float2 x[8];
    // ---- fwd S1: radix-8, D=256 ----
    {
#pragma unroll
        for (int r = 0; r < 8; ++r) x[r] = Zp[P8(r * 256 + t)];
        dft8v<1>(x);
        tw8<1>(x, t, 1.0f / 2048.0f);
#pragma unroll
        for (int r = 0; r < 8; ++r) Zp[P8(r * 256 + t)] = x[r];
    }
    __syncthreads();
    // ---- fwd S2: radix-8, D=32 ----
    {
        int g = t >> 5, j = t & 31, base = g * 256 + j;
#pragma unroll
        for (int r = 0; r < 8; ++r) x[r] = Zp[P8(base + r * 32)];
        dft8v<1>(x);
        tw8<1>(x, j, 1.0f / 256.0f);
#pragma unroll
        for (int r = 0; r < 8; ++r) Zp[P8(base + r * 32)] = x[r];
    }
    __syncthreads();
    // ---- fwd S3: radix-8, D=4 ----
    {
        int g = t >> 2, j = t & 3, base = g * 32 + j;
#pragma unroll
        for (int r = 0; r < 8; ++r) x[r] = Zp[P8(base + r * 4)];
        dft8v<1>(x);
        tw8<1>(x, j, 1.0f / 32.0f);
#pragma unroll
        for (int r = 0; r < 8; ++r) Zp[P8(base + r * 4)] = x[r];
    }
    __syncthreads();
    // ---- fwd S4: radix-4, D=1 (two per thread) ----
    {
        int base = t * 8;
#pragma unroll
        for (int q = 0; q < 4; ++q) { x[q] = Zp[P8(base + q)]; x[4 + q] = Zp[P8(base + 4 + q)]; }
        dft4v<1>(x);
        dft4v<1>(x + 4);
#pragma unroll
        for (int q = 0; q < 4; ++q) { Zp[P8(base + q)] = x[q]; Zp[P8(base + 4 + q)] = x[4 + q]; }
    }
    __syncthreads();

    // ---- untangle + gate + modrelu + re-tangle (digit-reversed domain) ----
    // pairs k in [1,1024], k2 = 2048-k; bin k=1024 self-pairs (writes same value twice).
#pragma unroll
    for (int r = 0; r < 4; ++r) {
        int k = 1 + (r << 8) + t;
        int k2 = 2048 - k;
        int sA = P8(SR8(k)), sB = P8(SR8(k2));
        float2 Za = Zp[sA], Zb = Zp[sB];
        float Er = 0.5f * (Za.x + Zb.x), Ei = 0.5f * (Za.y - Zb.y);
        float Dr = 0.5f * (Za.x - Zb.x), Di = 0.5f * (Za.y + Zb.y);
        float sn, cs;
        __sincosf(-1.5339807878856412e-3f * (float)k, &sn, &cs);   // W = e^{-2pi i k/4096}
        float WDr = cs * Dr - sn * Di, WDi = cs * Di + sn * Dr;    // W*D
        float Tr = -WDi, Ti = WDr;                                  // T = i*W*D
        float Vkr = Er - Tr, Vki = Ei - Ti;                         // V[k]  = E - T
        float Vk2r = Er + Tr, Vk2i = -(Ei + Ti);                    // V[k2] = conj(E + T)
        // gate+modrelu bin k
        float g1r = gre[gbase + k], g1i = gim[gbase + k], b1v = mrb[mbase + k];
        float Ykr = Vkr * g1r - Vki * g1i, Yki = Vkr * g1i + Vki * g1r;
        float m1 = sqrtf(Ykr * Ykr + Yki * Yki);
        float s1 = fmaxf(m1 + b1v, 0.f) / (m1 + 1e-6f);
        Ykr *= s1; Yki *= s1;
        // gate+modrelu bin k2
        float g2r = gre[gbase + k2], g2i = gim[gbase + k2], b2v = mrb[mbase + k2];
        float Yk2r = Vk2r * g2r - Vk2i * g2i, Yk2i = Vk2r * g2i + Vk2i * g2r;
        float m2 = sqrtf(Yk2r * Yk2r + Yk2i * Yk2i);
        float s2 = fmaxf(m2 + b2v, 0.f) / (m2 + 1e-6f);
        Yk2r *= s2; Yk2i *= s2;
        // inverse untangle: E' = (Yk + conj(Yk2))/2 ; F = (Yk - conj(Yk2))/2
        float Epr = 0.5f * (Ykr + Yk2r), Epi = 0.5f * (Yki - Yk2i);
        float Fr = 0.5f * (Ykr - Yk2r), Fi = 0.5f * (Yki + Yk2i);
        float CWFr = cs * Fr + sn * Fi;   // Re(conj(W)*F) ; also Re(W*conj(F))
        float CWFi = cs * Fi - sn * Fr;   // Im(conj(W)*F) = -Im(W*conj(F))
        Zp[sA] = make_float2(Epr - CWFi, Epi + CWFr);   // Z'[k]  = E' + i*conj(W)*F
        Zp[sB] = make_float2(Epr + CWFi, -Epi + CWFr);  // Z'[k2] = conj(E') + i*W*conj(F)
    }
    if (t == 0) {  // bins 0 and 2048 (both real after irfft convention)
        float2 Z0 = Zp[P8(0)];
        float V0 = Z0.x + Z0.y, VN = Z0.x - Z0.y;
        float g0r = gre[gbase], g0i = gim[gbase], b0v = mrb[mbase];
        float y0r = V0 * g0r, y0i = V0 * g0i;
        float m0 = sqrtf(y0r * y0r + y0i * y0i);
        float Y0 = y0r * (fmaxf(m0 + b0v, 0.f) / (m0 + 1e-6f));
        float gNr = gre[gbase + 2048], gNi = gim[gbase + 2048], bNv = mrb[mbase + 2048];
        float yNr = VN * gNr, yNi = VN * gNi;
        float mN = sqrtf(yNr * yNr + yNi * yNi);
        float YN = yNr * (fmaxf(mN + bNv, 0.f) / (mN + 1e-6f));
        Zp[P8(0)] = make_float2(0.5f * (Y0 + YN), 0.5f * (Y0 - YN));
    }
    __syncthreads();

    // ---- inv S4': radix-4, D=1 ----
    {
        int base = t * 8;
#pragma unroll
        for (int q = 0; q < 4; ++q) { x[q] = Zp[P8(base + q)]; x[4 + q] = Zp[P8(base + 4 + q)]; }
        dft4v<-1>(x);
        dft4v<-1>(x + 4);
#pragma unroll
        for (int q = 0; q < 4; ++q) { Zp[P8(base + q)] = x[q]; Zp[P8(base + 4 + q)] = x[4 + q]; }
    }
    __syncthreads();
    // ---- inv S3' ----
    {
        int g = t >> 2, j = t & 3, base = g * 32 + j;
#pragma unroll
        for (int r = 0; r < 8; ++r) x[r] = Zp[P8(base + r * 4)];
        tw8<-1>(x, j, 1.0f / 32.0f);
        dft8v<-1>(x);
#pragma unroll
        for (int r = 0; r < 8; ++r) Zp[P8(base + r * 4)] = x[r];
    }
    __syncthreads();
    // ---- inv S2' ----
    {
        int g = t >> 5, j = t & 31, base = g * 256 + j;
#pragma unroll
        for (int r = 0; r < 8; ++r) x[r] = Zp[P8(base + r * 32)];
        tw8<-1>(x, j, 1.0f / 256.0f);
        dft8v<-1>(x);
#pragma unroll
        for (int r = 0; r < 8; ++r) Zp[P8(base + r * 32)] = x[r];
    }
    __syncthreads();
    // ---- inv S1' + scale + pack + direct coalesced store ----
    {
#pragma unroll
        for (int r = 0; r < 8; ++r) x[r] = Zp[P8(r * 256 + t)];
        tw8<-1>(x, t, 1.0f / 2048.0f);
        dft8v<-1>(x);
        float sc = gwp1[bh * 64 + dh] * (1.0f / 2048.0f);
        unsigned int* row32 = (unsigned int*)row;
#pragma unroll
        for (int r = 0; r < 8; ++r) {
            __bf16 h1 = (__bf16)(x[r].x * sc);
            __bf16 h2 = (__bf16)(x[r].y * sc);
            unsigned int u = (unsigned int)__builtin_bit_cast(unsigned short, h1) |
                             ((unsigned int)__builtin_bit_cast(unsigned short, h2) << 16);
            row32[t + 256 * r] = u;   // = (y[2m], y[2m+1]) at m = t + 256r
        }
    }
}

// ---------------- transpose: vt[b][e][l] bf16 -> ybf[b][l][e] bf16 ----------------
__global__ __launch_bounds__(256) void k_t2(const __bf16* __restrict__ vt, __bf16* __restrict__ ybf) {
    __shared__ __bf16 tl[64][66];
    int e0 = blockIdx.x * 64, l0 = blockIdx.y * 64, b = blockIdx.z;
    int t = threadIdx.x;
    const __bf16* src = vt + ((size_t)b << 22);
    __bf16* dst = ybf + ((size_t)b << 22);
    int er = t >> 3, lc = (t & 7) * 8;
#pragma unroll
    for (int it = 0; it < 2; ++it) {
        int e = er + it * 32;
        bf16_8 v = *(const bf16_8*)&src[(size_t)(e0 + e) * LSEQ + l0 + lc];
#pragma unroll
        for (int j = 0; j < 8; ++j) tl[e][lc + j] = v[j];
    }
    __syncthreads();
    int lr = t >> 3, ec = (t & 7) * 8;
#pragma unroll
    for (int it = 0; it < 2; ++it) {
        int l = lr + it * 32;
        bf16_8 v;
#pragma unroll
        for (int j = 0; j < 8; ++j) v[j] = tl[ec + j][l];
        *(bf16_8*)&dst[(size_t)(l0 + l) * DDIM + e0 + ec] = v;
    }
}

extern "C" void kernel_launch(void* const* d_in, const int* in_sizes, int n_in,
                              void* d_out, int out_size, void* d_ws, size_t ws_size,
                              hipStream_t stream) {
    const float* x      = (const float*)d_in[0];
    const float* Wq     = (const float*)d_in[1];
    const float* Wv     = (const float*)d_in[2];
    const float* Wo     = (const float*)d_in[3];
    const float* ln_g_s = (const float*)d_in[4];
    const float* ln_g_b = (const float*)d_in[5];
    const float* W1     = (const float*)d_in[6];
    const float* b1     = (const float*)d_in[7];
    const float* W2     = (const float*)d_in[8];
    const float* b2     = (const float*)d_in[9];
    const float* mrb    = (const float*)d_in[10];
    const float* ln_w_s = (const float*)d_in[11];
    const float* ln_w_b = (const float*)d_in[12];
    const float* Ww1    = (const float*)d_in[13];
    const float* bw1    = (const float*)d_in[14];
    const float* Ww2    = (const float*)d_in[15];
    const float* bw2    = (const float*)d_in[16];
    float* out = (float*)d_out;

    char* W = (char*)d_ws;
    __bf16* xbf = (__bf16*)W;                       // 33,554,432 B (later aliased as ybf)
    __bf16* ybf = xbf;
    __bf16* Wvb = (__bf16*)(W + 33554432);          // 2 MB
    __bf16* Wob = (__bf16*)(W + 35651584);          // 2 MB
    float*  xbp = (float*)(W + 37748736);           // 65536 f
    float*  xbar= (float*)(W + 38010880);           // 4096 f
    float*  qbar= (float*)(W + 38027264);           // 4096 f
    float*  h1g = (float*)(W + 38043648);           // 16384 f
    float*  gwp1= (float*)(W + 38109184);           // 4096 f
    float*  gre = (float*)(W + 38125568);           // 131136 f
    float*  gim = (float*)(W + 38650112);           // 131136 f

    __bf16* vt = (__bf16*)d_out;                    // scratch inside d_out

    k_xbar_partial<<<dim3(4, 16, 4), 256, 0, stream>>>(x, xbp, xbf);
    k_cvt<<<1024, 256, 0, stream>>>(Wv, Wvb, DDIM * DDIM);
    k_cvt<<<1024, 256, 0, stream>>>(Wo, Wob, DDIM * DDIM);
    k_xbar_reduce<<<dim3(4, 4), 256, 0, stream>>>(xbp, xbar);
    k_qbar<<<256, 256, 0, stream>>>(xbar, Wq, qbar);
    k_mlp<<<64, 256, 0, stream>>>(qbar, ln_g_s, ln_g_b, W1, b1, ln_w_s, ln_w_b,
                                  Ww1, bw1, Ww2, bw2, h1g, gwp1);
    k_gate<<<1025, 256, 0, stream>>>(h1g, W2, b2, gre, gim);
    k_vgemm<<<dim3(8, 32, 4), 256, 0, stream>>>(xbf, Wvb, vt);
    k_fft<<<4096, 256, 0, stream>>>(vt, gre, gim, mrb, gwp1);
    k_t2<<<dim3(16, 64, 4), 256, 0, stream>>>(vt, ybf);
    k_ogemm<<<dim3(8, 32, 4), 256, 0, stream>>>(ybf, Wob, out);
}

// Round 7
// 229.198 us; speedup vs baseline: 5.2195x; 1.0688x over previous
//
#include <hip/hip_runtime.h>
#include <math.h>

#define LSEQ 4096
#define DDIM 1024
#define NB 4
#define NH 16
#define DHD 64
#define NFREQ 2049
#define NFMAX 4097

typedef __bf16 bf16_8 __attribute__((ext_vector_type(8)));
typedef float f32x4 __attribute__((ext_vector_type(4)));

__device__ __forceinline__ float gelu_exact(float v) {
    return 0.5f * v * (1.0f + erff(v * 0.70710678118654752440f));
}

__device__ __forceinline__ void gload16(const void* g, void* l) {
    __builtin_amdgcn_global_load_lds((const __attribute__((address_space(1))) char*)g,
                                     (__attribute__((address_space(3))) char*)l, 16, 0, 0);
}

// ---------------- xbar partial + x -> bf16 cast (single pass over x) ----------------
__global__ __launch_bounds__(256) void k_xbar_partial(const float* __restrict__ x, float* __restrict__ xbp,
                                                      __bf16* __restrict__ xbf) {
    int d = blockIdx.x * 256 + threadIdx.x;
    int chunk = blockIdx.y;
    int b = blockIdx.z;
    size_t base = ((size_t)b * LSEQ + (size_t)chunk * 256) * DDIM + d;
    float acc = 0.f;
    for (int l = 0; l < 256; ++l) {
        float v = x[base + (size_t)l * DDIM];
        acc += v;
        xbf[base + (size_t)l * DDIM] = (__bf16)v;
    }
    xbp[(size_t)(b * 16 + chunk) * DDIM + d] = acc;
}

__global__ __launch_bounds__(256) void k_xbar_reduce(const float* __restrict__ xbp, float* __restrict__ xbar) {
    int d = blockIdx.x * 256 + threadIdx.x;
    int b = blockIdx.y;
    float acc = 0.f;
    for (int c = 0; c < 16; ++c) acc += xbp[(size_t)(b * 16 + c) * DDIM + d];
    xbar[b * DDIM + d] = acc * (1.0f / LSEQ);
}

// ---------------- weight fp32 -> bf16 ----------------
__global__ __launch_bounds__(256) void k_cvt(const float* __restrict__ s, __bf16* __restrict__ d, int n) {
    int i = (blockIdx.x * 256 + threadIdx.x) * 4;
    if (i < n) {
        float4 v = *(const float4*)(s + i);
        d[i] = (__bf16)v.x; d[i + 1] = (__bf16)v.y; d[i + 2] = (__bf16)v.z; d[i + 3] = (__bf16)v.w;
    }
}

// ---------------- q_bar = xbar @ Wq^T ----------------
__global__ __launch_bounds__(256) void k_qbar(const float* __restrict__ xbar, const float* __restrict__ Wq,
                                              float* __restrict__ qbar) {
    int lane = threadIdx.x & 63;
    int e = blockIdx.x * 4 + (threadIdx.x >> 6);
    const float* wrow = Wq + (size_t)e * DDIM;
    float a0 = 0, a1 = 0, a2 = 0, a3 = 0;
    for (int i = 0; i < 16; ++i) {
        int d = lane + i * 64;
        float w = wrow[d];
        a0 += w * xbar[d];
        a1 += w * xbar[DDIM + d];
        a2 += w * xbar[2 * DDIM + d];
        a3 += w * xbar[3 * DDIM + d];
    }
    for (int off = 32; off > 0; off >>= 1) {
        a0 += __shfl_down(a0, off);
        a1 += __shfl_down(a1, off);
        a2 += __shfl_down(a2, off);
        a3 += __shfl_down(a3, off);
    }
    if (lane == 0) {
        qbar[e] = a0;
        qbar[DDIM + e] = a1;
        qbar[2 * DDIM + e] = a2;
        qbar[3 * DDIM + e] = a3;
    }
}

// ---------------- per-(b,h) MLPs ----------------
__global__ __launch_bounds__(256) void k_mlp(const float* __restrict__ qbar,
                                             const float* __restrict__ ln_g_s, const float* __restrict__ ln_g_b,
                                             const float* __restrict__ W1, const float* __restrict__ b1,
                                             const float* __restrict__ ln_w_s, const float* __restrict__ ln_w_b,
                                             const float* __restrict__ Ww1, const float* __restrict__ bw1,
                                             const float* __restrict__ Ww2, const float* __restrict__ bw2,
                                             float* __restrict__ h1g, float* __restrict__ gwp1) {
    int bh = blockIdx.x;
    __shared__ float q[64], hg[64], hw[64], g1[64];
    __shared__ float sm, sv;
    int t = threadIdx.x;
    if (t < 64) q[t] = qbar[bh * 64 + t];
    __syncthreads();
    if (t == 0) {
        float m = 0;
        for (int i = 0; i < 64; ++i) m += q[i];
        m *= (1.0f / 64.0f);
        float v = 0;
        for (int i = 0; i < 64; ++i) { float dd = q[i] - m; v += dd * dd; }
        v *= (1.0f / 64.0f);
        sm = m; sv = v;
    }
    __syncthreads();
    if (t < 64) {
        float n = (q[t] - sm) * rsqrtf(sv + 1e-5f);
        hg[t] = n * ln_g_s[t] + ln_g_b[t];
        hw[t] = n * ln_w_s[t] + ln_w_b[t];
    }
    __syncthreads();
    {
        int f = t;
        const float* w = W1 + (size_t)f * 64;
        float s = b1[f];
        for (int d0 = 0; d0 < 64; ++d0) s += hg[d0] * w[d0];
        h1g[(size_t)bh * 256 + f] = gelu_exact(s);
    }
    if (t < 64) {
        const float* w = Ww1 + (size_t)t * 64;
        float s = bw1[t];
        for (int k = 0; k < 64; ++k) s += hw[k] * w[k];
        g1[t] = gelu_exact(s);
    }
    __syncthreads();
    if (t < 64) {
        const float* w = Ww2 + (size_t)t * 64;
        float s = bw2[t];
        for (int k = 0; k < 64; ++k) s += g1[k] * w[k];
        gwp1[bh * 64 + t] = 1.0f + 1.0f / (1.0f + expf(-s));
    }
}

// ---------------- gate rows ----------------
__global__ __launch_bounds__(256) void k_gate(const float* __restrict__ h1g, const float* __restrict__ W2,
                                              const float* __restrict__ b2,
                                              float* __restrict__ gre, float* __restrict__ gim) {
    int task = blockIdx.x * 4 + (threadIdx.x >> 6);
    if (task >= 2 * NFREQ) return;
    int lane = threadIdx.x & 63;
    int part = task >= NFREQ;
    int f = task - part * NFREQ;
    int row = part ? (NFMAX + f) : f;
    const float* w = W2 + (size_t)row * 256;
    float w0 = w[lane], w1 = w[64 + lane], w2 = w[128 + lane], w3 = w[192 + lane];
    float bias = b2[row];
    float* dst = part ? gim : gre;
    for (int bh = 0; bh < 64; ++bh) {
        const float* hr = h1g + (size_t)bh * 256;
        float p = w0 * hr[lane] + w1 * hr[64 + lane] + w2 * hr[128 + lane] + w3 * hr[192 + lane];
        for (int off = 32; off > 0; off >>= 1) p += __shfl_down(p, off);
        if (lane == 0) dst[(size_t)bh * NFREQ + f] = p + bias;
    }
}

// ---------------- bf16 MFMA GEMM core ----------------
__device__ __forceinline__ void gemm_core(const __bf16* __restrict__ A, const __bf16* __restrict__ B,
                                          int m0, int n0, __bf16* As, __bf16* Bs, f32x4 (&acc)[4][4]) {
    int t = threadIdx.x;
    int lane = t & 63, w = t >> 6;
    int lrow = lane & 15, lk = (lane >> 4) * 8;
    int wm = (w >> 1) * 64, wn = (w & 1) * 64;
#pragma unroll
    for (int mi = 0; mi < 4; ++mi)
#pragma unroll
        for (int ni = 0; ni < 4; ++ni) acc[mi][ni] = (f32x4){0.f, 0.f, 0.f, 0.f};
    for (int k0 = 0; k0 < 1024; k0 += 32) {
#pragma unroll
        for (int i = 0; i < 2; ++i) {
            int r = w * 32 + i * 16 + (lane >> 2);
            int kc = k0 + (lane & 3) * 8;
            gload16(A + ((size_t)(m0 + r) << 10) + kc, &As[(w * 32 + i * 16) * 32]);
            gload16(B + ((size_t)(n0 + r) << 10) + kc, &Bs[(w * 32 + i * 16) * 32]);
        }
        __syncthreads();
        bf16_8 af[4], bfr[4];
#pragma unroll
        for (int mi = 0; mi < 4; ++mi) af[mi] = *(const bf16_8*)&As[(wm + mi * 16 + lrow) * 32 + lk];
#pragma unroll
        for (int ni = 0; ni < 4; ++ni) bfr[ni] = *(const bf16_8*)&Bs[(wn + ni * 16 + lrow) * 32 + lk];
#pragma unroll
        for (int mi = 0; mi < 4; ++mi)
#pragma unroll
            for (int ni = 0; ni < 4; ++ni)
                acc[mi][ni] = __builtin_amdgcn_mfma_f32_16x16x32_bf16(af[mi], bfr[ni], acc[mi][ni], 0, 0, 0);
        __syncthreads();
    }
}

// XCD-aware swizzle: 1024 blocks, 8 XCDs -> XCD k owns contiguous work chunk
// [k*128, (k+1)*128): 16 m0-tiles x all 8 n0 -> A-tile L2-resident across its 8 n0 blocks.
__device__ __forceinline__ void swz_decode(int bid, int& n0, int& m0, int& b) {
    int swz = (bid & 7) * 128 + (bid >> 3);
    n0 = (swz & 7) << 7;
    m0 = ((swz >> 3) & 31) << 7;
    b = swz >> 8;
}

// vgemm: vt[b][e][l] (bf16) = (x @ Wv^T)^T
__global__ __launch_bounds__(256) void k_vgemm(const __bf16* __restrict__ xbf, const __bf16* __restrict__ Wvb,
                                               __bf16* __restrict__ vt) {
    __shared__ __align__(16) __bf16 As[128 * 32];
    __shared__ __align__(16) __bf16 Bs[128 * 32];
    __shared__ __bf16 st[4][16][68];
    int n0, m0, b;
    swz_decode(blockIdx.x, n0, m0, b);
    f32x4 acc[4][4];
    gemm_core(xbf + ((size_t)b << 22), Wvb, m0, n0, As, Bs, acc);
    int t = threadIdx.x;
    int lane = t & 63, w = t >> 6;
    int wm = (w >> 1) * 64, wn = (w & 1) * 64;
    size_t vbase = ((size_t)b << 22);
#pragma unroll
    for (int ni = 0; ni < 4; ++ni) {
#pragma unroll
        for (int mi = 0; mi < 4; ++mi)
#pragma unroll
            for (int r = 0; r < 4; ++r)
                st[w][lane & 15][mi * 16 + (lane >> 4) * 4 + r] = (__bf16)acc[mi][ni][r];
        asm volatile("" ::: "memory");
#pragma unroll
        for (int er = 0; er < 16; ++er) {
            vt[vbase + (size_t)(n0 + wn + ni * 16 + er) * LSEQ + m0 + wm + lane] = st[w][er][lane];
        }
        asm volatile("" ::: "memory");
    }
}

// ogemm: out[b][l][e2] (fp32) = ybf @ Wo^T
__global__ __launch_bounds__(256) void k_ogemm(const __bf16* __restrict__ ybf, const __bf16* __restrict__ Wob,
                                               float* __restrict__ out) {
    __shared__ __align__(16) __bf16 As[128 * 32];
    __shared__ __align__(16) __bf16 Bs[128 * 32];
    int n0, m0, b;
    swz_decode(blockIdx.x, n0, m0, b);
    f32x4 acc[4][4];
    gemm_core(ybf + ((size_t)b << 22), Wob, m0, n0, As, Bs, acc);
    int t = threadIdx.x;
    int lane = t & 63, w = t >> 6;
    int wm = (w >> 1) * 64, wn = (w & 1) * 64;
    float* ob = out + ((size_t)b << 22);
#pragma unroll
    for (int mi = 0; mi < 4; ++mi)
#pragma unroll
        for (int ni = 0; ni < 4; ++ni)
#pragma unroll
            for (int r = 0; r < 4; ++r)
                ob[(size_t)(m0 + wm + mi * 16 + (lane >> 4) * 4 + r) * DDIM + n0 + wn + ni * 16 + (lane & 15)] =
                    acc[mi][ni][r];
}

// ================= rfft4096 per channel via cfft2048 (even/odd pack), radix 8-8-8-4 =================
__device__ __forceinline__ float2 cmul(float2 a, float2 b) {
    return make_float2(a.x * b.x - a.y * b.y, a.x * b.y + a.y * b.x);
}
__device__ __forceinline__ int P8(int i) { return i + (i >> 3) + (i >> 8); }
// storage slot of bin k after DIF stages radix 8(D=256),8(D=32),8(D=4),4(D=1)
__device__ __forceinline__ int SR8(int k) {
    return ((k & 7) << 8) | (((k >> 3) & 7) << 5) | (((k >> 6) & 7) << 2) | (k >> 9);
}

template <int S>  // S=1 fwd (e^{-i..}), S=-1 inverse
__device__ __forceinline__ void dft4v(float2* x) {
    float2 t0 = make_float2(x[0].x + x[2].x, x[0].y + x[2].y);
    float2 t1 = make_float2(x[0].x - x[2].x, x[0].y - x[2].y);
    float2 t2 = make_float2(x[1].x + x[3].x, x[1].y + x[3].y);
    float2 t3 = make_float2(x[1].x - x[3].x, x[1].y - x[3].y);
    float2 j3 = (S == 1) ? make_float2(t3.y, -t3.x) : make_float2(-t3.y, t3.x);
    x[0] = make_float2(t0.x + t2.x, t0.y + t2.y);
    x[2] = make_float2(t0.x - t2.x, t0.y - t2.y);
    x[1] = make_float2(t1.x + j3.x, t1.y + j3.y);
    x[3] = make_float2(t1.x - j3.x, t1.y - j3.y);
}

template <int S>
__device__ __forceinline__ void dft8v(float2* x) {
    float2 e[4] = {x[0], x[2], x[4], x[6]};
    float2 o[4] = {x[1], x[3], x[5], x[7]};
    dft4v<S>(e);
    dft4v<S>(o);
    const float c = 0.7071067811865476f;
    const float sg = (S == 1) ? -1.f : 1.f;
    o[1] = cmul(o[1], make_float2(c, sg * c));
    o[2] = (S == 1) ? make_float2(o[2].y, -o[2].x) : make_float2(-o[2].y, o[2].x);
    o[3] = cmul(o[3], make_float2(-c, sg * c));
    x[0] = make_float2(e[0].x + o[0].x, e[0].y + o[0].y);
    x[4] = make_float2(e[0].x - o[0].x, e[0].y - o[0].y);
    x[1] = make_float2(e[1].x + o[1].x, e[1].y + o[1].y);
    x[5] = make_float2(e[1].x - o[1].x, e[1].y - o[1].y);
    x[2] = make_float2(e[2].x + o[2].x, e[2].y + o[2].y);
    x[6] = make_float2(e[2].x - o[2].x, e[2].y - o[2].y);
    x[3] = make_float2(e[3].x + o[3].x, e[3].y + o[3].y);
    x[7] = make_float2(e[3].x - o[3].x, e[3].y - o[3].y);
}

template <int S>
__device__ __forceinline__ void tw8(float2* x, int j, float invN) {
    float base = ((S == 1) ? -6.283185307179586f : 6.283185307179586f) * invN;
#pragma unroll
    for (int r = 1; r < 8; ++r) {
        float sn, cs;
        __sincosf(base * (float)(j * r), &sn, &cs);
        x[r] = cmul(x[r], make_float2(cs, sn));
    }
}

__global__ __launch_bounds__(256, 2) void k_fft(__bf16* __restrict__ vty,
                                                const float* __restrict__ gre, const float* __restrict__ gim,
                                                const float* __restrict__ mrb, const float* __restrict__ gwp1) {
    __shared__ float2 Zp[2312];
    int pid = blockIdx.x;
    int b = pid >> 10, e = pid & 1023;
    int h = e >> 6, dh = e & 63;
    int bh = b * 16 + h;
    size_t gbase = (size_t)bh * NFREQ;
    size_t mbase = (size_t)h * NFMAX;
    __bf16* row = vty + ((size_t)b << 22) + ((size_t)e << 12);
    int t = threadIdx.x;

    // ---- load: z[m] = (v[2m], v[2m+1]) ----
#pragma unroll
    for (int cc = 0; cc < 2; ++cc) {
        int c = t + cc * 256;
        bf16_8 a = *(const bf16_8*)&row[c * 8];
#pragma unroll
        for (int q = 0; q < 4; ++q)
            Zp[P8(c * 4 + q)] = make_float2((float)a[2 * q], (float)a[2 * q + 1]);
    }
    __syncthreads();

    float2 x[8];
    // ---- fwd S1: radix-8, D=256 ----
    {
#pragma unroll
        for (int r = 0; r < 8; ++r) x[r] = Zp[P8(r * 256 + t)];
        dft8v<1>(x);
        tw8<1>(x, t, 1.0f / 2048.0f);
#pragma unroll
        for (int r = 0; r < 8; ++r) Zp[P8(r * 256 + t)] = x[r];
    }
    __syncthreads();
    // ---- fwd S2: radix-8, D=32 ----
    {
        int g = t >> 5, j = t & 31, base = g * 256 + j;
#pragma unroll
        for (int r = 0; r < 8; ++r) x[r] = Zp[P8(base + r * 32)];
        dft8v<1>(x);
        tw8<1>(x, j, 1.0f / 256.0f);
#pragma unroll
        for (int r = 0; r < 8; ++r) Zp[P8(base + r * 32)] = x[r];
    }
    __syncthreads();
    // ---- fwd S3: radix-8, D=4 ----
    {
        int g = t >> 2, j = t & 3, base = g * 32 + j;
#pragma unroll
        for (int r = 0; r < 8; ++r) x[r] = Zp[P8(base + r * 4)];
        dft8v<1>(x);
        tw8<1>(x, j, 1.0f / 32.0f);
#pragma unroll
        for (int r = 0; r < 8; ++r) Zp[P8(base + r * 4)] = x[r];
    }
    __syncthreads();
    // ---- fwd S4: radix-4, D=1 (two per thread) ----
    {
        int base = t * 8;
#pragma unroll
        for (int q = 0; q < 4; ++q) { x[q] = Zp[P8(base + q)]; x[4 + q] = Zp[P8(base + 4 + q)]; }
        dft4v<1>(x);
        dft4v<1>(x + 4);
#pragma unroll
        for (int q = 0; q < 4; ++q) { Zp[P8(base + q)] = x[q]; Zp[P8(base + 4 + q)] = x[4 + q]; }
    }
    __syncthreads();

    // ---- untangle + gate + modrelu + re-tangle (digit-reversed domain) ----
#pragma unroll
    for (int r = 0; r < 4; ++r) {
        int k = 1 + (r << 8) + t;
        int k2 = 2048 - k;
        int sA = P8(SR8(k)), sB = P8(SR8(k2));
        float2 Za = Zp[sA], Zb = Zp[sB];
        float Er = 0.5f * (Za.x + Zb.x), Ei = 0.5f * (Za.y - Zb.y);
        float Dr = 0.5f * (Za.x - Zb.x), Di = 0.5f * (Za.y + Zb.y);
        float sn, cs;
        __sincosf(-1.5339807878856412e-3f * (float)k, &sn, &cs);   // W = e^{-2pi i k/4096}
        float WDr = cs * Dr - sn * Di, WDi = cs * Di + sn * Dr;    // W*D
        float Tr = -WDi, Ti = WDr;                                  // T = i*W*D
        float Vkr = Er - Tr, Vki = Ei - Ti;                         // V[k]  = E - T
        float Vk2r = Er + Tr, Vk2i = -(Ei + Ti);                    // V[k2] = conj(E + T)
        float g1r = gre[gbase + k], g1i = gim[gbase + k], b1v = mrb[mbase + k];
        float Ykr = Vkr * g1r - Vki * g1i, Yki = Vkr * g1i + Vki * g1r;
        float m1 = sqrtf(Ykr * Ykr + Yki * Yki);
        float s1 = fmaxf(m1 + b1v, 0.f) / (m1 + 1e-6f);
        Ykr *= s1; Yki *= s1;
        float g2r = gre[gbase + k2], g2i = gim[gbase + k2], b2v = mrb[mbase + k2];
        float Yk2r = Vk2r * g2r - Vk2i * g2i, Yk2i = Vk2r * g2i + Vk2i * g2r;
        float m2 = sqrtf(Yk2r * Yk2r + Yk2i * Yk2i);
        float s2 = fmaxf(m2 + b2v, 0.f) / (m2 + 1e-6f);
        Yk2r *= s2; Yk2i *= s2;
        float Epr = 0.5f * (Ykr + Yk2r), Epi = 0.5f * (Yki - Yk2i);
        float Fr = 0.5f * (Ykr - Yk2r), Fi = 0.5f * (Yki + Yk2i);
        float CWFr = cs * Fr + sn * Fi;
        float CWFi = cs * Fi - sn * Fr;
        Zp[sA] = make_float2(Epr - CWFi, Epi + CWFr);
        Zp[sB] = make_float2(Epr + CWFi, -Epi + CWFr);
    }
    if (t == 0) {
        float2 Z0 = Zp[P8(0)];
        float V0 = Z0.x + Z0.y, VN = Z0.x - Z0.y;
        float g0r = gre[gbase], g0i = gim[gbase], b0v = mrb[mbase];
        float y0r = V0 * g0r, y0i = V0 * g0i;
        float m0 = sqrtf(y0r * y0r + y0i * y0i);
        float Y0 = y0r * (fmaxf(m0 + b0v, 0.f) / (m0 + 1e-6f));
        float gNr = gre[gbase + 2048], gNi = gim[gbase + 2048], bNv = mrb[mbase + 2048];
        float yNr = VN * gNr, yNi = VN * gNi;
        float mN = sqrtf(yNr * yNr + yNi * yNi);
        float YN = yNr * (fmaxf(mN + bNv, 0.f) / (mN + 1e-6f));
        Zp[P8(0)] = make_float2(0.5f * (Y0 + YN), 0.5f * (Y0 - YN));
    }
    __syncthreads();

    // ---- inv S4': radix-4, D=1 ----
    {
        int base = t * 8;
#pragma unroll
        for (int q = 0; q < 4; ++q) { x[q] = Zp[P8(base + q)]; x[4 + q] = Zp[P8(base + 4 + q)]; }
        dft4v<-1>(x);
        dft4v<-1>(x + 4);
#pragma unroll
        for (int q = 0; q < 4; ++q) { Zp[P8(base + q)] = x[q]; Zp[P8(base + 4 + q)] = x[4 + q]; }
    }
    __syncthreads();
    // ---- inv S3' ----
    {
        int g = t >> 2, j = t & 3, base = g * 32 + j;
#pragma unroll
        for (int r = 0; r < 8; ++r) x[r] = Zp[P8(base + r * 4)];
        tw8<-1>(x, j, 1.0f / 32.0f);
        dft8v<-1>(x);
#pragma unroll
        for (int r = 0; r < 8; ++r) Zp[P8(base + r * 4)] = x[r];
    }
    __syncthreads();
    // ---- inv S2' ----
    {
        int g = t >> 5, j = t & 31, base = g * 256 + j;
#pragma unroll
        for (int r = 0; r < 8; ++r) x[r] = Zp[P8(base + r * 32)];
        tw8<-1>(x, j, 1.0f / 256.0f);
        dft8v<-1>(x);
#pragma unroll
        for (int r = 0; r < 8; ++r) Zp[P8(base + r * 32)] = x[r];
    }
    __syncthreads();
    // ---- inv S1' + scale + pack + direct coalesced store ----
    {
#pragma unroll
        for (int r = 0; r < 8; ++r) x[r] = Zp[P8(r * 256 + t)];
        tw8<-1>(x, t, 1.0f / 2048.0f);
        dft8v<-1>(x);
        float sc = gwp1[bh * 64 + dh] * (1.0f / 2048.0f);
        unsigned int* row32 = (unsigned int*)row;
#pragma unroll
        for (int r = 0; r < 8; ++r) {
            __bf16 h1 = (__bf16)(x[r].x * sc);
            __bf16 h2 = (__bf16)(x[r].y * sc);
            unsigned int u = (unsigned int)__builtin_bit_cast(unsigned short, h1) |
                             ((unsigned int)__builtin_bit_cast(unsigned short, h2) << 16);
            row32[t + 256 * r] = u;
        }
    }
}

// ---------------- transpose: vt[b][e][l] bf16 -> ybf[b][l][e] bf16 ----------------
__global__ __launch_bounds__(256) void k_t2(const __bf16* __restrict__ vt, __bf16* __restrict__ ybf) {
    __shared__ __bf16 tl[64][66];
    int e0 = blockIdx.x * 64, l0 = blockIdx.y * 64, b = blockIdx.z;
    int t = threadIdx.x;
    const __bf16* src = vt + ((size_t)b << 22);
    __bf16* dst = ybf + ((size_t)b << 22);
    int er = t >> 3, lc = (t & 7) * 8;
#pragma unroll
    for (int it = 0; it < 2; ++it) {
        int e = er + it * 32;
        bf16_8 v = *(const bf16_8*)&src[(size_t)(e0 + e) * LSEQ + l0 + lc];
#pragma unroll
        for (int j = 0; j < 8; ++j) tl[e][lc + j] = v[j];
    }
    __syncthreads();
    int lr = t >> 3, ec = (t & 7) * 8;
#pragma unroll
    for (int it = 0; it < 2; ++it) {
        int l = lr + it * 32;
        bf16_8 v;
#pragma unroll
        for (int j = 0; j < 8; ++j) v[j] = tl[ec + j][l];
        *(bf16_8*)&dst[(size_t)(l0 + l) * DDIM + e0 + ec] = v;
    }
}

extern "C" void kernel_launch(void* const* d_in, const int* in_sizes, int n_in,
                              void* d_out, int out_size, void* d_ws, size_t ws_size,
                              hipStream_t stream) {
    const float* x      = (const float*)d_in[0];
    const float* Wq     = (const float*)d_in[1];
    const float* Wv     = (const float*)d_in[2];
    const float* Wo     = (const float*)d_in[3];
    const float* ln_g_s = (const float*)d_in[4];
    const float* ln_g_b = (const float*)d_in[5];
    const float* W1     = (const float*)d_in[6];
    const float* b1     = (const float*)d_in[7];
    const float* W2     = (const float*)d_in[8];
    const float* b2     = (const float*)d_in[9];
    const float* mrb    = (const float*)d_in[10];
    const float* ln_w_s = (const float*)d_in[11];
    const float* ln_w_b = (const float*)d_in[12];
    const float* Ww1    = (const float*)d_in[13];
    const float* bw1    = (const float*)d_in[14];
    const float* Ww2    = (const float*)d_in[15];
    const float* bw2    = (const float*)d_in[16];
    float* out = (float*)d_out;

    char* W = (char*)d_ws;
    __bf16* xbf = (__bf16*)W;                       // 33,554,432 B (later aliased as ybf)
    __bf16* ybf = xbf;
    __bf16* Wvb = (__bf16*)(W + 33554432);          // 2 MB
    __bf16* Wob = (__bf16*)(W + 35651584);          // 2 MB
    float*  xbp = (float*)(W + 37748736);           // 65536 f
    float*  xbar= (float*)(W + 38010880);           // 4096 f
    float*  qbar= (float*)(W + 38027264);           // 4096 f
    float*  h1g = (float*)(W + 38043648);           // 16384 f
    float*  gwp1= (float*)(W + 38109184);           // 4096 f
    float*  gre = (float*)(W + 38125568);           // 131136 f
    float*  gim = (float*)(W + 38650112);           // 131136 f

    __bf16* vt = (__bf16*)d_out;                    // scratch inside d_out

    k_xbar_partial<<<dim3(4, 16, 4), 256, 0, stream>>>(x, xbp, xbf);
    k_cvt<<<1024, 256, 0, stream>>>(Wv, Wvb, DDIM * DDIM);
    k_cvt<<<1024, 256, 0, stream>>>(Wo, Wob, DDIM * DDIM);
    k_xbar_reduce<<<dim3(4, 4), 256, 0, stream>>>(xbp, xbar);
    k_qbar<<<256, 256, 0, stream>>>(xbar, Wq, qbar);
    k_mlp<<<64, 256, 0, stream>>>(qbar, ln_g_s, ln_g_b, W1, b1, ln_w_s, ln_w_b,
                                  Ww1, bw1, Ww2, bw2, h1g, gwp1);
    k_gate<<<1025, 256, 0, stream>>>(h1g, W2, b2, gre, gim);
    k_vgemm<<<1024, 256, 0, stream>>>(xbf, Wvb, vt);
    k_fft<<<4096, 256, 0, stream>>>(vt, gre, gim, mrb, gwp1);
    k_t2<<<dim3(16, 64, 4), 256, 0, stream>>>(vt, ybf);
    k_ogemm<<<1024, 256, 0, stream>>>(ybf, Wob, out);
}

// Round 8
// 224.757 us; speedup vs baseline: 5.3226x; 1.0198x over previous
//
#include <hip/hip_runtime.h>
#include <math.h>

#define LSEQ 4096
#define DDIM 1024
#define NB 4
#define NH 16
#define DHD 64
#define NFREQ 2049
#define NFMAX 4097

typedef __bf16 bf16_8 __attribute__((ext_vector_type(8)));
typedef float f32x4 __attribute__((ext_vector_type(4)));

__device__ __forceinline__ float gelu_exact(float v) {
    return 0.5f * v * (1.0f + erff(v * 0.70710678118654752440f));
}

__device__ __forceinline__ void gload16(const void* g, void* l) {
    __builtin_amdgcn_global_load_lds((const __attribute__((address_space(1))) char*)g,
                                     (__attribute__((address_space(3))) char*)l, 16, 0, 0);
}

// ---------------- xbar partial + x -> bf16 cast (single pass over x) ----------------
__global__ __launch_bounds__(256) void k_xbar_partial(const float* __restrict__ x, float* __restrict__ xbp,
                                                      __bf16* __restrict__ xbf) {
    int d = blockIdx.x * 256 + threadIdx.x;
    int chunk = blockIdx.y;
    int b = blockIdx.z;
    size_t base = ((size_t)b * LSEQ + (size_t)chunk * 256) * DDIM + d;
    float acc = 0.f;
    for (int l = 0; l < 256; ++l) {
        float v = x[base + (size_t)l * DDIM];
        acc += v;
        xbf[base + (size_t)l * DDIM] = (__bf16)v;
    }
    xbp[(size_t)(b * 16 + chunk) * DDIM + d] = acc;
}

__global__ __launch_bounds__(256) void k_xbar_reduce(const float* __restrict__ xbp, float* __restrict__ xbar) {
    int d = blockIdx.x * 256 + threadIdx.x;
    int b = blockIdx.y;
    float acc = 0.f;
    for (int c = 0; c < 16; ++c) acc += xbp[(size_t)(b * 16 + c) * DDIM + d];
    xbar[b * DDIM + d] = acc * (1.0f / LSEQ);
}

// ---------------- weight fp32 -> bf16 ----------------
__global__ __launch_bounds__(256) void k_cvt(const float* __restrict__ s, __bf16* __restrict__ d, int n) {
    int i = (blockIdx.x * 256 + threadIdx.x) * 4;
    if (i < n) {
        float4 v = *(const float4*)(s + i);
        d[i] = (__bf16)v.x; d[i + 1] = (__bf16)v.y; d[i + 2] = (__bf16)v.z; d[i + 3] = (__bf16)v.w;
    }
}

// ---------------- q_bar = xbar @ Wq^T ----------------
__global__ __launch_bounds__(256) void k_qbar(const float* __restrict__ xbar, const float* __restrict__ Wq,
                                              float* __restrict__ qbar) {
    int lane = threadIdx.x & 63;
    int e = blockIdx.x * 4 + (threadIdx.x >> 6);
    const float* wrow = Wq + (size_t)e * DDIM;
    float a0 = 0, a1 = 0, a2 = 0, a3 = 0;
    for (int i = 0; i < 16; ++i) {
        int d = lane + i * 64;
        float w = wrow[d];
        a0 += w * xbar[d];
        a1 += w * xbar[DDIM + d];
        a2 += w * xbar[2 * DDIM + d];
        a3 += w * xbar[3 * DDIM + d];
    }
    for (int off = 32; off > 0; off >>= 1) {
        a0 += __shfl_down(a0, off);
        a1 += __shfl_down(a1, off);
        a2 += __shfl_down(a2, off);
        a3 += __shfl_down(a3, off);
    }
    if (lane == 0) {
        qbar[e] = a0;
        qbar[DDIM + e] = a1;
        qbar[2 * DDIM + e] = a2;
        qbar[3 * DDIM + e] = a3;
    }
}

// ---------------- per-(b,h) MLPs ----------------
__global__ __launch_bounds__(256) void k_mlp(const float* __restrict__ qbar,
                                             const float* __restrict__ ln_g_s, const float* __restrict__ ln_g_b,
                                             const float* __restrict__ W1, const float* __restrict__ b1,
                                             const float* __restrict__ ln_w_s, const float* __restrict__ ln_w_b,
                                             const float* __restrict__ Ww1, const float* __restrict__ bw1,
                                             const float* __restrict__ Ww2, const float* __restrict__ bw2,
                                             float* __restrict__ h1g, float* __restrict__ gwp1) {
    int bh = blockIdx.x;
    __shared__ float q[64], hg[64], hw[64], g1[64];
    __shared__ float sm, sv;
    int t = threadIdx.x;
    if (t < 64) q[t] = qbar[bh * 64 + t];
    __syncthreads();
    if (t == 0) {
        float m = 0;
        for (int i = 0; i < 64; ++i) m += q[i];
        m *= (1.0f / 64.0f);
        float v = 0;
        for (int i = 0; i < 64; ++i) { float dd = q[i] - m; v += dd * dd; }
        v *= (1.0f / 64.0f);
        sm = m; sv = v;
    }
    __syncthreads();
    if (t < 64) {
        float n = (q[t] - sm) * rsqrtf(sv + 1e-5f);
        hg[t] = n * ln_g_s[t] + ln_g_b[t];
        hw[t] = n * ln_w_s[t] + ln_w_b[t];
    }
    __syncthreads();
    {
        int f = t;
        const float* w = W1 + (size_t)f * 64;
        float s = b1[f];
        for (int d0 = 0; d0 < 64; ++d0) s += hg[d0] * w[d0];
        h1g[(size_t)bh * 256 + f] = gelu_exact(s);
    }
    if (t < 64) {
        const float* w = Ww1 + (size_t)t * 64;
        float s = bw1[t];
        for (int k = 0; k < 64; ++k) s += hw[k] * w[k];
        g1[t] = gelu_exact(s);
    }
    __syncthreads();
    if (t < 64) {
        const float* w = Ww2 + (size_t)t * 64;
        float s = bw2[t];
        for (int k = 0; k < 64; ++k) s += g1[k] * w[k];
        gwp1[bh * 64 + t] = 1.0f + 1.0f / (1.0f + expf(-s));
    }
}

// ---------------- gate rows ----------------
__global__ __launch_bounds__(256) void k_gate(const float* __restrict__ h1g, const float* __restrict__ W2,
                                              const float* __restrict__ b2,
                                              float* __restrict__ gre, float* __restrict__ gim) {
    int task = blockIdx.x * 4 + (threadIdx.x >> 6);
    if (task >= 2 * NFREQ) return;
    int lane = threadIdx.x & 63;
    int part = task >= NFREQ;
    int f = task - part * NFREQ;
    int row = part ? (NFMAX + f) : f;
    const float* w = W2 + (size_t)row * 256;
    float w0 = w[lane], w1 = w[64 + lane], w2 = w[128 + lane], w3 = w[192 + lane];
    float bias = b2[row];
    float* dst = part ? gim : gre;
    for (int bh = 0; bh < 64; ++bh) {
        const float* hr = h1g + (size_t)bh * 256;
        float p = w0 * hr[lane] + w1 * hr[64 + lane] + w2 * hr[128 + lane] + w3 * hr[192 + lane];
        for (int off = 32; off > 0; off >>= 1) p += __shfl_down(p, off);
        if (lane == 0) dst[(size_t)bh * NFREQ + f] = p + bias;
    }
}

// ================= 256x256-tile, 8-wave, BK=32, double-buffered GEMM =================
// swizzle for 256 blocks: XCD k owns work ids [k*32,(k+1)*32) -> contiguous m-chunk, all n
__device__ __forceinline__ void swz256(int bid, int& n0, int& m0, int& b) {
    int w = (bid & 7) * 32 + (bid >> 3);
    b = w >> 6;
    m0 = ((w >> 2) & 15) << 8;
    n0 = (w & 3) << 8;
}

// stage 256 rows x 32 bf16 (16KB) from src[(row0+r)*1024 + kt*32 ...] into lds (linear [row][32])
__device__ __forceinline__ void g2_stage(const __bf16* __restrict__ src, int row0, int kt,
                                         __bf16* lds, int tid) {
#pragma unroll
    for (int j = 0; j < 2; ++j) {
        int c = j * 512 + tid;                    // global-side chunk (per-lane)
        int r = c >> 2, kc = (c & 3) * 8;
        __bf16* ldsbase = lds + (size_t)(j * 512 + (tid & ~63)) * 8;  // wave-uniform; HW adds lane*16B
        gload16(src + ((size_t)(row0 + r) << 10) + kt * 32 + kc, ldsbase);
    }
}

__device__ __forceinline__ void g2_core(const __bf16* __restrict__ A, const __bf16* __restrict__ B,
                                        int m0, int n0, __bf16 (*As)[256 * 32], __bf16 (*Bs)[256 * 32],
                                        f32x4 (&acc)[8][4]) {
    int tid = threadIdx.x;
    int lane = tid & 63, w = tid >> 6;
    int wm = w >> 2, wn = w & 3;
    int lrow = lane & 15, lk = (lane >> 4) * 8;
#pragma unroll
    for (int mi = 0; mi < 8; ++mi)
#pragma unroll
        for (int ni = 0; ni < 4; ++ni) acc[mi][ni] = (f32x4){0.f, 0.f, 0.f, 0.f};

    g2_stage(A, m0, 0, As[0], tid);
    g2_stage(B, n0, 0, Bs[0], tid);
    __syncthreads();
    int buf = 0;
    for (int kt = 0; kt < 32; ++kt) {
        if (kt < 31) {
            g2_stage(A, m0, kt + 1, As[buf ^ 1], tid);   // issue next tile FIRST
            g2_stage(B, n0, kt + 1, Bs[buf ^ 1], tid);   // drains at barrier, hidden under MFMA
        }
        bf16_8 af[8], bfr[4];
#pragma unroll
        for (int mi = 0; mi < 8; ++mi)
            af[mi] = *(const bf16_8*)&As[buf][(wm * 128 + mi * 16 + lrow) * 32 + lk];
#pragma unroll
        for (int ni = 0; ni < 4; ++ni)
            bfr[ni] = *(const bf16_8*)&Bs[buf][(wn * 64 + ni * 16 + lrow) * 32 + lk];
#pragma unroll
        for (int mi = 0; mi < 8; ++mi)
#pragma unroll
            for (int ni = 0; ni < 4; ++ni)
                acc[mi][ni] = __builtin_amdgcn_mfma_f32_16x16x32_bf16(af[mi], bfr[ni], acc[mi][ni], 0, 0, 0);
        __syncthreads();
        buf ^= 1;
    }
}

// vgemm: vt[b][e][l] (bf16) = (x @ Wv^T)^T  (transposed epilogue via per-wave LDS staging)
__global__ __launch_bounds__(512, 2) void k_vgemm(const __bf16* __restrict__ xbf, const __bf16* __restrict__ Wvb,
                                                  __bf16* __restrict__ vt) {
    __shared__ __align__(16) __bf16 As[2][256 * 32];
    __shared__ __align__(16) __bf16 Bs[2][256 * 32];
    __shared__ __bf16 st[8][16][68];
    int n0, m0, b;
    swz256(blockIdx.x, n0, m0, b);
    f32x4 acc[8][4];
    g2_core(xbf + ((size_t)b << 22), Wvb, m0, n0, As, Bs, acc);
    int tid = threadIdx.x;
    int lane = tid & 63, w = tid >> 6;
    int wm = w >> 2, wn = w & 3;
    size_t vbase = ((size_t)b << 22);
#pragma unroll
    for (int ni = 0; ni < 4; ++ni) {
#pragma unroll
        for (int half = 0; half < 2; ++half) {
#pragma unroll
            for (int ml = 0; ml < 4; ++ml)
#pragma unroll
                for (int r = 0; r < 4; ++r)
                    st[w][lane & 15][ml * 16 + (lane >> 4) * 4 + r] = (__bf16)acc[half * 4 + ml][ni][r];
            asm volatile("" ::: "memory");
#pragma unroll
            for (int er = 0; er < 16; ++er) {
                vt[vbase + (size_t)(n0 + wn * 64 + ni * 16 + er) * LSEQ + m0 + wm * 128 + half * 64 + lane] =
                    st[w][er][lane];
            }
            asm volatile("" ::: "memory");
        }
    }
}

// ogemm: out[b][l][e2] (fp32) = ybf @ Wo^T
__global__ __launch_bounds__(512, 2) void k_ogemm(const __bf16* __restrict__ ybf, const __bf16* __restrict__ Wob,
                                                  float* __restrict__ out) {
    __shared__ __align__(16) __bf16 As[2][256 * 32];
    __shared__ __align__(16) __bf16 Bs[2][256 * 32];
    int n0, m0, b;
    swz256(blockIdx.x, n0, m0, b);
    f32x4 acc[8][4];
    g2_core(ybf + ((size_t)b << 22), Wob, m0, n0, As, Bs, acc);
    int tid = threadIdx.x;
    int lane = tid & 63, w = tid >> 6;
    int wm = w >> 2, wn = w & 3;
    float* ob = out + ((size_t)b << 22);
#pragma unroll
    for (int mi = 0; mi < 8; ++mi)
#pragma unroll
        for (int ni = 0; ni < 4; ++ni)
#pragma unroll
            for (int r = 0; r < 4; ++r)
                ob[(size_t)(m0 + wm * 128 + mi * 16 + (lane >> 4) * 4 + r) * DDIM +
                   n0 + wn * 64 + ni * 16 + (lane & 15)] = acc[mi][ni][r];
}

// ================= rfft4096 per channel via cfft2048 (even/odd pack), radix 8-8-8-4 =================
__device__ __forceinline__ float2 cmul(float2 a, float2 b) {
    return make_float2(a.x * b.x - a.y * b.y, a.x * b.y + a.y * b.x);
}
__device__ __forceinline__ int P8(int i) { return i + (i >> 3) + (i >> 8); }
__device__ __forceinline__ int SR8(int k) {
    return ((k & 7) << 8) | (((k >> 3) & 7) << 5) | (((k >> 6) & 7) << 2) | (k >> 9);
}

template <int S>
__device__ __forceinline__ void dft4v(float2* x) {
    float2 t0 = make_float2(x[0].x + x[2].x, x[0].y + x[2].y);
    float2 t1 = make_float2(x[0].x - x[2].x, x[0].y - x[2].y);
    float2 t2 = make_float2(x[1].x + x[3].x, x[1].y + x[3].y);
    float2 t3 = make_float2(x[1].x - x[3].x, x[1].y - x[3].y);
    float2 j3 = (S == 1) ? make_float2(t3.y, -t3.x) : make_float2(-t3.y, t3.x);
    x[0] = make_float2(t0.x + t2.x, t0.y + t2.y);
    x[2] = make_float2(t0.x - t2.x, t0.y - t2.y);
    x[1] = make_float2(t1.x + j3.x, t1.y + j3.y);
    x[3] = make_float2(t1.x - j3.x, t1.y - j3.y);
}

template <int S>
__device__ __forceinline__ void dft8v(float2* x) {
    float2 e[4] = {x[0], x[2], x[4], x[6]};
    float2 o[4] = {x[1], x[3], x[5], x[7]};
    dft4v<S>(e);
    dft4v<S>(o);
    const float c = 0.7071067811865476f;
    const float sg = (S == 1) ? -1.f : 1.f;
    o[1] = cmul(o[1], make_float2(c, sg * c));
    o[2] = (S == 1) ? make_float2(o[2].y, -o[2].x) : make_float2(-o[2].y, o[2].x);
    o[3] = cmul(o[3], make_float2(-c, sg * c));
    x[0] = make_float2(e[0].x + o[0].x, e[0].y + o[0].y);
    x[4] = make_float2(e[0].x - o[0].x, e[0].y - o[0].y);
    x[1] = make_float2(e[1].x + o[1].x, e[1].y + o[1].y);
    x[5] = make_float2(e[1].x - o[1].x, e[1].y - o[1].y);
    x[2] = make_float2(e[2].x + o[2].x, e[2].y + o[2].y);
    x[6] = make_float2(e[2].x - o[2].x, e[2].y - o[2].y);
    x[3] = make_float2(e[3].x + o[3].x, e[3].y + o[3].y);
    x[7] = make_float2(e[3].x - o[3].x, e[3].y - o[3].y);
}

template <int S>
__device__ __forceinline__ void tw8(float2* x, int j, float invN) {
    float base = ((S == 1) ? -6.283185307179586f : 6.283185307179586f) * invN;
#pragma unroll
    for (int r = 1; r < 8; ++r) {
        float sn, cs;
        __sincosf(base * (float)(j * r), &sn, &cs);
        x[r] = cmul(x[r], make_float2(cs, sn));
    }
}

__global__ __launch_bounds__(256, 2) void k_fft(__bf16* __restrict__ vty,
                                                const float* __restrict__ gre, const float* __restrict__ gim,
                                                const float* __restrict__ mrb, const float* __restrict__ gwp1) {
    __shared__ float2 Zp[2312];
    int pid = blockIdx.x;
    int b = pid >> 10, e = pid & 1023;
    int h = e >> 6, dh = e & 63;
    int bh = b * 16 + h;
    size_t gbase = (size_t)bh * NFREQ;
    size_t mbase = (size_t)h * NFMAX;
    __bf16* row = vty + ((size_t)b << 22) + ((size_t)e << 12);
    int t = threadIdx.x;

#pragma unroll
    for (int cc = 0; cc < 2; ++cc) {
        int c = t + cc * 256;
        bf16_8 a = *(const bf16_8*)&row[c * 8];
#pragma unroll
        for (int q = 0; q < 4; ++q)
            Zp[P8(c * 4 + q)] = make_float2((float)a[2 * q], (float)a[2 * q + 1]);
    }
    __syncthreads();

    float2 x[8];
    {
#pragma unroll
        for (int r = 0; r < 8; ++r) x[r] = Zp[P8(r * 256 + t)];
        dft8v<1>(x);
        tw8<1>(x, t, 1.0f / 2048.0f);
#pragma unroll
        for (int r = 0; r < 8; ++r) Zp[P8(r * 256 + t)] = x[r];
    }
    __syncthreads();
    {
        int g = t >> 5, j = t & 31, base = g * 256 + j;
#pragma unroll
        for (int r = 0; r < 8; ++r) x[r] = Zp[P8(base + r * 32)];
        dft8v<1>(x);
        tw8<1>(x, j, 1.0f / 256.0f);
#pragma unroll
        for (int r = 0; r < 8; ++r) Zp[P8(base + r * 32)] = x[r];
    }
    __syncthreads();
    {
        int g = t >> 2, j = t & 3, base = g * 32 + j;
#pragma unroll
        for (int r = 0; r < 8; ++r) x[r] = Zp[P8(base + r * 4)];
        dft8v<1>(x);
        tw8<1>(x, j, 1.0f / 32.0f);
#pragma unroll
        for (int r = 0; r < 8; ++r) Zp[P8(base + r * 4)] = x[r];
    }
    __syncthreads();
    {
        int base = t * 8;
#pragma unroll
        for (int q = 0; q < 4; ++q) { x[q] = Zp[P8(base + q)]; x[4 + q] = Zp[P8(base + 4 + q)]; }
        dft4v<1>(x);
        dft4v<1>(x + 4);
#pragma unroll
        for (int q = 0; q < 4; ++q) { Zp[P8(base + q)] = x[q]; Zp[P8(base + 4 + q)] = x[4 + q]; }
    }
    __syncthreads();

#pragma unroll
    for (int r = 0; r < 4; ++r) {
        int k = 1 + (r << 8) + t;
        int k2 = 2048 - k;
        int sA = P8(SR8(k)), sB = P8(SR8(k2));
        float2 Za = Zp[sA], Zb = Zp[sB];
        float Er = 0.5f * (Za.x + Zb.x), Ei = 0.5f * (Za.y - Zb.y);
        float Dr = 0.5f * (Za.x - Zb.x), Di = 0.5f * (Za.y + Zb.y);
        float sn, cs;
        __sincosf(-1.5339807878856412e-3f * (float)k, &sn, &cs);
        float WDr = cs * Dr - sn * Di, WDi = cs * Di + sn * Dr;
        float Tr = -WDi, Ti = WDr;
        float Vkr = Er - Tr, Vki = Ei - Ti;
        float Vk2r = Er + Tr, Vk2i = -(Ei + Ti);
        float g1r = gre[gbase + k], g1i = gim[gbase + k], b1v = mrb[mbase + k];
        float Ykr = Vkr * g1r - Vki * g1i, Yki = Vkr * g1i + Vki * g1r;
        float m1 = sqrtf(Ykr * Ykr + Yki * Yki);
        float s1 = fmaxf(m1 + b1v, 0.f) / (m1 + 1e-6f);
        Ykr *= s1; Yki *= s1;
        float g2r = gre[gbase + k2], g2i = gim[gbase + k2], b2v = mrb[mbase + k2];
        float Yk2r = Vk2r * g2r - Vk2i * g2i, Yk2i = Vk2r * g2i + Vk2i * g2r;
        float m2 = sqrtf(Yk2r * Yk2r + Yk2i * Yk2i);
        float s2 = fmaxf(m2 + b2v, 0.f) / (m2 + 1e-6f);
        Yk2r *= s2; Yk2i *= s2;
        float Epr = 0.5f * (Ykr + Yk2r), Epi = 0.5f * (Yki - Yk2i);
        float Fr = 0.5f * (Ykr - Yk2r), Fi = 0.5f * (Yki + Yk2i);
        float CWFr = cs * Fr + sn * Fi;
        float CWFi = cs * Fi - sn * Fr;
        Zp[sA] = make_float2(Epr - CWFi, Epi + CWFr);
        Zp[sB] = make_float2(Epr + CWFi, -Epi + CWFr);
    }
    if (t == 0) {
        float2 Z0 = Zp[P8(0)];
        float V0 = Z0.x + Z0.y, VN = Z0.x - Z0.y;
        float g0r = gre[gbase], g0i = gim[gbase], b0v = mrb[mbase];
        float y0r = V0 * g0r, y0i = V0 * g0i;
        float m0 = sqrtf(y0r * y0r + y0i * y0i);
        float Y0 = y0r * (fmaxf(m0 + b0v, 0.f) / (m0 + 1e-6f));
        float gNr = gre[gbase + 2048], gNi = gim[gbase + 2048], bNv = mrb[mbase + 2048];
        float yNr = VN * gNr, yNi = VN * gNi;
        float mN = sqrtf(yNr * yNr + yNi * yNi);
        float YN = yNr * (fmaxf(mN + bNv, 0.f) / (mN + 1e-6f));
        Zp[P8(0)] = make_float2(0.5f * (Y0 + YN), 0.5f * (Y0 - YN));
    }
    __syncthreads();

    {
        int base = t * 8;
#pragma unroll
        for (int q = 0; q < 4; ++q) { x[q] = Zp[P8(base + q)]; x[4 + q] = Zp[P8(base + 4 + q)]; }
        dft4v<-1>(x);
        dft4v<-1>(x + 4);
#pragma unroll
        for (int q = 0; q < 4; ++q) { Zp[P8(base + q)] = x[q]; Zp[P8(base + 4 + q)] = x[4 + q]; }
    }
    __syncthreads();
    {
        int g = t >> 2, j = t & 3, base = g * 32 + j;
#pragma unroll
        for (int r = 0; r < 8; ++r) x[r] = Zp[P8(base + r * 4)];
        tw8<-1>(x, j, 1.0f / 32.0f);
        dft8v<-1>(x);
#pragma unroll
        for (int r = 0; r < 8; ++r) Zp[P8(base + r * 4)] = x[r];
    }
    __syncthreads();
    {
        int g = t >> 5, j = t & 31, base = g * 256 + j;
#pragma unroll
        for (int r = 0; r < 8; ++r) x[r] = Zp[P8(base + r * 32)];
        tw8<-1>(x, j, 1.0f / 256.0f);
        dft8v<-1>(x);
#pragma unroll
        for (int r = 0; r < 8; ++r) Zp[P8(base + r * 32)] = x[r];
    }
    __syncthreads();
    {
#pragma unroll
        for (int r = 0; r < 8; ++r) x[r] = Zp[P8(r * 256 + t)];
        tw8<-1>(x, t, 1.0f / 2048.0f);
        dft8v<-1>(x);
        float sc = gwp1[bh * 64 + dh] * (1.0f / 2048.0f);
        unsigned int* row32 = (unsigned int*)row;
#pragma unroll
        for (int r = 0; r < 8; ++r) {
            __bf16 h1 = (__bf16)(x[r].x * sc);
            __bf16 h2 = (__bf16)(x[r].y * sc);
            unsigned int u = (unsigned int)__builtin_bit_cast(unsigned short, h1) |
                             ((unsigned int)__builtin_bit_cast(unsigned short, h2) << 16);
            row32[t + 256 * r] = u;
        }
    }
}

// ---------------- transpose: vt[b][e][l] bf16 -> ybf[b][l][e] bf16 ----------------
__global__ __launch_bounds__(256) void k_t2(const __bf16* __restrict__ vt, __bf16* __restrict__ ybf) {
    __shared__ __bf16 tl[64][66];
    int e0 = blockIdx.x * 64, l0 = blockIdx.y * 64, b = blockIdx.z;
    int t = threadIdx.x;
    const __bf16* src = vt + ((size_t)b << 22);
    __bf16* dst = ybf + ((size_t)b << 22);
    int er = t >> 3, lc = (t & 7) * 8;
#pragma unroll
    for (int it = 0; it < 2; ++it) {
        int e = er + it * 32;
        bf16_8 v = *(const bf16_8*)&src[(size_t)(e0 + e) * LSEQ + l0 + lc];
#pragma unroll
        for (int j = 0; j < 8; ++j) tl[e][lc + j] = v[j];
    }
    __syncthreads();
    int lr = t >> 3, ec = (t & 7) * 8;
#pragma unroll
    for (int it = 0; it < 2; ++it) {
        int l = lr + it * 32;
        bf16_8 v;
#pragma unroll
        for (int j = 0; j < 8; ++j) v[j] = tl[ec + j][l];
        *(bf16_8*)&dst[(size_t)(l0 + l) * DDIM + e0 + ec] = v;
    }
}

extern "C" void kernel_launch(void* const* d_in, const int* in_sizes, int n_in,
                              void* d_out, int out_size, void* d_ws, size_t ws_size,
                              hipStream_t stream) {
    const float* x      = (const float*)d_in[0];
    const float* Wq     = (const float*)d_in[1];
    const float* Wv     = (const float*)d_in[2];
    const float* Wo     = (const float*)d_in[3];
    const float* ln_g_s = (const float*)d_in[4];
    const float* ln_g_b = (const float*)d_in[5];
    const float* W1     = (const float*)d_in[6];
    const float* b1     = (const float*)d_in[7];
    const float* W2     = (const float*)d_in[8];
    const float* b2     = (const float*)d_in[9];
    const float* mrb    = (const float*)d_in[10];
    const float* ln_w_s = (const float*)d_in[11];
    const float* ln_w_b = (const float*)d_in[12];
    const float* Ww1    = (const float*)d_in[13];
    const float* bw1    = (const float*)d_in[14];
    const float* Ww2    = (const float*)d_in[15];
    const float* bw2    = (const float*)d_in[16];
    float* out = (float*)d_out;

    char* W = (char*)d_ws;
    __bf16* xbf = (__bf16*)W;                       // 33,554,432 B (later aliased as ybf)
    __bf16* ybf = xbf;
    __bf16* Wvb = (__bf16*)(W + 33554432);          // 2 MB
    __bf16* Wob = (__bf16*)(W + 35651584);          // 2 MB
    float*  xbp = (float*)(W + 37748736);           // 65536 f
    float*  xbar= (float*)(W + 38010880);           // 4096 f
    float*  qbar= (float*)(W + 38027264);           // 4096 f
    float*  h1g = (float*)(W + 38043648);           // 16384 f
    float*  gwp1= (float*)(W + 38109184);           // 4096 f
    float*  gre = (float*)(W + 38125568);           // 131136 f
    float*  gim = (float*)(W + 38650112);           // 131136 f

    __bf16* vt = (__bf16*)d_out;                    // scratch inside d_out

    k_xbar_partial<<<dim3(4, 16, 4), 256, 0, stream>>>(x, xbp, xbf);
    k_cvt<<<1024, 256, 0, stream>>>(Wv, Wvb, DDIM * DDIM);
    k_cvt<<<1024, 256, 0, stream>>>(Wo, Wob, DDIM * DDIM);
    k_xbar_reduce<<<dim3(4, 4), 256, 0, stream>>>(xbp, xbar);
    k_qbar<<<256, 256, 0, stream>>>(xbar, Wq, qbar);
    k_mlp<<<64, 256, 0, stream>>>(qbar, ln_g_s, ln_g_b, W1, b1, ln_w_s, ln_w_b,
                                  Ww1, bw1, Ww2, bw2, h1g, gwp1);
    k_gate<<<1025, 256, 0, stream>>>(h1g, W2, b2, gre, gim);
    k_vgemm<<<256, 512, 0, stream>>>(xbf, Wvb, vt);
    k_fft<<<4096, 256, 0, stream>>>(vt, gre, gim, mrb, gwp1);
    k_t2<<<dim3(16, 64, 4), 256, 0, stream>>>(vt, ybf);
    k_ogemm<<<256, 512, 0, stream>>>(ybf, Wob, out);
}

// Round 9
// 224.713 us; speedup vs baseline: 5.3237x; 1.0002x over previous
//
#include <hip/hip_runtime.h>
#include <math.h>

#define LSEQ 4096
#define DDIM 1024
#define NB 4
#define NH 16
#define DHD 64
#define NFREQ 2049
#define NFMAX 4097

typedef __bf16 bf16_8 __attribute__((ext_vector_type(8)));
typedef float f32x4 __attribute__((ext_vector_type(4)));

__device__ __forceinline__ float gelu_exact(float v) {
    return 0.5f * v * (1.0f + erff(v * 0.70710678118654752440f));
}

__device__ __forceinline__ void gload16(const void* g, void* l) {
    __builtin_amdgcn_global_load_lds((const __attribute__((address_space(1))) char*)g,
                                     (__attribute__((address_space(3))) char*)l, 16, 0, 0);
}

// ---------------- xbar partial + x -> bf16 cast (single pass over x) ----------------
__global__ __launch_bounds__(256) void k_xbar_partial(const float* __restrict__ x, float* __restrict__ xbp,
                                                      __bf16* __restrict__ xbf) {
    int d = blockIdx.x * 256 + threadIdx.x;
    int chunk = blockIdx.y;
    int b = blockIdx.z;
    size_t base = ((size_t)b * LSEQ + (size_t)chunk * 256) * DDIM + d;
    float acc = 0.f;
    for (int l = 0; l < 256; ++l) {
        float v = x[base + (size_t)l * DDIM];
        acc += v;
        xbf[base + (size_t)l * DDIM] = (__bf16)v;
    }
    xbp[(size_t)(b * 16 + chunk) * DDIM + d] = acc;
}

__global__ __launch_bounds__(256) void k_xbar_reduce(const float* __restrict__ xbp, float* __restrict__ xbar) {
    int d = blockIdx.x * 256 + threadIdx.x;
    int b = blockIdx.y;
    float acc = 0.f;
    for (int c = 0; c < 16; ++c) acc += xbp[(size_t)(b * 16 + c) * DDIM + d];
    xbar[b * DDIM + d] = acc * (1.0f / LSEQ);
}

// ---------------- weight fp32 -> bf16 ----------------
__global__ __launch_bounds__(256) void k_cvt(const float* __restrict__ s, __bf16* __restrict__ d, int n) {
    int i = (blockIdx.x * 256 + threadIdx.x) * 4;
    if (i < n) {
        float4 v = *(const float4*)(s + i);
        d[i] = (__bf16)v.x; d[i + 1] = (__bf16)v.y; d[i + 2] = (__bf16)v.z; d[i + 3] = (__bf16)v.w;
    }
}

// ---------------- q_bar = xbar @ Wq^T ----------------
__global__ __launch_bounds__(256) void k_qbar(const float* __restrict__ xbar, const float* __restrict__ Wq,
                                              float* __restrict__ qbar) {
    int lane = threadIdx.x & 63;
    int e = blockIdx.x * 4 + (threadIdx.x >> 6);
    const float* wrow = Wq + (size_t)e * DDIM;
    float a0 = 0, a1 = 0, a2 = 0, a3 = 0;
    for (int i = 0; i < 16; ++i) {
        int d = lane + i * 64;
        float w = wrow[d];
        a0 += w * xbar[d];
        a1 += w * xbar[DDIM + d];
        a2 += w * xbar[2 * DDIM + d];
        a3 += w * xbar[3 * DDIM + d];
    }
    for (int off = 32; off > 0; off >>= 1) {
        a0 += __shfl_down(a0, off);
        a1 += __shfl_down(a1, off);
        a2 += __shfl_down(a2, off);
        a3 += __shfl_down(a3, off);
    }
    if (lane == 0) {
        qbar[e] = a0;
        qbar[DDIM + e] = a1;
        qbar[2 * DDIM + e] = a2;
        qbar[3 * DDIM + e] = a3;
    }
}

// ---------------- per-(b,h) MLPs ----------------
__global__ __launch_bounds__(256) void k_mlp(const float* __restrict__ qbar,
                                             const float* __restrict__ ln_g_s, const float* __restrict__ ln_g_b,
                                             const float* __restrict__ W1, const float* __restrict__ b1,
                                             const float* __restrict__ ln_w_s, const float* __restrict__ ln_w_b,
                                             const float* __restrict__ Ww1, const float* __restrict__ bw1,
                                             const float* __restrict__ Ww2, const float* __restrict__ bw2,
                                             float* __restrict__ h1g, float* __restrict__ gwp1) {
    int bh = blockIdx.x;
    __shared__ float q[64], hg[64], hw[64], g1[64];
    __shared__ float sm, sv;
    int t = threadIdx.x;
    if (t < 64) q[t] = qbar[bh * 64 + t];
    __syncthreads();
    if (t == 0) {
        float m = 0;
        for (int i = 0; i < 64; ++i) m += q[i];
        m *= (1.0f / 64.0f);
        float v = 0;
        for (int i = 0; i < 64; ++i) { float dd = q[i] - m; v += dd * dd; }
        v *= (1.0f / 64.0f);
        sm = m; sv = v;
    }
    __syncthreads();
    if (t < 64) {
        float n = (q[t] - sm) * rsqrtf(sv + 1e-5f);
        hg[t] = n * ln_g_s[t] + ln_g_b[t];
        hw[t] = n * ln_w_s[t] + ln_w_b[t];
    }
    __syncthreads();
    {
        int f = t;
        const float* w = W1 + (size_t)f * 64;
        float s = b1[f];
        for (int d0 = 0; d0 < 64; ++d0) s += hg[d0] * w[d0];
        h1g[(size_t)bh * 256 + f] = gelu_exact(s);
    }
    if (t < 64) {
        const float* w = Ww1 + (size_t)t * 64;
        float s = bw1[t];
        for (int k = 0; k < 64; ++k) s += hw[k] * w[k];
        g1[t] = gelu_exact(s);
    }
    __syncthreads();
    if (t < 64) {
        const float* w = Ww2 + (size_t)t * 64;
        float s = bw2[t];
        for (int k = 0; k < 64; ++k) s += g1[k] * w[k];
        gwp1[bh * 64 + t] = 1.0f + 1.0f / (1.0f + expf(-s));
    }
}

// ---------------- gate rows ----------------
__global__ __launch_bounds__(256) void k_gate(const float* __restrict__ h1g, const float* __restrict__ W2,
                                              const float* __restrict__ b2,
                                              float* __restrict__ gre, float* __restrict__ gim) {
    int task = blockIdx.x * 4 + (threadIdx.x >> 6);
    if (task >= 2 * NFREQ) return;
    int lane = threadIdx.x & 63;
    int part = task >= NFREQ;
    int f = task - part * NFREQ;
    int row = part ? (NFMAX + f) : f;
    const float* w = W2 + (size_t)row * 256;
    float w0 = w[lane], w1 = w[64 + lane], w2 = w[128 + lane], w3 = w[192 + lane];
    float bias = b2[row];
    float* dst = part ? gim : gre;
    for (int bh = 0; bh < 64; ++bh) {
        const float* hr = h1g + (size_t)bh * 256;
        float p = w0 * hr[lane] + w1 * hr[64 + lane] + w2 * hr[128 + lane] + w3 * hr[192 + lane];
        for (int off = 32; off > 0; off >>= 1) p += __shfl_down(p, off);
        if (lane == 0) dst[(size_t)bh * NFREQ + f] = p + bias;
    }
}

// ================= 256x256-tile, 8-wave, BK=32, double-buffered GEMM =================
__device__ __forceinline__ void swz256(int bid, int& n0, int& m0, int& b) {
    int w = (bid & 7) * 32 + (bid >> 3);
    b = w >> 6;
    m0 = ((w >> 2) & 15) << 8;
    n0 = (w & 3) << 8;
}

__device__ __forceinline__ void g2_stage(const __bf16* __restrict__ src, int row0, int kt,
                                         __bf16* lds, int tid) {
#pragma unroll
    for (int j = 0; j < 2; ++j) {
        int c = j * 512 + tid;
        int r = c >> 2, kc = (c & 3) * 8;
        __bf16* ldsbase = lds + (size_t)(j * 512 + (tid & ~63)) * 8;
        gload16(src + ((size_t)(row0 + r) << 10) + kt * 32 + kc, ldsbase);
    }
}

__device__ __forceinline__ void g2_core(const __bf16* __restrict__ A, const __bf16* __restrict__ B,
                                        int m0, int n0, __bf16 (*As)[256 * 32], __bf16 (*Bs)[256 * 32],
                                        f32x4 (&acc)[8][4]) {
    int tid = threadIdx.x;
    int lane = tid & 63, w = tid >> 6;
    int wm = w >> 2, wn = w & 3;
    int lrow = lane & 15, lk = (lane >> 4) * 8;
#pragma unroll
    for (int mi = 0; mi < 8; ++mi)
#pragma unroll
        for (int ni = 0; ni < 4; ++ni) acc[mi][ni] = (f32x4){0.f, 0.f, 0.f, 0.f};

    g2_stage(A, m0, 0, As[0], tid);
    g2_stage(B, n0, 0, Bs[0], tid);
    __syncthreads();
    int buf = 0;
    for (int kt = 0; kt < 32; ++kt) {
        if (kt < 31) {
            g2_stage(A, m0, kt + 1, As[buf ^ 1], tid);
            g2_stage(B, n0, kt + 1, Bs[buf ^ 1], tid);
        }
        bf16_8 af[8], bfr[4];
#pragma unroll
        for (int mi = 0; mi < 8; ++mi)
            af[mi] = *(const bf16_8*)&As[buf][(wm * 128 + mi * 16 + lrow) * 32 + lk];
#pragma unroll
        for (int ni = 0; ni < 4; ++ni)
            bfr[ni] = *(const bf16_8*)&Bs[buf][(wn * 64 + ni * 16 + lrow) * 32 + lk];
#pragma unroll
        for (int mi = 0; mi < 8; ++mi)
#pragma unroll
            for (int ni = 0; ni < 4; ++ni)
                acc[mi][ni] = __builtin_amdgcn_mfma_f32_16x16x32_bf16(af[mi], bfr[ni], acc[mi][ni], 0, 0, 0);
        __syncthreads();
        buf ^= 1;
    }
}

// vgemm: vt[b][e][l] (bf16) = (x @ Wv^T)^T
__global__ __launch_bounds__(512, 2) void k_vgemm(const __bf16* __restrict__ xbf, const __bf16* __restrict__ Wvb,
                                                  __bf16* __restrict__ vt) {
    __shared__ __align__(16) __bf16 As[2][256 * 32];
    __shared__ __align__(16) __bf16 Bs[2][256 * 32];
    __shared__ __bf16 st[8][16][68];
    int n0, m0, b;
    swz256(blockIdx.x, n0, m0, b);
    f32x4 acc[8][4];
    g2_core(xbf + ((size_t)b << 22), Wvb, m0, n0, As, Bs, acc);
    int tid = threadIdx.x;
    int lane = tid & 63, w = tid >> 6;
    int wm = w >> 2, wn = w & 3;
    size_t vbase = ((size_t)b << 22);
#pragma unroll
    for (int ni = 0; ni < 4; ++ni) {
#pragma unroll
        for (int half = 0; half < 2; ++half) {
#pragma unroll
            for (int ml = 0; ml < 4; ++ml)
#pragma unroll
                for (int r = 0; r < 4; ++r)
                    st[w][lane & 15][ml * 16 + (lane >> 4) * 4 + r] = (__bf16)acc[half * 4 + ml][ni][r];
            asm volatile("" ::: "memory");
#pragma unroll
            for (int er = 0; er < 16; ++er) {
                vt[vbase + (size_t)(n0 + wn * 64 + ni * 16 + er) * LSEQ + m0 + wm * 128 + half * 64 + lane] =
                    st[w][er][lane];
            }
            asm volatile("" ::: "memory");
        }
    }
}

// ogemm: out[b][l][e2] (fp32) = ybf @ Wo^T
__global__ __launch_bounds__(512, 2) void k_ogemm(const __bf16* __restrict__ ybf, const __bf16* __restrict__ Wob,
                                                  float* __restrict__ out) {
    __shared__ __align__(16) __bf16 As[2][256 * 32];
    __shared__ __align__(16) __bf16 Bs[2][256 * 32];
    int n0, m0, b;
    swz256(blockIdx.x, n0, m0, b);
    f32x4 acc[8][4];
    g2_core(ybf + ((size_t)b << 22), Wob, m0, n0, As, Bs, acc);
    int tid = threadIdx.x;
    int lane = tid & 63, w = tid >> 6;
    int wm = w >> 2, wn = w & 3;
    float* ob = out + ((size_t)b << 22);
#pragma unroll
    for (int mi = 0; mi < 8; ++mi)
#pragma unroll
        for (int ni = 0; ni < 4; ++ni)
#pragma unroll
            for (int r = 0; r < 4; ++r)
                ob[(size_t)(m0 + wm * 128 + mi * 16 + (lane >> 4) * 4 + r) * DDIM +
                   n0 + wn * 64 + ni * 16 + (lane & 15)] = acc[mi][ni][r];
}

// ================= rfft4096 per channel via cfft2048 (even/odd pack), radix 8-8-8-4 =================
__device__ __forceinline__ float2 cmul(float2 a, float2 b) {
    return make_float2(a.x * b.x - a.y * b.y, a.x * b.y + a.y * b.x);
}
__device__ __forceinline__ int P8(int i) { return i + (i >> 3) + (i >> 8); }
__device__ __forceinline__ int SR8(int k) {
    return ((k & 7) << 8) | (((k >> 3) & 7) << 5) | (((k >> 6) & 7) << 2) | (k >> 9);
}

template <int S>
__device__ __forceinline__ void dft4v(float2* x) {
    float2 t0 = make_float2(x[0].x + x[2].x, x[0].y + x[2].y);
    float2 t1 = make_float2(x[0].x - x[2].x, x[0].y - x[2].y);
    float2 t2 = make_float2(x[1].x + x[3].x, x[1].y + x[3].y);
    float2 t3 = make_float2(x[1].x - x[3].x, x[1].y - x[3].y);
    float2 j3 = (S == 1) ? make_float2(t3.y, -t3.x) : make_float2(-t3.y, t3.x);
    x[0] = make_float2(t0.x + t2.x, t0.y + t2.y);
    x[2] = make_float2(t0.x - t2.x, t0.y - t2.y);
    x[1] = make_float2(t1.x + j3.x, t1.y + j3.y);
    x[3] = make_float2(t1.x - j3.x, t1.y - j3.y);
}

template <int S>
__device__ __forceinline__ void dft8v(float2* x) {
    float2 e[4] = {x[0], x[2], x[4], x[6]};
    float2 o[4] = {x[1], x[3], x[5], x[7]};
    dft4v<S>(e);
    dft4v<S>(o);
    const float c = 0.7071067811865476f;
    const float sg = (S == 1) ? -1.f : 1.f;
    o[1] = cmul(o[1], make_float2(c, sg * c));
    o[2] = (S == 1) ? make_float2(o[2].y, -o[2].x) : make_float2(-o[2].y, o[2].x);
    o[3] = cmul(o[3], make_float2(-c, sg * c));
    x[0] = make_float2(e[0].x + o[0].x, e[0].y + o[0].y);
    x[4] = make_float2(e[0].x - o[0].x, e[0].y - o[0].y);
    x[1] = make_float2(e[1].x + o[1].x, e[1].y + o[1].y);
    x[5] = make_float2(e[1].x - o[1].x, e[1].y - o[1].y);
    x[2] = make_float2(e[2].x + o[2].x, e[2].y + o[2].y);
    x[6] = make_float2(e[2].x - o[2].x, e[2].y - o[2].y);
    x[3] = make_float2(e[3].x + o[3].x, e[3].y + o[3].y);
    x[7] = make_float2(e[3].x - o[3].x, e[3].y - o[3].y);
}

// Twiddle via log-depth product tree: 1 sincos + 6 cmuls (depth 3), no serial chain,
// no per-r TRANS ops. w_r = w1^r exactly (fp32 product error ~4e-7, invisible at bf16).
template <int S>
__device__ __forceinline__ void tw8(float2* x, int j, float invN) {
    float base = ((S == 1) ? -6.283185307179586f : 6.283185307179586f) * invN;
    float sn, cs;
    __sincosf(base * (float)j, &sn, &cs);
    float2 w1 = make_float2(cs, sn);
    float2 w2 = cmul(w1, w1);
    float2 w3 = cmul(w2, w1);
    float2 w4 = cmul(w2, w2);
    float2 w5 = cmul(w4, w1);
    float2 w6 = cmul(w4, w2);
    float2 w7 = cmul(w4, w3);
    x[1] = cmul(x[1], w1);
    x[2] = cmul(x[2], w2);
    x[3] = cmul(x[3], w3);
    x[4] = cmul(x[4], w4);
    x[5] = cmul(x[5], w5);
    x[6] = cmul(x[6], w6);
    x[7] = cmul(x[7], w7);
}

__global__ __launch_bounds__(256, 2) void k_fft(__bf16* __restrict__ vty,
                                                const float* __restrict__ gre, const float* __restrict__ gim,
                                                const float* __restrict__ mrb, const float* __restrict__ gwp1) {
    __shared__ float2 Zp[2312];
    int pid = blockIdx.x;
    int b = pid >> 10, e = pid & 1023;
    int h = e >> 6, dh = e & 63;
    int bh = b * 16 + h;
    size_t gbase = (size_t)bh * NFREQ;
    size_t mbase = (size_t)h * NFMAX;
    __bf16* row = vty + ((size_t)b << 22) + ((size_t)e << 12);
    int t = threadIdx.x;

#pragma unroll
    for (int cc = 0; cc < 2; ++cc) {
        int c = t + cc * 256;
        bf16_8 a = *(const bf16_8*)&row[c * 8];
#pragma unroll
        for (int q = 0; q < 4; ++q)
            Zp[P8(c * 4 + q)] = make_float2((float)a[2 * q], (float)a[2 * q + 1]);
    }
    __syncthreads();

    float2 x[8];
    {
#pragma unroll
        for (int r = 0; r < 8; ++r) x[r] = Zp[P8(r * 256 + t)];
        dft8v<1>(x);
        tw8<1>(x, t, 1.0f / 2048.0f);
#pragma unroll
        for (int r = 0; r < 8; ++r) Zp[P8(r * 256 + t)] = x[r];
    }
    __syncthreads();
    {
        int g = t >> 5, j = t & 31, base = g * 256 + j;
#pragma unroll
        for (int r = 0; r < 8; ++r) x[r] = Zp[P8(base + r * 32)];
        dft8v<1>(x);
        tw8<1>(x, j, 1.0f / 256.0f);
#pragma unroll
        for (int r = 0; r < 8; ++r) Zp[P8(base + r * 32)] = x[r];
    }
    __syncthreads();
    {
        int g = t >> 2, j = t & 3, base = g * 32 + j;
#pragma unroll
        for (int r = 0; r < 8; ++r) x[r] = Zp[P8(base + r * 4)];
        dft8v<1>(x);
        tw8<1>(x, j, 1.0f / 32.0f);
#pragma unroll
        for (int r = 0; r < 8; ++r) Zp[P8(base + r * 4)] = x[r];
    }
    __syncthreads();
    {
        int base = t * 8;
#pragma unroll
        for (int q = 0; q < 4; ++q) { x[q] = Zp[P8(base + q)]; x[4 + q] = Zp[P8(base + 4 + q)]; }
        dft4v<1>(x);
        dft4v<1>(x + 4);
#pragma unroll
        for (int q = 0; q < 4; ++q) { Zp[P8(base + q)] = x[q]; Zp[P8(base + 4 + q)] = x[4 + q]; }
    }
    __syncthreads();

    // untangle + gate + modrelu + re-tangle; W^k chained by constant W256 = e^{-i*pi/8}
    {
        float sn0, cs0;
        __sincosf(-1.5339807878856412e-3f * (float)(1 + t), &sn0, &cs0);  // W^(1+t)
        float2 wk = make_float2(cs0, sn0);
        const float2 W256 = make_float2(0.92387953251128675613f, -0.38268343236508977172f);
#pragma unroll
        for (int r = 0; r < 4; ++r) {
            int k = 1 + (r << 8) + t;
            int k2 = 2048 - k;
            int sA = P8(SR8(k)), sB = P8(SR8(k2));
            float cs = wk.x, sn = wk.y;
            float2 Za = Zp[sA], Zb = Zp[sB];
            float Er = 0.5f * (Za.x + Zb.x), Ei = 0.5f * (Za.y - Zb.y);
            float Dr = 0.5f * (Za.x - Zb.x), Di = 0.5f * (Za.y + Zb.y);
            float WDr = cs * Dr - sn * Di, WDi = cs * Di + sn * Dr;
            float Tr = -WDi, Ti = WDr;
            float Vkr = Er - Tr, Vki = Ei - Ti;
            float Vk2r = Er + Tr, Vk2i = -(Ei + Ti);
            float g1r = gre[gbase + k], g1i = gim[gbase + k], b1v = mrb[mbase + k];
            float Ykr = Vkr * g1r - Vki * g1i, Yki = Vkr * g1i + Vki * g1r;
            float m1 = sqrtf(Ykr * Ykr + Yki * Yki);
            float s1 = fmaxf(m1 + b1v, 0.f) / (m1 + 1e-6f);
            Ykr *= s1; Yki *= s1;
            float g2r = gre[gbase + k2], g2i = gim[gbase + k2], b2v = mrb[mbase + k2];
            float Yk2r = Vk2r * g2r - Vk2i * g2i, Yk2i = Vk2r * g2i + Vk2i * g2r;
            float m2 = sqrtf(Yk2r * Yk2r + Yk2i * Yk2i);
            float s2 = fmaxf(m2 + b2v, 0.f) / (m2 + 1e-6f);
            Yk2r *= s2; Yk2i *= s2;
            float Epr = 0.5f * (Ykr + Yk2r), Epi = 0.5f * (Yki - Yk2i);
            float Fr = 0.5f * (Ykr - Yk2r), Fi = 0.5f * (Yki + Yk2i);
            float CWFr = cs * Fr + sn * Fi;
            float CWFi = cs * Fi - sn * Fr;
            Zp[sA] = make_float2(Epr - CWFi, Epi + CWFr);
            Zp[sB] = make_float2(Epr + CWFi, -Epi + CWFr);
            wk = cmul(wk, W256);
        }
    }
    if (t == 0) {
        float2 Z0 = Zp[P8(0)];
        float V0 = Z0.x + Z0.y, VN = Z0.x - Z0.y;
        float g0r = gre[gbase], g0i = gim[gbase], b0v = mrb[mbase];
        float y0r = V0 * g0r, y0i = V0 * g0i;
        float m0 = sqrtf(y0r * y0r + y0i * y0i);
        float Y0 = y0r * (fmaxf(m0 + b0v, 0.f) / (m0 + 1e-6f));
        float gNr = gre[gbase + 2048], gNi = gim[gbase + 2048], bNv = mrb[mbase + 2048];
        float yNr = VN * gNr, yNi = VN * gNi;
        float mN = sqrtf(yNr * yNr + yNi * yNi);
        float YN = yNr * (fmaxf(mN + bNv, 0.f) / (mN + 1e-6f));
        Zp[P8(0)] = make_float2(0.5f * (Y0 + YN), 0.5f * (Y0 - YN));
    }
    __syncthreads();

    {
        int base = t * 8;
#pragma unroll
        for (int q = 0; q < 4; ++q) { x[q] = Zp[P8(base + q)]; x[4 + q] = Zp[P8(base + 4 + q)]; }
        dft4v<-1>(x);
        dft4v<-1>(x + 4);
#pragma unroll
        for (int q = 0; q < 4; ++q) { Zp[P8(base + q)] = x[q]; Zp[P8(base + 4 + q)] = x[4 + q]; }
    }
    __syncthreads();
    {
        int g = t >> 2, j = t & 3, base = g * 32 + j;
#pragma unroll
        for (int r = 0; r < 8; ++r) x[r] = Zp[P8(base + r * 4)];
        tw8<-1>(x, j, 1.0f / 32.0f);
        dft8v<-1>(x);
#pragma unroll
        for (int r = 0; r < 8; ++r) Zp[P8(base + r * 4)] = x[r];
    }
    __syncthreads();
    {
        int g = t >> 5, j = t & 31, base = g * 256 + j;
#pragma unroll
        for (int r = 0; r < 8; ++r) x[r] = Zp[P8(base + r * 32)];
        tw8<-1>(x, j, 1.0f / 256.0f);
        dft8v<-1>(x);
#pragma unroll
        for (int r = 0; r < 8; ++r) Zp[P8(base + r * 32)] = x[r];
    }
    __syncthreads();
    {
#pragma unroll
        for (int r = 0; r < 8; ++r) x[r] = Zp[P8(r * 256 + t)];
        tw8<-1>(x, t, 1.0f / 2048.0f);
        dft8v<-1>(x);
        float sc = gwp1[bh * 64 + dh] * (1.0f / 2048.0f);
        unsigned int* row32 = (unsigned int*)row;
#pragma unroll
        for (int r = 0; r < 8; ++r) {
            __bf16 h1 = (__bf16)(x[r].x * sc);
            __bf16 h2 = (__bf16)(x[r].y * sc);
            unsigned int u = (unsigned int)__builtin_bit_cast(unsigned short, h1) |
                             ((unsigned int)__builtin_bit_cast(unsigned short, h2) << 16);
            row32[t + 256 * r] = u;
        }
    }
}

// ---------------- transpose: vt[b][e][l] bf16 -> ybf[b][l][e] bf16 ----------------
__global__ __launch_bounds__(256) void k_t2(const __bf16* __restrict__ vt, __bf16* __restrict__ ybf) {
    __shared__ __bf16 tl[64][66];
    int e0 = blockIdx.x * 64, l0 = blockIdx.y * 64, b = blockIdx.z;
    int t = threadIdx.x;
    const __bf16* src = vt + ((size_t)b << 22);
    __bf16* dst = ybf + ((size_t)b << 22);
    int er = t >> 3, lc = (t & 7) * 8;
#pragma unroll
    for (int it = 0; it < 2; ++it) {
        int e = er + it * 32;
        bf16_8 v = *(const bf16_8*)&src[(size_t)(e0 + e) * LSEQ + l0 + lc];
#pragma unroll
        for (int j = 0; j < 8; ++j) tl[e][lc + j] = v[j];
    }
    __syncthreads();
    int lr = t >> 3, ec = (t & 7) * 8;
#pragma unroll
    for (int it = 0; it < 2; ++it) {
        int l = lr + it * 32;
        bf16_8 v;
#pragma unroll
        for (int j = 0; j < 8; ++j) v[j] = tl[ec + j][l];
        *(bf16_8*)&dst[(size_t)(l0 + l) * DDIM + e0 + ec] = v;
    }
}

extern "C" void kernel_launch(void* const* d_in, const int* in_sizes, int n_in,
                              void* d_out, int out_size, void* d_ws, size_t ws_size,
                              hipStream_t stream) {
    const float* x      = (const float*)d_in[0];
    const float* Wq     = (const float*)d_in[1];
    const float* Wv     = (const float*)d_in[2];
    const float* Wo     = (const float*)d_in[3];
    const float* ln_g_s = (const float*)d_in[4];
    const float* ln_g_b = (const float*)d_in[5];
    const float* W1     = (const float*)d_in[6];
    const float* b1     = (const float*)d_in[7];
    const float* W2     = (const float*)d_in[8];
    const float* b2     = (const float*)d_in[9];
    const float* mrb    = (const float*)d_in[10];
    const float* ln_w_s = (const float*)d_in[11];
    const float* ln_w_b = (const float*)d_in[12];
    const float* Ww1    = (const float*)d_in[13];
    const float* bw1    = (const float*)d_in[14];
    const float* Ww2    = (const float*)d_in[15];
    const float* bw2    = (const float*)d_in[16];
    float* out = (float*)d_out;

    char* W = (char*)d_ws;
    __bf16* xbf = (__bf16*)W;                       // 33,554,432 B (later aliased as ybf)
    __bf16* ybf = xbf;
    __bf16* Wvb = (__bf16*)(W + 33554432);          // 2 MB
    __bf16* Wob = (__bf16*)(W + 35651584);          // 2 MB
    float*  xbp = (float*)(W + 37748736);           // 65536 f
    float*  xbar= (float*)(W + 38010880);           // 4096 f
    float*  qbar= (float*)(W + 38027264);           // 4096 f
    float*  h1g = (float*)(W + 38043648);           // 16384 f
    float*  gwp1= (float*)(W + 38109184);           // 4096 f
    float*  gre = (float*)(W + 38125568);           // 131136 f
    float*  gim = (float*)(W + 38650112);           // 131136 f

    __bf16* vt = (__bf16*)d_out;                    // scratch inside d_out

    k_xbar_partial<<<dim3(4, 16, 4), 256, 0, stream>>>(x, xbp, xbf);
    k_cvt<<<1024, 256, 0, stream>>>(Wv, Wvb, DDIM * DDIM);
    k_cvt<<<1024, 256, 0, stream>>>(Wo, Wob, DDIM * DDIM);
    k_xbar_reduce<<<dim3(4, 4), 256, 0, stream>>>(xbp, xbar);
    k_qbar<<<256, 256, 0, stream>>>(xbar, Wq, qbar);
    k_mlp<<<64, 256, 0, stream>>>(qbar, ln_g_s, ln_g_b, W1, b1, ln_w_s, ln_w_b,
                                  Ww1, bw1, Ww2, bw2, h1g, gwp1);
    k_gate<<<1025, 256, 0, stream>>>(h1g, W2, b2, gre, gim);
    k_vgemm<<<256, 512, 0, stream>>>(xbf, Wvb, vt);
    k_fft<<<4096, 256, 0, stream>>>(vt, gre, gim, mrb, gwp1);
    k_t2<<<dim3(16, 64, 4), 256, 0, stream>>>(vt, ybf);
    k_ogemm<<<256, 512, 0, stream>>>(ybf, Wob, out);
}

// Round 11
// 201.047 us; speedup vs baseline: 5.9503x; 1.1177x over previous
//
#include <hip/hip_runtime.h>
#include <math.h>

#define LSEQ 4096
#define DDIM 1024
#define NB 4
#define NH 16
#define DHD 64
#define NFREQ 2049
#define NFMAX 4097

typedef __bf16 bf16_8 __attribute__((ext_vector_type(8)));
typedef float f32x4 __attribute__((ext_vector_type(4)));

__device__ __forceinline__ float gelu_exact(float v) {
    return 0.5f * v * (1.0f + erff(v * 0.70710678118654752440f));
}

__device__ __forceinline__ void gload16(const void* g, void* l) {
    __builtin_amdgcn_global_load_lds((const __attribute__((address_space(1))) char*)g,
                                     (__attribute__((address_space(3))) char*)l, 16, 0, 0);
}

// ---------------- xbar partial + x -> bf16 cast (single pass over x) ----------------
__global__ __launch_bounds__(256) void k_xbar_partial(const float* __restrict__ x, float* __restrict__ xbp,
                                                      __bf16* __restrict__ xbf) {
    int d = blockIdx.x * 256 + threadIdx.x;
    int chunk = blockIdx.y;
    int b = blockIdx.z;
    size_t base = ((size_t)b * LSEQ + (size_t)chunk * 256) * DDIM + d;
    float acc = 0.f;
    for (int l = 0; l < 256; ++l) {
        float v = x[base + (size_t)l * DDIM];
        acc += v;
        xbf[base + (size_t)l * DDIM] = (__bf16)v;
    }
    xbp[(size_t)(b * 16 + chunk) * DDIM + d] = acc;
}

__global__ __launch_bounds__(256) void k_xbar_reduce(const float* __restrict__ xbp, float* __restrict__ xbar) {
    int d = blockIdx.x * 256 + threadIdx.x;
    int b = blockIdx.y;
    float acc = 0.f;
    for (int c = 0; c < 16; ++c) acc += xbp[(size_t)(b * 16 + c) * DDIM + d];
    xbar[b * DDIM + d] = acc * (1.0f / LSEQ);
}

// ---------------- weight fp32 -> bf16 ----------------
__global__ __launch_bounds__(256) void k_cvt(const float* __restrict__ s, __bf16* __restrict__ d, int n) {
    int i = (blockIdx.x * 256 + threadIdx.x) * 4;
    if (i < n) {
        float4 v = *(const float4*)(s + i);
        d[i] = (__bf16)v.x; d[i + 1] = (__bf16)v.y; d[i + 2] = (__bf16)v.z; d[i + 3] = (__bf16)v.w;
    }
}

// ---------------- q_bar = xbar @ Wq^T ----------------
__global__ __launch_bounds__(256) void k_qbar(const float* __restrict__ xbar, const float* __restrict__ Wq,
                                              float* __restrict__ qbar) {
    int lane = threadIdx.x & 63;
    int e = blockIdx.x * 4 + (threadIdx.x >> 6);
    const float* wrow = Wq + (size_t)e * DDIM;
    float a0 = 0, a1 = 0, a2 = 0, a3 = 0;
    for (int i = 0; i < 16; ++i) {
        int d = lane + i * 64;
        float w = wrow[d];
        a0 += w * xbar[d];
        a1 += w * xbar[DDIM + d];
        a2 += w * xbar[2 * DDIM + d];
        a3 += w * xbar[3 * DDIM + d];
    }
    for (int off = 32; off > 0; off >>= 1) {
        a0 += __shfl_down(a0, off);
        a1 += __shfl_down(a1, off);
        a2 += __shfl_down(a2, off);
        a3 += __shfl_down(a3, off);
    }
    if (lane == 0) {
        qbar[e] = a0;
        qbar[DDIM + e] = a1;
        qbar[2 * DDIM + e] = a2;
        qbar[3 * DDIM + e] = a3;
    }
}

// ---------------- per-(b,h) MLPs ----------------
__global__ __launch_bounds__(256) void k_mlp(const float* __restrict__ qbar,
                                             const float* __restrict__ ln_g_s, const float* __restrict__ ln_g_b,
                                             const float* __restrict__ W1, const float* __restrict__ b1,
                                             const float* __restrict__ ln_w_s, const float* __restrict__ ln_w_b,
                                             const float* __restrict__ Ww1, const float* __restrict__ bw1,
                                             const float* __restrict__ Ww2, const float* __restrict__ bw2,
                                             float* __restrict__ h1g, float* __restrict__ gwp1) {
    int bh = blockIdx.x;
    __shared__ float q[64], hg[64], hw[64], g1[64];
    __shared__ float sm, sv;
    int t = threadIdx.x;
    if (t < 64) q[t] = qbar[bh * 64 + t];
    __syncthreads();
    if (t == 0) {
        float m = 0;
        for (int i = 0; i < 64; ++i) m += q[i];
        m *= (1.0f / 64.0f);
        float v = 0;
        for (int i = 0; i < 64; ++i) { float dd = q[i] - m; v += dd * dd; }
        v *= (1.0f / 64.0f);
        sm = m; sv = v;
    }
    __syncthreads();
    if (t < 64) {
        float n = (q[t] - sm) * rsqrtf(sv + 1e-5f);
        hg[t] = n * ln_g_s[t] + ln_g_b[t];
        hw[t] = n * ln_w_s[t] + ln_w_b[t];
    }
    __syncthreads();
    {
        int f = t;
        const float* w = W1 + (size_t)f * 64;
        float s = b1[f];
        for (int d0 = 0; d0 < 64; ++d0) s += hg[d0] * w[d0];
        h1g[(size_t)bh * 256 + f] = gelu_exact(s);
    }
    if (t < 64) {
        const float* w = Ww1 + (size_t)t * 64;
        float s = bw1[t];
        for (int k = 0; k < 64; ++k) s += hw[k] * w[k];
        g1[t] = gelu_exact(s);
    }
    __syncthreads();
    if (t < 64) {
        const float* w = Ww2 + (size_t)t * 64;
        float s = bw2[t];
        for (int k = 0; k < 64; ++k) s += g1[k] * w[k];
        gwp1[bh * 64 + t] = 1.0f + 1.0f / (1.0f + expf(-s));
    }
}

// ---------------- gate rows ----------------
__global__ __launch_bounds__(256) void k_gate(const float* __restrict__ h1g, const float* __restrict__ W2,
                                              const float* __restrict__ b2,
                                              float* __restrict__ gre, float* __restrict__ gim) {
    int task = blockIdx.x * 4 + (threadIdx.x >> 6);
    if (task >= 2 * NFREQ) return;
    int lane = threadIdx.x & 63;
    int part = task >= NFREQ;
    int f = task - part * NFREQ;
    int row = part ? (NFMAX + f) : f;
    const float* w = W2 + (size_t)row * 256;
    float w0 = w[lane], w1 = w[64 + lane], w2 = w[128 + lane], w3 = w[192 + lane];
    float bias = b2[row];
    float* dst = part ? gim : gre;
    for (int bh = 0; bh < 64; ++bh) {
        const float* hr = h1g + (size_t)bh * 256;
        float p = w0 * hr[lane] + w1 * hr[64 + lane] + w2 * hr[128 + lane] + w3 * hr[192 + lane];
        for (int off = 32; off > 0; off >>= 1) p += __shfl_down(p, off);
        if (lane == 0) dst[(size_t)bh * NFREQ + f] = p + bias;
    }
}

// ================= 256x256, 8-wave, BK=64, dbuf LDS, counted-vmcnt pipeline =================
// LDS map (bytes): A[db][half] at db*32768 + half*16384 (0..65535)
//                  B[db][half] at 65536 + db*32768 + half*16384 (65536..131071)
// half = 128 rows x 64 cols bf16 = 16KB, row stride 128B.
// T2 swizzle: 16B slot s stored at physical slot s ^ (row&7)  (source-side permuted for
// gload_lds linear dest; read-side applies same XOR -> 2-way bank conflicts = free).
__device__ __forceinline__ void swz256(int bid, int& n0, int& m0, int& b) {
    int w = (bid & 7) * 32 + (bid >> 3);
    b = w >> 6;
    m0 = ((w >> 2) & 15) << 8;
    n0 = (w & 3) << 8;
}

__device__ __forceinline__ void g3_stage_half(const __bf16* __restrict__ src, int row0, int kt,
                                              char* ldshalf, int tid) {
#pragma unroll
    for (int j = 0; j < 2; ++j) {
        int c = j * 512 + tid;
        int r = c >> 3;                              // 0..127
        int kc = ((c & 7) ^ (r & 7)) * 8;            // source slot = dest slot ^ (row&7)
        char* dst = ldshalf + (size_t)(j * 512 + (tid & ~63)) * 16;  // wave-uniform base
        gload16(src + ((size_t)(row0 + r) << 10) + kt * 64 + kc, dst);
    }
}

__device__ __forceinline__ void g3_compute(const char* L, int db, int wm, int wn,
                                           int lrow, int lsl, f32x4 (&acc)[8][4]) {
    const char* Ab = L + db * 32768 + wm * 16384;
    const char* Bb = L + 65536 + db * 32768 + (wn >> 1) * 16384;
    int xs = lrow & 7;
    int brb = (wn & 1) * 64;
#pragma unroll
    for (int kk = 0; kk < 2; ++kk) {
        int slot = ((kk * 4 + lsl) ^ xs) << 4;
        bf16_8 af[8], bfr[4];
#pragma unroll
        for (int mi = 0; mi < 8; ++mi)
            af[mi] = *(const bf16_8*)(Ab + (mi * 16 + lrow) * 128 + slot);
#pragma unroll
        for (int ni = 0; ni < 4; ++ni)
            bfr[ni] = *(const bf16_8*)(Bb + (brb + ni * 16 + lrow) * 128 + slot);
        __builtin_amdgcn_s_setprio(1);
#pragma unroll
        for (int mi = 0; mi < 8; ++mi)
#pragma unroll
            for (int ni = 0; ni < 4; ++ni)
                acc[mi][ni] = __builtin_amdgcn_mfma_f32_16x16x32_bf16(af[mi], bfr[ni], acc[mi][ni], 0, 0, 0);
        __builtin_amdgcn_s_setprio(0);
    }
}

__device__ __forceinline__ void g3_core(const __bf16* __restrict__ A, const __bf16* __restrict__ B,
                                        int m0, int n0, char* L, f32x4 (&acc)[8][4]) {
    int tid = threadIdx.x;
    int lane = tid & 63, w = tid >> 6;
    int wm = w >> 2, wn = w & 3;
    int lrow = lane & 15, lsl = lane >> 4;
#pragma unroll
    for (int mi = 0; mi < 8; ++mi)
#pragma unroll
        for (int ni = 0; ni < 4; ++ni) acc[mi][ni] = (f32x4){0.f, 0.f, 0.f, 0.f};

#define G3_STAGE(KT, DB)                                                        \
    do {                                                                        \
        g3_stage_half(A, m0,       (KT), L + (DB) * 32768,               tid);  \
        g3_stage_half(A, m0 + 128, (KT), L + (DB) * 32768 + 16384,       tid);  \
        g3_stage_half(B, n0,       (KT), L + 65536 + (DB) * 32768,       tid);  \
        g3_stage_half(B, n0 + 128, (KT), L + 65536 + (DB) * 32768 + 16384, tid);\
    } while (0)

    G3_STAGE(0, 0);
    G3_STAGE(1, 1);
    asm volatile("s_waitcnt vmcnt(8)" ::: "memory");   // tile0's 8 loads done; tile1's in flight
    __builtin_amdgcn_s_barrier();
    asm volatile("" ::: "memory");
#pragma unroll 1
    for (int kt = 0; kt < 16; ++kt) {
        int db = kt & 1;
        g3_compute(L, db, wm, wn, lrow, lsl, acc);
        asm volatile("s_waitcnt lgkmcnt(0)" ::: "memory");  // my ds_reads of buf[db] retired
        __builtin_amdgcn_s_barrier();                       // all waves done reading buf[db]
        asm volatile("" ::: "memory");
        if (kt < 14) {
            G3_STAGE(kt + 2, db);                           // overwrite buf[db]; stays in flight
            asm volatile("s_waitcnt vmcnt(8)" ::: "memory");// tile kt+1 done; kt+2's 8 in flight
            __builtin_amdgcn_s_barrier();
            asm volatile("" ::: "memory");
        } else if (kt == 14) {
            asm volatile("s_waitcnt vmcnt(0)" ::: "memory");// tile 15 done
            __builtin_amdgcn_s_barrier();
            asm volatile("" ::: "memory");
        }
    }
#undef G3_STAGE
}

// vgemm: vt[b][e][l] (bf16) = (x @ Wv^T)^T  (transposed epilogue via per-wave LDS staging)
__global__ __launch_bounds__(512, 2) void k_vgemm(const __bf16* __restrict__ xbf, const __bf16* __restrict__ Wvb,
                                                  __bf16* __restrict__ vt) {
    __shared__ __align__(16) char L[131072 + 17408];
    __bf16 (*st)[16][68] = (__bf16(*)[16][68])(L + 131072);
    int n0, m0, b;
    swz256(blockIdx.x, n0, m0, b);
    f32x4 acc[8][4];
    g3_core(xbf + ((size_t)b << 22), Wvb, m0, n0, L, acc);
    int tid = threadIdx.x;
    int lane = tid & 63, w = tid >> 6;
    int wm = w >> 2, wn = w & 3;
    size_t vbase = ((size_t)b << 22);
#pragma unroll
    for (int ni = 0; ni < 4; ++ni) {
#pragma unroll
        for (int half = 0; half < 2; ++half) {
#pragma unroll
            for (int ml = 0; ml < 4; ++ml)
#pragma unroll
                for (int r = 0; r < 4; ++r)
                    st[w][lane & 15][ml * 16 + (lane >> 4) * 4 + r] = (__bf16)acc[half * 4 + ml][ni][r];
            asm volatile("" ::: "memory");
#pragma unroll
            for (int er = 0; er < 16; ++er) {
                vt[vbase + (size_t)(n0 + wn * 64 + ni * 16 + er) * LSEQ + m0 + wm * 128 + half * 64 + lane] =
                    st[w][er][lane];
            }
            asm volatile("" ::: "memory");
        }
    }
}

// ogemm: out[b][l][e2] (fp32) = ybf @ Wo^T
__global__ __launch_bounds__(512, 2) void k_ogemm(const __bf16* __restrict__ ybf, const __bf16* __restrict__ Wob,
                                                  float* __restrict__ out) {
    __shared__ __align__(16) char L[131072];
    int n0, m0, b;
    swz256(blockIdx.x, n0, m0, b);
    f32x4 acc[8][4];
    g3_core(ybf + ((size_t)b << 22), Wob, m0, n0, L, acc);
    int tid = threadIdx.x;
    int lane = tid & 63, w = tid >> 6;
    int wm = w >> 2, wn = w & 3;
    float* ob = out + ((size_t)b << 22);
#pragma unroll
    for (int mi = 0; mi < 8; ++mi)
#pragma unroll
        for (int ni = 0; ni < 4; ++ni)
#pragma unroll
            for (int r = 0; r < 4; ++r)
                ob[(size_t)(m0 + wm * 128 + mi * 16 + (lane >> 4) * 4 + r) * DDIM +
                   n0 + wn * 64 + ni * 16 + (lane & 15)] = acc[mi][ni][r];
}

// ================= rfft4096 per channel via cfft2048 (even/odd pack), radix 8-8-8-4 =================
__device__ __forceinline__ float2 cmul(float2 a, float2 b) {
    return make_float2(a.x * b.x - a.y * b.y, a.x * b.y + a.y * b.x);
}
__device__ __forceinline__ int P8(int i) { return i + (i >> 3) + (i >> 8); }
__device__ __forceinline__ int SR8(int k) {
    return ((k & 7) << 8) | (((k >> 3) & 7) << 5) | (((k >> 6) & 7) << 2) | (k >> 9);
}

template <int S>
__device__ __forceinline__ void dft4v(float2* x) {
    float2 t0 = make_float2(x[0].x + x[2].x, x[0].y + x[2].y);
    float2 t1 = make_float2(x[0].x - x[2].x, x[0].y - x[2].y);
    float2 t2 = make_float2(x[1].x + x[3].x, x[1].y + x[3].y);
    float2 t3 = make_float2(x[1].x - x[3].x, x[1].y - x[3].y);
    float2 j3 = (S == 1) ? make_float2(t3.y, -t3.x) : make_float2(-t3.y, t3.x);
    x[0] = make_float2(t0.x + t2.x, t0.y + t2.y);
    x[2] = make_float2(t0.x - t2.x, t0.y - t2.y);
    x[1] = make_float2(t1.x + j3.x, t1.y + j3.y);
    x[3] = make_float2(t1.x - j3.x, t1.y - j3.y);
}

template <int S>
__device__ __forceinline__ void dft8v(float2* x) {
    float2 e[4] = {x[0], x[2], x[4], x[6]};
    float2 o[4] = {x[1], x[3], x[5], x[7]};
    dft4v<S>(e);
    dft4v<S>(o);
    const float c = 0.7071067811865476f;
    const float sg = (S == 1) ? -1.f : 1.f;
    o[1] = cmul(o[1], make_float2(c, sg * c));
    o[2] = (S == 1) ? make_float2(o[2].y, -o[2].x) : make_float2(-o[2].y, o[2].x);
    o[3] = cmul(o[3], make_float2(-c, sg * c));
    x[0] = make_float2(e[0].x + o[0].x, e[0].y + o[0].y);
    x[4] = make_float2(e[0].x - o[0].x, e[0].y - o[0].y);
    x[1] = make_float2(e[1].x + o[1].x, e[1].y + o[1].y);
    x[5] = make_float2(e[1].x - o[1].x, e[1].y - o[1].y);
    x[2] = make_float2(e[2].x + o[2].x, e[2].y + o[2].y);
    x[6] = make_float2(e[2].x - o[2].x, e[2].y - o[2].y);
    x[3] = make_float2(e[3].x + o[3].x, e[3].y + o[3].y);
    x[7] = make_float2(e[3].x - o[3].x, e[3].y - o[3].y);
}

template <int S>
__device__ __forceinline__ void tw8(float2* x, int j, float invN) {
    float base = ((S == 1) ? -6.283185307179586f : 6.283185307179586f) * invN;
    float sn, cs;
    __sincosf(base * (float)j, &sn, &cs);
    float2 w1 = make_float2(cs, sn);
    float2 w2 = cmul(w1, w1);
    float2 w3 = cmul(w2, w1);
    float2 w4 = cmul(w2, w2);
    float2 w5 = cmul(w4, w1);
    float2 w6 = cmul(w4, w2);
    float2 w7 = cmul(w4, w3);
    x[1] = cmul(x[1], w1);
    x[2] = cmul(x[2], w2);
    x[3] = cmul(x[3], w3);
    x[4] = cmul(x[4], w4);
    x[5] = cmul(x[5], w5);
    x[6] = cmul(x[6], w6);
    x[7] = cmul(x[7], w7);
}

__global__ __launch_bounds__(256, 2) void k_fft(__bf16* __restrict__ vty,
                                                const float* __restrict__ gre, const float* __restrict__ gim,
                                                const float* __restrict__ mrb, const float* __restrict__ gwp1) {
    __shared__ float2 Zp[2312];
    int pid = blockIdx.x;
    int b = pid >> 10, e = pid & 1023;
    int h = e >> 6, dh = e & 63;
    int bh = b * 16 + h;
    size_t gbase = (size_t)bh * NFREQ;
    size_t mbase = (size_t)h * NFMAX;
    __bf16* row = vty + ((size_t)b << 22) + ((size_t)e << 12);
    int t = threadIdx.x;

#pragma unroll
    for (int cc = 0; cc < 2; ++cc) {
        int c = t + cc * 256;
        bf16_8 a = *(const bf16_8*)&row[c * 8];
#pragma unroll
        for (int q = 0; q < 4; ++q)
            Zp[P8(c * 4 + q)] = make_float2((float)a[2 * q], (float)a[2 * q + 1]);
    }
    __syncthreads();

    float2 x[8];
    {
#pragma unroll
        for (int r = 0; r < 8; ++r) x[r] = Zp[P8(r * 256 + t)];
        dft8v<1>(x);
        tw8<1>(x, t, 1.0f / 2048.0f);
#pragma unroll
        for (int r = 0; r < 8; ++r) Zp[P8(r * 256 + t)] = x[r];
    }
    __syncthreads();
    {
        int g = t >> 5, j = t & 31, base = g * 256 + j;
#pragma unroll
        for (int r = 0; r < 8; ++r) x[r] = Zp[P8(base + r * 32)];
        dft8v<1>(x);
        tw8<1>(x, j, 1.0f / 256.0f);
#pragma unroll
        for (int r = 0; r < 8; ++r) Zp[P8(base + r * 32)] = x[r];
    }
    __syncthreads();
    {
        int g = t >> 2, j = t & 3, base = g * 32 + j;
#pragma unroll
        for (int r = 0; r < 8; ++r) x[r] = Zp[P8(base + r * 4)];
        dft8v<1>(x);
        tw8<1>(x, j, 1.0f / 32.0f);
#pragma unroll
        for (int r = 0; r < 8; ++r) Zp[P8(base + r * 4)] = x[r];
    }
    __syncthreads();
    {
        int base = t * 8;
#pragma unroll
        for (int q = 0; q < 4; ++q) { x[q] = Zp[P8(base + q)]; x[4 + q] = Zp[P8(base + 4 + q)]; }
        dft4v<1>(x);
        dft4v<1>(x + 4);
#pragma unroll
        for (int q = 0; q < 4; ++q) { Zp[P8(base + q)] = x[q]; Zp[P8(base + 4 + q)] = x[4 + q]; }
    }
    __syncthreads();

    {
        float sn0, cs0;
        __sincosf(-1.5339807878856412e-3f * (float)(1 + t), &sn0, &cs0);
        float2 wk = make_float2(cs0, sn0);
        const float2 W256 = make_float2(0.92387953251128675613f, -0.38268343236508977172f);
#pragma unroll
        for (int r = 0; r < 4; ++r) {
            int k = 1 + (r << 8) + t;
            int k2 = 2048 - k;
            int sA = P8(SR8(k)), sB = P8(SR8(k2));
            float cs = wk.x, sn = wk.y;
            float2 Za = Zp[sA], Zb = Zp[sB];
            float Er = 0.5f * (Za.x + Zb.x), Ei = 0.5f * (Za.y - Zb.y);
            float Dr = 0.5f * (Za.x - Zb.x), Di = 0.5f * (Za.y + Zb.y);
            float WDr = cs * Dr - sn * Di, WDi = cs * Di + sn * Dr;
            float Tr = -WDi, Ti = WDr;
            float Vkr = Er - Tr, Vki = Ei - Ti;
            float Vk2r = Er + Tr, Vk2i = -(Ei + Ti);
            float g1r = gre[gbase + k], g1i = gim[gbase + k], b1v = mrb[mbase + k];
            float Ykr = Vkr * g1r - Vki * g1i, Yki = Vkr * g1i + Vki * g1r;
            float m1 = sqrtf(Ykr * Ykr + Yki * Yki);
            float s1 = fmaxf(m1 + b1v, 0.f) / (m1 + 1e-6f);
            Ykr *= s1; Yki *= s1;
            float g2r = gre[gbase + k2], g2i = gim[gbase + k2], b2v = mrb[mbase + k2];
            float Yk2r = Vk2r * g2r - Vk2i * g2i, Yk2i = Vk2r * g2i + Vk2i * g2r;
            float m2 = sqrtf(Yk2r * Yk2r + Yk2i * Yk2i);
            float s2 = fmaxf(m2 + b2v, 0.f) / (m2 + 1e-6f);
            Yk2r *= s2; Yk2i *= s2;
            float Epr = 0.5f * (Ykr + Yk2r), Epi = 0.5f * (Yki - Yk2i);
            float Fr = 0.5f * (Ykr - Yk2r), Fi = 0.5f * (Yki + Yk2i);
            float CWFr = cs * Fr + sn * Fi;
            float CWFi = cs * Fi - sn * Fr;
            Zp[sA] = make_float2(Epr - CWFi, Epi + CWFr);
            Zp[sB] = make_float2(Epr + CWFi, -Epi + CWFr);
            wk = cmul(wk, W256);
        }
    }
    if (t == 0) {
        float2 Z0 = Zp[P8(0)];
        float V0 = Z0.x + Z0.y, VN = Z0.x - Z0.y;
        float g0r = gre[gbase], g0i = gim[gbase], b0v = mrb[mbase];
        float y0r = V0 * g0r, y0i = V0 * g0i;
        float m0 = sqrtf(y0r * y0r + y0i * y0i);
        float Y0 = y0r * (fmaxf(m0 + b0v, 0.f) / (m0 + 1e-6f));
        float gNr = gre[gbase + 2048], gNi = gim[gbase + 2048], bNv = mrb[mbase + 2048];
        float yNr = VN * gNr, yNi = VN * gNi;
        float mN = sqrtf(yNr * yNr + yNi * yNi);
        float YN = yNr * (fmaxf(mN + bNv, 0.f) / (mN + 1e-6f));
        Zp[P8(0)] = make_float2(0.5f * (Y0 + YN), 0.5f * (Y0 - YN));
    }
    __syncthreads();

    {
        int base = t * 8;
#pragma unroll
        for (int q = 0; q < 4; ++q) { x[q] = Zp[P8(base + q)]; x[4 + q] = Zp[P8(base + 4 + q)]; }
        dft4v<-1>(x);
        dft4v<-1>(x + 4);
#pragma unroll
        for (int q = 0; q < 4; ++q) { Zp[P8(base + q)] = x[q]; Zp[P8(base + 4 + q)] = x[4 + q]; }
    }
    __syncthreads();
    {
        int g = t >> 2, j = t & 3, base = g * 32 + j;
#pragma unroll
        for (int r = 0; r < 8; ++r) x[r] = Zp[P8(base + r * 4)];
        tw8<-1>(x, j, 1.0f / 32.0f);
        dft8v<-1>(x);
#pragma unroll
        for (int r = 0; r < 8; ++r) Zp[P8(base + r * 4)] = x[r];
    }
    __syncthreads();
    {
        int g = t >> 5, j = t & 31, base = g * 256 + j;
#pragma unroll
        for (int r = 0; r < 8; ++r) x[r] = Zp[P8(base + r * 32)];
        tw8<-1>(x, j, 1.0f / 256.0f);
        dft8v<-1>(x);
#pragma unroll
        for (int r = 0; r < 8; ++r) Zp[P8(base + r * 32)] = x[r];
    }
    __syncthreads();
    {
#pragma unroll
        for (int r = 0; r < 8; ++r) x[r] = Zp[P8(r * 256 + t)];
        tw8<-1>(x, t, 1.0f / 2048.0f);
        dft8v<-1>(x);
        float sc = gwp1[bh * 64 + dh] * (1.0f / 2048.0f);
        unsigned int* row32 = (unsigned int*)row;
#pragma unroll
        for (int r = 0; r < 8; ++r) {
            __bf16 h1 = (__bf16)(x[r].x * sc);
            __bf16 h2 = (__bf16)(x[r].y * sc);
            unsigned int u = (unsigned int)__builtin_bit_cast(unsigned short, h1) |
                             ((unsigned int)__builtin_bit_cast(unsigned short, h2) << 16);
            row32[t + 256 * r] = u;
        }
    }
}

// ---------------- transpose: vt[b][e][l] bf16 -> ybf[b][l][e] bf16 ----------------
__global__ __launch_bounds__(256) void k_t2(const __bf16* __restrict__ vt, __bf16* __restrict__ ybf) {
    __shared__ __bf16 tl[64][66];
    int e0 = blockIdx.x * 64, l0 = blockIdx.y * 64, b = blockIdx.z;
    int t = threadIdx.x;
    const __bf16* src = vt + ((size_t)b << 22);
    __bf16* dst = ybf + ((size_t)b << 22);
    int er = t >> 3, lc = (t & 7) * 8;
#pragma unroll
    for (int it = 0; it < 2; ++it) {
        int e = er + it * 32;
        bf16_8 v = *(const bf16_8*)&src[(size_t)(e0 + e) * LSEQ + l0 + lc];
#pragma unroll
        for (int j = 0; j < 8; ++j) tl[e][lc + j] = v[j];
    }
    __syncthreads();
    int lr = t >> 3, ec = (t & 7) * 8;
#pragma unroll
    for (int it = 0; it < 2; ++it) {
        int l = lr + it * 32;
        bf16_8 v;
#pragma unroll
        for (int j = 0; j < 8; ++j) v[j] = tl[ec + j][l];
        *(bf16_8*)&dst[(size_t)(l0 + l) * DDIM + e0 + ec] = v;
    }
}

extern "C" void kernel_launch(void* const* d_in, const int* in_sizes, int n_in,
                              void* d_out, int out_size, void* d_ws, size_t ws_size,
                              hipStream_t stream) {
    const float* x      = (const float*)d_in[0];
    const float* Wq     = (const float*)d_in[1];
    const float* Wv     = (const float*)d_in[2];
    const float* Wo     = (const float*)d_in[3];
    const float* ln_g_s = (const float*)d_in[4];
    const float* ln_g_b = (const float*)d_in[5];
    const float* W1     = (const float*)d_in[6];
    const float* b1     = (const float*)d_in[7];
    const float* W2     = (const float*)d_in[8];
    const float* b2     = (const float*)d_in[9];
    const float* mrb    = (const float*)d_in[10];
    const float* ln_w_s = (const float*)d_in[11];
    const float* ln_w_b = (const float*)d_in[12];
    const float* Ww1    = (const float*)d_in[13];
    const float* bw1    = (const float*)d_in[14];
    const float* Ww2    = (const float*)d_in[15];
    const float* bw2    = (const float*)d_in[16];
    float* out = (float*)d_out;

    char* W = (char*)d_ws;
    __bf16* xbf = (__bf16*)W;                       // 33,554,432 B (later aliased as ybf)
    __bf16* ybf = xbf;
    __bf16* Wvb = (__bf16*)(W + 33554432);          // 2 MB
    __bf16* Wob = (__bf16*)(W + 35651584);          // 2 MB
    float*  xbp = (float*)(W + 37748736);
    float*  xbar= (float*)(W + 38010880);
    float*  qbar= (float*)(W + 38027264);
    float*  h1g = (float*)(W + 38043648);
    float*  gwp1= (float*)(W + 38109184);
    float*  gre = (float*)(W + 38125568);
    float*  gim = (float*)(W + 38650112);

    __bf16* vt = (__bf16*)d_out;                    // scratch inside d_out

    k_xbar_partial<<<dim3(4, 16, 4), 256, 0, stream>>>(x, xbp, xbf);
    k_cvt<<<1024, 256, 0, stream>>>(Wv, Wvb, DDIM * DDIM);
    k_cvt<<<1024, 256, 0, stream>>>(Wo, Wob, DDIM * DDIM);
    k_xbar_reduce<<<dim3(4, 4), 256, 0, stream>>>(xbp, xbar);
    k_qbar<<<256, 256, 0, stream>>>(xbar, Wq, qbar);
    k_mlp<<<64, 256, 0, stream>>>(qbar, ln_g_s, ln_g_b, W1, b1, ln_w_s, ln_w_b,
                                  Ww1, bw1, Ww2, bw2, h1g, gwp1);
    k_gate<<<1025, 256, 0, stream>>>(h1g, W2, b2, gre, gim);
    k_vgemm<<<256, 512, 0, stream>>>(xbf, Wvb, vt);
    k_fft<<<4096, 256, 0, stream>>>(vt, gre, gim, mrb, gwp1);
    k_t2<<<dim3(16, 64, 4), 256, 0, stream>>>(vt, ybf);
    k_ogemm<<<256, 512, 0, stream>>>(ybf, Wob, out);
}

// Round 12
// 193.851 us; speedup vs baseline: 6.1712x; 1.0371x over previous
//
#include <hip/hip_runtime.h>
#include <math.h>

#define LSEQ 4096
#define DDIM 1024
#define NB 4
#define NH 16
#define DHD 64
#define NFREQ 2049
#define NFMAX 4097

typedef __bf16 bf16_8 __attribute__((ext_vector_type(8)));
typedef float f32x4 __attribute__((ext_vector_type(4)));
typedef float f2 __attribute__((ext_vector_type(2)));

__device__ __forceinline__ float gelu_exact(float v) {
    return 0.5f * v * (1.0f + erff(v * 0.70710678118654752440f));
}

__device__ __forceinline__ void gload16(const void* g, void* l) {
    __builtin_amdgcn_global_load_lds((const __attribute__((address_space(1))) char*)g,
                                     (__attribute__((address_space(3))) char*)l, 16, 0, 0);
}

// ---------------- xbar partial + x -> bf16 cast (single pass over x) ----------------
__global__ __launch_bounds__(256) void k_xbar_partial(const float* __restrict__ x, float* __restrict__ xbp,
                                                      __bf16* __restrict__ xbf) {
    int d = blockIdx.x * 256 + threadIdx.x;
    int chunk = blockIdx.y;
    int b = blockIdx.z;
    size_t base = ((size_t)b * LSEQ + (size_t)chunk * 256) * DDIM + d;
    float acc = 0.f;
    for (int l = 0; l < 256; ++l) {
        float v = x[base + (size_t)l * DDIM];
        acc += v;
        xbf[base + (size_t)l * DDIM] = (__bf16)v;
    }
    xbp[(size_t)(b * 16 + chunk) * DDIM + d] = acc;
}

__global__ __launch_bounds__(256) void k_xbar_reduce(const float* __restrict__ xbp, float* __restrict__ xbar) {
    int d = blockIdx.x * 256 + threadIdx.x;
    int b = blockIdx.y;
    float acc = 0.f;
    for (int c = 0; c < 16; ++c) acc += xbp[(size_t)(b * 16 + c) * DDIM + d];
    xbar[b * DDIM + d] = acc * (1.0f / LSEQ);
}

// ---------------- weight fp32 -> bf16 ----------------
__global__ __launch_bounds__(256) void k_cvt(const float* __restrict__ s, __bf16* __restrict__ d, int n) {
    int i = (blockIdx.x * 256 + threadIdx.x) * 4;
    if (i < n) {
        float4 v = *(const float4*)(s + i);
        d[i] = (__bf16)v.x; d[i + 1] = (__bf16)v.y; d[i + 2] = (__bf16)v.z; d[i + 3] = (__bf16)v.w;
    }
}

// ---------------- q_bar = xbar @ Wq^T ----------------
__global__ __launch_bounds__(256) void k_qbar(const float* __restrict__ xbar, const float* __restrict__ Wq,
                                              float* __restrict__ qbar) {
    int lane = threadIdx.x & 63;
    int e = blockIdx.x * 4 + (threadIdx.x >> 6);
    const float* wrow = Wq + (size_t)e * DDIM;
    float a0 = 0, a1 = 0, a2 = 0, a3 = 0;
    for (int i = 0; i < 16; ++i) {
        int d = lane + i * 64;
        float w = wrow[d];
        a0 += w * xbar[d];
        a1 += w * xbar[DDIM + d];
        a2 += w * xbar[2 * DDIM + d];
        a3 += w * xbar[3 * DDIM + d];
    }
    for (int off = 32; off > 0; off >>= 1) {
        a0 += __shfl_down(a0, off);
        a1 += __shfl_down(a1, off);
        a2 += __shfl_down(a2, off);
        a3 += __shfl_down(a3, off);
    }
    if (lane == 0) {
        qbar[e] = a0;
        qbar[DDIM + e] = a1;
        qbar[2 * DDIM + e] = a2;
        qbar[3 * DDIM + e] = a3;
    }
}

// ---------------- per-(b,h) MLPs ----------------
__global__ __launch_bounds__(256) void k_mlp(const float* __restrict__ qbar,
                                             const float* __restrict__ ln_g_s, const float* __restrict__ ln_g_b,
                                             const float* __restrict__ W1, const float* __restrict__ b1,
                                             const float* __restrict__ ln_w_s, const float* __restrict__ ln_w_b,
                                             const float* __restrict__ Ww1, const float* __restrict__ bw1,
                                             const float* __restrict__ Ww2, const float* __restrict__ bw2,
                                             float* __restrict__ h1g, float* __restrict__ gwp1) {
    int bh = blockIdx.x;
    __shared__ float q[64], hg[64], hw[64], g1[64];
    __shared__ float sm, sv;
    int t = threadIdx.x;
    if (t < 64) q[t] = qbar[bh * 64 + t];
    __syncthreads();
    if (t == 0) {
        float m = 0;
        for (int i = 0; i < 64; ++i) m += q[i];
        m *= (1.0f / 64.0f);
        float v = 0;
        for (int i = 0; i < 64; ++i) { float dd = q[i] - m; v += dd * dd; }
        v *= (1.0f / 64.0f);
        sm = m; sv = v;
    }
    __syncthreads();
    if (t < 64) {
        float n = (q[t] - sm) * rsqrtf(sv + 1e-5f);
        hg[t] = n * ln_g_s[t] + ln_g_b[t];
        hw[t] = n * ln_w_s[t] + ln_w_b[t];
    }
    __syncthreads();
    {
        int f = t;
        const float* w = W1 + (size_t)f * 64;
        float s = b1[f];
        for (int d0 = 0; d0 < 64; ++d0) s += hg[d0] * w[d0];
        h1g[(size_t)bh * 256 + f] = gelu_exact(s);
    }
    if (t < 64) {
        const float* w = Ww1 + (size_t)t * 64;
        float s = bw1[t];
        for (int k = 0; k < 64; ++k) s += hw[k] * w[k];
        g1[t] = gelu_exact(s);
    }
    __syncthreads();
    if (t < 64) {
        const float* w = Ww2 + (size_t)t * 64;
        float s = bw2[t];
        for (int k = 0; k < 64; ++k) s += g1[k] * w[k];
        gwp1[bh * 64 + t] = 1.0f + 1.0f / (1.0f + expf(-s));
    }
}

// ---------------- gate rows ----------------
__global__ __launch_bounds__(256) void k_gate(const float* __restrict__ h1g, const float* __restrict__ W2,
                                              const float* __restrict__ b2,
                                              float* __restrict__ gre, float* __restrict__ gim) {
    int task = blockIdx.x * 4 + (threadIdx.x >> 6);
    if (task >= 2 * NFREQ) return;
    int lane = threadIdx.x & 63;
    int part = task >= NFREQ;
    int f = task - part * NFREQ;
    int row = part ? (NFMAX + f) : f;
    const float* w = W2 + (size_t)row * 256;
    float w0 = w[lane], w1 = w[64 + lane], w2 = w[128 + lane], w3 = w[192 + lane];
    float bias = b2[row];
    float* dst = part ? gim : gre;
    for (int bh = 0; bh < 64; ++bh) {
        const float* hr = h1g + (size_t)bh * 256;
        float p = w0 * hr[lane] + w1 * hr[64 + lane] + w2 * hr[128 + lane] + w3 * hr[192 + lane];
        for (int off = 32; off > 0; off >>= 1) p += __shfl_down(p, off);
        if (lane == 0) dst[(size_t)bh * NFREQ + f] = p + bias;
    }
}

// ================= 256x256, 8-wave, BK=64, dbuf LDS, counted-vmcnt pipeline =================
__device__ __forceinline__ void swz256(int bid, int& n0, int& m0, int& b) {
    int w = (bid & 7) * 32 + (bid >> 3);
    b = w >> 6;
    m0 = ((w >> 2) & 15) << 8;
    n0 = (w & 3) << 8;
}

__device__ __forceinline__ void g3_stage_half(const __bf16* __restrict__ src, int row0, int kt,
                                              char* ldshalf, int tid) {
#pragma unroll
    for (int j = 0; j < 2; ++j) {
        int c = j * 512 + tid;
        int r = c >> 3;                              // 0..127
        int kc = ((c & 7) ^ (r & 7)) * 8;            // source slot = dest slot ^ (row&7)
        char* dst = ldshalf + (size_t)(j * 512 + (tid & ~63)) * 16;  // wave-uniform base
        gload16(src + ((size_t)(row0 + r) << 10) + kt * 64 + kc, dst);
    }
}

__device__ __forceinline__ void g3_compute(const char* L, int db, int wm, int wn,
                                           int lrow, int lsl, f32x4 (&acc)[8][4]) {
    const char* Ab = L + db * 32768 + wm * 16384;
    const char* Bb = L + 65536 + db * 32768 + (wn >> 1) * 16384;
    int xs = lrow & 7;
    int brb = (wn & 1) * 64;
#pragma unroll
    for (int kk = 0; kk < 2; ++kk) {
        int slot = ((kk * 4 + lsl) ^ xs) << 4;
        bf16_8 af[8], bfr[4];
#pragma unroll
        for (int mi = 0; mi < 8; ++mi)
            af[mi] = *(const bf16_8*)(Ab + (mi * 16 + lrow) * 128 + slot);
#pragma unroll
        for (int ni = 0; ni < 4; ++ni)
            bfr[ni] = *(const bf16_8*)(Bb + (brb + ni * 16 + lrow) * 128 + slot);
        __builtin_amdgcn_s_setprio(1);
#pragma unroll
        for (int mi = 0; mi < 8; ++mi)
#pragma unroll
            for (int ni = 0; ni < 4; ++ni)
                acc[mi][ni] = __builtin_amdgcn_mfma_f32_16x16x32_bf16(af[mi], bfr[ni], acc[mi][ni], 0, 0, 0);
        __builtin_amdgcn_s_setprio(0);
    }
}

__device__ __forceinline__ void g3_core(const __bf16* __restrict__ A, const __bf16* __restrict__ B,
                                        int m0, int n0, char* L, f32x4 (&acc)[8][4]) {
    int tid = threadIdx.x;
    int lane = tid & 63, w = tid >> 6;
    int wm = w >> 2, wn = w & 3;
    int lrow = lane & 15, lsl = lane >> 4;
#pragma unroll
    for (int mi = 0; mi < 8; ++mi)
#pragma unroll
        for (int ni = 0; ni < 4; ++ni) acc[mi][ni] = (f32x4){0.f, 0.f, 0.f, 0.f};

#define G3_STAGE(KT, DB)                                                        \
    do {                                                                        \
        g3_stage_half(A, m0,       (KT), L + (DB) * 32768,               tid);  \
        g3_stage_half(A, m0 + 128, (KT), L + (DB) * 32768 + 16384,       tid);  \
        g3_stage_half(B, n0,       (KT), L + 65536 + (DB) * 32768,       tid);  \
        g3_stage_half(B, n0 + 128, (KT), L + 65536 + (DB) * 32768 + 16384, tid);\
    } while (0)

    G3_STAGE(0, 0);
    G3_STAGE(1, 1);
    asm volatile("s_waitcnt vmcnt(8)" ::: "memory");   // tile0's 8 loads done; tile1's in flight
    __builtin_amdgcn_s_barrier();
    asm volatile("" ::: "memory");
#pragma unroll 1
    for (int kt = 0; kt < 16; ++kt) {
        int db = kt & 1;
        g3_compute(L, db, wm, wn, lrow, lsl, acc);
        asm volatile("s_waitcnt lgkmcnt(0)" ::: "memory");  // my ds_reads of buf[db] retired
        __builtin_amdgcn_s_barrier();                       // all waves done reading buf[db]
        asm volatile("" ::: "memory");
        if (kt < 14) {
            G3_STAGE(kt + 2, db);                           // overwrite buf[db]; stays in flight
            asm volatile("s_waitcnt vmcnt(8)" ::: "memory");// tile kt+1 done; kt+2's 8 in flight
            __builtin_amdgcn_s_barrier();
            asm volatile("" ::: "memory");
        } else if (kt == 14) {
            asm volatile("s_waitcnt vmcnt(0)" ::: "memory");// tile 15 done
            __builtin_amdgcn_s_barrier();
            asm volatile("" ::: "memory");
        }
    }
#undef G3_STAGE
}

// vgemm: vt[b][e][l] (bf16) = (x @ Wv^T)^T  (transposed epilogue via per-wave LDS staging)
__global__ __launch_bounds__(512, 2) void k_vgemm(const __bf16* __restrict__ xbf, const __bf16* __restrict__ Wvb,
                                                  __bf16* __restrict__ vt) {
    __shared__ __align__(16) char L[131072 + 17408];
    __bf16 (*st)[16][68] = (__bf16(*)[16][68])(L + 131072);
    int n0, m0, b;
    swz256(blockIdx.x, n0, m0, b);
    f32x4 acc[8][4];
    g3_core(xbf + ((size_t)b << 22), Wvb, m0, n0, L, acc);
    int tid = threadIdx.x;
    int lane = tid & 63, w = tid >> 6;
    int wm = w >> 2, wn = w & 3;
    size_t vbase = ((size_t)b << 22);
#pragma unroll
    for (int ni = 0; ni < 4; ++ni) {
#pragma unroll
        for (int half = 0; half < 2; ++half) {
#pragma unroll
            for (int ml = 0; ml < 4; ++ml)
#pragma unroll
                for (int r = 0; r < 4; ++r)
                    st[w][lane & 15][ml * 16 + (lane >> 4) * 4 + r] = (__bf16)acc[half * 4 + ml][ni][r];
            asm volatile("" ::: "memory");
#pragma unroll
            for (int er = 0; er < 16; ++er) {
                vt[vbase + (size_t)(n0 + wn * 64 + ni * 16 + er) * LSEQ + m0 + wm * 128 + half * 64 + lane] =
                    st[w][er][lane];
            }
            asm volatile("" ::: "memory");
        }
    }
}

// ogemm: out[b][l][e2] (fp32) = ybf @ Wo^T
__global__ __launch_bounds__(512, 2) void k_ogemm(const __bf16* __restrict__ ybf, const __bf16* __restrict__ Wob,
                                                  float* __restrict__ out) {
    __shared__ __align__(16) char L[131072];
    int n0, m0, b;
    swz256(blockIdx.x, n0, m0, b);
    f32x4 acc[8][4];
    g3_core(ybf + ((size_t)b << 22), Wob, m0, n0, L, acc);
    int tid = threadIdx.x;
    int lane = tid & 63, w = tid >> 6;
    int wm = w >> 2, wn = w & 3;
    float* ob = out + ((size_t)b << 22);
#pragma unroll
    for (int mi = 0; mi < 8; ++mi)
#pragma unroll
        for (int ni = 0; ni < 4; ++ni)
#pragma unroll
            for (int r = 0; r < 4; ++r)
                ob[(size_t)(m0 + wm * 128 + mi * 16 + (lane >> 4) * 4 + r) * DDIM +
                   n0 + wn * 64 + ni * 16 + (lane & 15)] = acc[mi][ni][r];
}

// ================= rfft4096 per channel via cfft2048 (even/odd pack), radix 8-8-8-4 =================
// Complex = 2-lane fp32 vector -> VOP3P packed ops (v_pk_add/mul/fma_f32).
__device__ __forceinline__ f2 cmul2(f2 a, f2 b) {
    f2 t = a * (f2){b.x, b.x};
    f2 ayx = __builtin_shufflevector(a, a, 1, 0);
    return t + ayx * (f2){-b.y, b.y};
}
__device__ __forceinline__ f2 mulmi(f2 v) {  // v * (-i) = (v.y, -v.x)
    f2 s = __builtin_shufflevector(v, v, 1, 0);
    return s * (f2){1.f, -1.f};
}
__device__ __forceinline__ f2 mulpi(f2 v) {  // v * (+i) = (-v.y, v.x)
    f2 s = __builtin_shufflevector(v, v, 1, 0);
    return s * (f2){-1.f, 1.f};
}
__device__ __forceinline__ int P8(int i) { return i + (i >> 3) + (i >> 8); }
__device__ __forceinline__ int SR8(int k) {
    return ((k & 7) << 8) | (((k >> 3) & 7) << 5) | (((k >> 6) & 7) << 2) | (k >> 9);
}

template <int S>
__device__ __forceinline__ void dft4v(f2* x) {
    f2 t0 = x[0] + x[2], t1 = x[0] - x[2];
    f2 t2 = x[1] + x[3], t3 = x[1] - x[3];
    f2 j3 = (S == 1) ? mulmi(t3) : mulpi(t3);
    x[0] = t0 + t2;
    x[2] = t0 - t2;
    x[1] = t1 + j3;
    x[3] = t1 - j3;
}

template <int S>
__device__ __forceinline__ void dft8v(f2* x) {
    f2 e[4] = {x[0], x[2], x[4], x[6]};
    f2 o[4] = {x[1], x[3], x[5], x[7]};
    dft4v<S>(e);
    dft4v<S>(o);
    const float c = 0.7071067811865476f;
    const float sg = (S == 1) ? -1.f : 1.f;
    o[1] = cmul2(o[1], (f2){c, sg * c});
    o[2] = (S == 1) ? mulmi(o[2]) : mulpi(o[2]);
    o[3] = cmul2(o[3], (f2){-c, sg * c});
    x[0] = e[0] + o[0];
    x[4] = e[0] - o[0];
    x[1] = e[1] + o[1];
    x[5] = e[1] - o[1];
    x[2] = e[2] + o[2];
    x[6] = e[2] - o[2];
    x[3] = e[3] + o[3];
    x[7] = e[3] - o[3];
}

// log-depth twiddle product tree (1 sincos + 6 cmuls)
template <int S>
__device__ __forceinline__ void tw8(f2* x, int j, float invN) {
    float base = ((S == 1) ? -6.283185307179586f : 6.283185307179586f) * invN;
    float sn, cs;
    __sincosf(base * (float)j, &sn, &cs);
    f2 w1 = (f2){cs, sn};
    f2 w2 = cmul2(w1, w1);
    f2 w3 = cmul2(w2, w1);
    f2 w4 = cmul2(w2, w2);
    f2 w5 = cmul2(w4, w1);
    f2 w6 = cmul2(w4, w2);
    f2 w7 = cmul2(w4, w3);
    x[1] = cmul2(x[1], w1);
    x[2] = cmul2(x[2], w2);
    x[3] = cmul2(x[3], w3);
    x[4] = cmul2(x[4], w4);
    x[5] = cmul2(x[5], w5);
    x[6] = cmul2(x[6], w6);
    x[7] = cmul2(x[7], w7);
}

__global__ __launch_bounds__(256, 2) void k_fft(__bf16* __restrict__ vty,
                                                const float* __restrict__ gre, const float* __restrict__ gim,
                                                const float* __restrict__ mrb, const float* __restrict__ gwp1) {
    __shared__ f2 Zp[2312];
    int pid = blockIdx.x;
    int b = pid >> 10, e = pid & 1023;
    int h = e >> 6, dh = e & 63;
    int bh = b * 16 + h;
    size_t gbase = (size_t)bh * NFREQ;
    size_t mbase = (size_t)h * NFMAX;
    __bf16* row = vty + ((size_t)b << 22) + ((size_t)e << 12);
    int t = threadIdx.x;

#pragma unroll
    for (int cc = 0; cc < 2; ++cc) {
        int c = t + cc * 256;
        bf16_8 a = *(const bf16_8*)&row[c * 8];
#pragma unroll
        for (int q = 0; q < 4; ++q)
            Zp[P8(c * 4 + q)] = (f2){(float)a[2 * q], (float)a[2 * q + 1]};
    }
    __syncthreads();

    f2 x[8];
    {
#pragma unroll
        for (int r = 0; r < 8; ++r) x[r] = Zp[P8(r * 256 + t)];
        dft8v<1>(x);
        tw8<1>(x, t, 1.0f / 2048.0f);
#pragma unroll
        for (int r = 0; r < 8; ++r) Zp[P8(r * 256 + t)] = x[r];
    }
    __syncthreads();
    {
        int g = t >> 5, j = t & 31, base = g * 256 + j;
#pragma unroll
        for (int r = 0; r < 8; ++r) x[r] = Zp[P8(base + r * 32)];
        dft8v<1>(x);
        tw8<1>(x, j, 1.0f / 256.0f);
#pragma unroll
        for (int r = 0; r < 8; ++r) Zp[P8(base + r * 32)] = x[r];
    }
    __syncthreads();
    {
        int g = t >> 2, j = t & 3, base = g * 32 + j;
#pragma unroll
        for (int r = 0; r < 8; ++r) x[r] = Zp[P8(base + r * 4)];
        dft8v<1>(x);
        tw8<1>(x, j, 1.0f / 32.0f);
#pragma unroll
        for (int r = 0; r < 8; ++r) Zp[P8(base + r * 4)] = x[r];
    }
    __syncthreads();
    {
        int base = t * 8;
#pragma unroll
        for (int q = 0; q < 4; ++q) { x[q] = Zp[P8(base + q)]; x[4 + q] = Zp[P8(base + 4 + q)]; }
        dft4v<1>(x);
        dft4v<1>(x + 4);
#pragma unroll
        for (int q = 0; q < 4; ++q) { Zp[P8(base + q)] = x[q]; Zp[P8(base + 4 + q)] = x[4 + q]; }
    }
    __syncthreads();

    // untangle + gate + modrelu + re-tangle; W^k chained by constant W256 = e^{-i*pi/8}
    {
        float sn0, cs0;
        __sincosf(-1.5339807878856412e-3f * (float)(1 + t), &sn0, &cs0);
        f2 wk = (f2){cs0, sn0};
        const f2 W256 = (f2){0.92387953251128675613f, -0.38268343236508977172f};
#pragma unroll
        for (int r = 0; r < 4; ++r) {
            int k = 1 + (r << 8) + t;
            int k2 = 2048 - k;
            int sA = P8(SR8(k)), sB = P8(SR8(k2));
            float cs = wk.x, sn = wk.y;
            f2 Za = Zp[sA], Zb = Zp[sB];
            float Er = 0.5f * (Za.x + Zb.x), Ei = 0.5f * (Za.y - Zb.y);
            float Dr = 0.5f * (Za.x - Zb.x), Di = 0.5f * (Za.y + Zb.y);
            float WDr = cs * Dr - sn * Di, WDi = cs * Di + sn * Dr;
            float Tr = -WDi, Ti = WDr;
            float Vkr = Er - Tr, Vki = Ei - Ti;
            float Vk2r = Er + Tr, Vk2i = -(Ei + Ti);
            float g1r = gre[gbase + k], g1i = gim[gbase + k], b1v = mrb[mbase + k];
            float Ykr = Vkr * g1r - Vki * g1i, Yki = Vkr * g1i + Vki * g1r;
            float m1 = sqrtf(Ykr * Ykr + Yki * Yki);
            float s1 = fmaxf(m1 + b1v, 0.f) / (m1 + 1e-6f);
            Ykr *= s1; Yki *= s1;
            float g2r = gre[gbase + k2], g2i = gim[gbase + k2], b2v = mrb[mbase + k2];
            float Yk2r = Vk2r * g2r - Vk2i * g2i, Yk2i = Vk2r * g2i + Vk2i * g2r;
            float m2 = sqrtf(Yk2r * Yk2r + Yk2i * Yk2i);
            float s2 = fmaxf(m2 + b2v, 0.f) / (m2 + 1e-6f);
            Yk2r *= s2; Yk2i *= s2;
            float Epr = 0.5f * (Ykr + Yk2r), Epi = 0.5f * (Yki - Yk2i);
            float Fr = 0.5f * (Ykr - Yk2r), Fi = 0.5f * (Yki + Yk2i);
            float CWFr = cs * Fr + sn * Fi;
            float CWFi = cs * Fi - sn * Fr;
            Zp[sA] = (f2){Epr - CWFi, Epi + CWFr};
            Zp[sB] = (f2){Epr + CWFi, -Epi + CWFr};
            wk = cmul2(wk, W256);
        }
    }
    if (t == 0) {
        f2 Z0 = Zp[P8(0)];
        float V0 = Z0.x + Z0.y, VN = Z0.x - Z0.y;
        float g0r = gre[gbase], g0i = gim[gbase], b0v = mrb[mbase];
        float y0r = V0 * g0r, y0i = V0 * g0i;
        float m0 = sqrtf(y0r * y0r + y0i * y0i);
        float Y0 = y0r * (fmaxf(m0 + b0v, 0.f) / (m0 + 1e-6f));
        float gNr = gre[gbase + 2048], gNi = gim[gbase + 2048], bNv = mrb[mbase + 2048];
        float yNr = VN * gNr, yNi = VN * gNi;
        float mN = sqrtf(yNr * yNr + yNi * yNi);
        float YN = yNr * (fmaxf(mN + bNv, 0.f) / (mN + 1e-6f));
        Zp[P8(0)] = (f2){0.5f * (Y0 + YN), 0.5f * (Y0 - YN)};
    }
    __syncthreads();

    {
        int base = t * 8;
#pragma unroll
        for (int q = 0; q < 4; ++q) { x[q] = Zp[P8(base + q)]; x[4 + q] = Zp[P8(base + 4 + q)]; }
        dft4v<-1>(x);
        dft4v<-1>(x + 4);
#pragma unroll
        for (int q = 0; q < 4; ++q) { Zp[P8(base + q)] = x[q]; Zp[P8(base + 4 + q)] = x[4 + q]; }
    }
    __syncthreads();
    {
        int g = t >> 2, j = t & 3, base = g * 32 + j;
#pragma unroll
        for (int r = 0; r < 8; ++r) x[r] = Zp[P8(base + r * 4)];
        tw8<-1>(x, j, 1.0f / 32.0f);
        dft8v<-1>(x);
#pragma unroll
        for (int r = 0; r < 8; ++r) Zp[P8(base + r * 4)] = x[r];
    }
    __syncthreads();
    {
        int g = t >> 5, j = t & 31, base = g * 256 + j;
#pragma unroll
        for (int r = 0; r < 8; ++r) x[r] = Zp[P8(base + r * 32)];
        tw8<-1>(x, j, 1.0f / 256.0f);
        dft8v<-1>(x);
#pragma unroll
        for (int r = 0; r < 8; ++r) Zp[P8(base + r * 32)] = x[r];
    }
    __syncthreads();
    {
#pragma unroll
        for (int r = 0; r < 8; ++r) x[r] = Zp[P8(r * 256 + t)];
        tw8<-1>(x, t, 1.0f / 2048.0f);
        dft8v<-1>(x);
        float sc = gwp1[bh * 64 + dh] * (1.0f / 2048.0f);
        unsigned int* row32 = (unsigned int*)row;
#pragma unroll
        for (int r = 0; r < 8; ++r) {
            __bf16 h1 = (__bf16)(x[r].x * sc);
            __bf16 h2 = (__bf16)(x[r].y * sc);
            unsigned int u = (unsigned int)__builtin_bit_cast(unsigned short, h1) |
                             ((unsigned int)__builtin_bit_cast(unsigned short, h2) << 16);
            row32[t + 256 * r] = u;
        }
    }
}

// ---------------- transpose: vt[b][e][l] bf16 -> ybf[b][l][e] bf16 ----------------
__global__ __launch_bounds__(256) void k_t2(const __bf16* __restrict__ vt, __bf16* __restrict__ ybf) {
    __shared__ __bf16 tl[64][66];
    int e0 = blockIdx.x * 64, l0 = blockIdx.y * 64, b = blockIdx.z;
    int t = threadIdx.x;
    const __bf16* src = vt + ((size_t)b << 22);
    __bf16* dst = ybf + ((size_t)b << 22);
    int er = t >> 3, lc = (t & 7) * 8;
#pragma unroll
    for (int it = 0; it < 2; ++it) {
        int e = er + it * 32;
        bf16_8 v = *(const bf16_8*)&src[(size_t)(e0 + e) * LSEQ + l0 + lc];
#pragma unroll
        for (int j = 0; j < 8; ++j) tl[e][lc + j] = v[j];
    }
    __syncthreads();
    int lr = t >> 3, ec = (t & 7) * 8;
#pragma unroll
    for (int it = 0; it < 2; ++it) {
        int l = lr + it * 32;
        bf16_8 v;
#pragma unroll
        for (int j = 0; j < 8; ++j) v[j] = tl[ec + j][l];
        *(bf16_8*)&dst[(size_t)(l0 + l) * DDIM + e0 + ec] = v;
    }
}

extern "C" void kernel_launch(void* const* d_in, const int* in_sizes, int n_in,
                              void* d_out, int out_size, void* d_ws, size_t ws_size,
                              hipStream_t stream) {
    const float* x      = (const float*)d_in[0];
    const float* Wq     = (const float*)d_in[1];
    const float* Wv     = (const float*)d_in[2];
    const float* Wo     = (const float*)d_in[3];
    const float* ln_g_s = (const float*)d_in[4];
    const float* ln_g_b = (const float*)d_in[5];
    const float* W1     = (const float*)d_in[6];
    const float* b1     = (const float*)d_in[7];
    const float* W2     = (const float*)d_in[8];
    const float* b2     = (const float*)d_in[9];
    const float* mrb    = (const float*)d_in[10];
    const float* ln_w_s = (const float*)d_in[11];
    const float* ln_w_b = (const float*)d_in[12];
    const float* Ww1    = (const float*)d_in[13];
    const float* bw1    = (const float*)d_in[14];
    const float* Ww2    = (const float*)d_in[15];
    const float* bw2    = (const float*)d_in[16];
    float* out = (float*)d_out;

    char* W = (char*)d_ws;
    __bf16* xbf = (__bf16*)W;                       // 33,554,432 B (later aliased as ybf)
    __bf16* ybf = xbf;
    __bf16* Wvb = (__bf16*)(W + 33554432);          // 2 MB
    __bf16* Wob = (__bf16*)(W + 35651584);          // 2 MB
    float*  xbp = (float*)(W + 37748736);
    float*  xbar= (float*)(W + 38010880);
    float*  qbar= (float*)(W + 38027264);
    float*  h1g = (float*)(W + 38043648);
    float*  gwp1= (float*)(W + 38109184);
    float*  gre = (float*)(W + 38125568);
    float*  gim = (float*)(W + 38650112);

    __bf16* vt = (__bf16*)d_out;                    // scratch inside d_out

    k_xbar_partial<<<dim3(4, 16, 4), 256, 0, stream>>>(x, xbp, xbf);
    k_cvt<<<1024, 256, 0, stream>>>(Wv, Wvb, DDIM * DDIM);
    k_cvt<<<1024, 256, 0, stream>>>(Wo, Wob, DDIM * DDIM);
    k_xbar_reduce<<<dim3(4, 4), 256, 0, stream>>>(xbp, xbar);
    k_qbar<<<256, 256, 0, stream>>>(xbar, Wq, qbar);
    k_mlp<<<64, 256, 0, stream>>>(qbar, ln_g_s, ln_g_b, W1, b1, ln_w_s, ln_w_b,
                                  Ww1, bw1, Ww2, bw2, h1g, gwp1);
    k_gate<<<1025, 256, 0, stream>>>(h1g, W2, b2, gre, gim);
    k_vgemm<<<256, 512, 0, stream>>>(xbf, Wvb, vt);
    k_fft<<<4096, 256, 0, stream>>>(vt, gre, gim, mrb, gwp1);
    k_t2<<<dim3(16, 64, 4), 256, 0, stream>>>(vt, ybf);
    k_ogemm<<<256, 512, 0, stream>>>(ybf, Wob, out);
}